// Round 1
// baseline (4380.368 us; speedup 1.0000x reference)
//
#include <hip/hip_runtime.h>

#define NN 50000
#define NE 800000
#define NG 50

static constexpr float BN_EPS = 1e-5f;

// ---------------- helpers ----------------
__device__ __forceinline__ unsigned f2ord(float f) {
    unsigned u = __float_as_uint(f);
    return (u & 0x80000000u) ? ~u : (u | 0x80000000u);
}
__device__ __forceinline__ float ord2f(unsigned o) {
    unsigned u = (o & 0x80000000u) ? (o & 0x7fffffffu) : ~o;
    return __uint_as_float(u);
}

// ---------------- degree / norm / counts ----------------
__global__ void k_indeg(const int* __restrict__ dst, float* __restrict__ indeg) {
    int e = blockIdx.x * 256 + threadIdx.x;
    if (e < NE) atomicAdd(&indeg[dst[e]], 1.0f);
}

__global__ void k_gcn_norm(const int* __restrict__ src, const int* __restrict__ dst,
                           const float* __restrict__ indeg, float* __restrict__ norm) {
    int e = blockIdx.x * 256 + threadIdx.x;
    if (e < NE)
        norm[e] = rsqrtf(indeg[src[e]] + 1.0f) * rsqrtf(indeg[dst[e]] + 1.0f);
}

__global__ void k_count(const int* __restrict__ batch, float* __restrict__ cntG) {
    int n = blockIdx.x * 256 + threadIdx.x;
    if (n < NN) atomicAdd(&cntG[batch[n]], 1.0f);
}

// ---------------- matmul: out[n][c] = sum_k in[n][k]*W[k][c] (+bias) (+=) -------
template <int FIN, int FOUT, bool ACCUM, bool BIAS>
__global__ void k_matmul(const float* __restrict__ in, const float* __restrict__ W,
                         const float* __restrict__ bias, float* __restrict__ out) {
    constexpr int CT = FOUT / 4;      // threads per row (each does 4 cols)
    constexpr int ROWS = 256 / CT;    // rows per block
    int lane = threadIdx.x % CT;
    int row = blockIdx.x * ROWS + threadIdx.x / CT;
    if (row >= NN) return;
    int col = lane * 4;
    const float* ip = in + (size_t)row * FIN;
    float4 acc = make_float4(0.f, 0.f, 0.f, 0.f);
#pragma unroll 4
    for (int k = 0; k < FIN; ++k) {
        float xv = ip[k];
        float4 w = *(const float4*)&W[k * FOUT + col];
        acc.x += xv * w.x; acc.y += xv * w.y; acc.z += xv * w.z; acc.w += xv * w.w;
    }
    if (BIAS) {
        float4 bb = *(const float4*)&bias[col];
        acc.x += bb.x; acc.y += bb.y; acc.z += bb.z; acc.w += bb.w;
    }
    float* op = &out[(size_t)row * FOUT + col];
    if (ACCUM) {
        float4 prev = *(float4*)op;
        acc.x += prev.x; acc.y += prev.y; acc.z += prev.z; acc.w += prev.w;
    }
    *(float4*)op = acc;
}

// ---------------- GCN aggregation ----------------
// init: out = h * dis^2 (self loop) [+ bias]
template <int F, bool BIAS>
__global__ void k_gcn_init(const float* __restrict__ h, const float* __restrict__ indeg,
                           const float* __restrict__ bias, float* __restrict__ out) {
    int idx = blockIdx.x * 256 + threadIdx.x;
    if (idx >= NN * F) return;
    int n = idx / F, f = idx % F;
    float selfn = 1.0f / (indeg[n] + 1.0f);   // dis^2
    float v = h[idx] * selfn;
    if (BIAS) v += bias[f];
    out[idx] = v;
}

template <int F>
__global__ void k_gcn_edges(const int* __restrict__ src, const int* __restrict__ dst,
                            const float* __restrict__ norm, const float* __restrict__ h,
                            float* __restrict__ out) {
    int idx = blockIdx.x * 256 + threadIdx.x;
    if (idx >= NE * F) return;
    int e = idx / F, f = idx % F;
    atomicAdd(&out[(size_t)dst[e] * F + f], h[(size_t)src[e] * F + f] * norm[e]);
}

// ---------------- BatchNorm ----------------
template <int F>
__global__ void k_bn_stats(const float* __restrict__ x, float* __restrict__ sums) {
    constexpr int LANES = 256 / F;
    __shared__ float ls[256], ls2[256];
    int f = threadIdx.x % F;
    int lane = threadIdx.x / F;
    float s = 0.f, s2 = 0.f;
    for (int n = blockIdx.x * LANES + lane; n < NN; n += gridDim.x * LANES) {
        float v = x[(size_t)n * F + f];
        s += v; s2 += v * v;
    }
    ls[threadIdx.x] = s; ls2[threadIdx.x] = s2;
    __syncthreads();
    if (lane == 0) {
#pragma unroll
        for (int l = 1; l < LANES; ++l) { s += ls[l * F + f]; s2 += ls2[l * F + f]; }
        atomicAdd(&sums[f], s);
        atomicAdd(&sums[F + f], s2);
    }
}

// ACT: 0 none, 1 relu, 2 elu
template <int F, int ACT>
__global__ void k_bn_apply(const float* __restrict__ x, const float* __restrict__ sums,
                           const float* __restrict__ gamma, const float* __restrict__ beta,
                           float* __restrict__ out) {
    int idx = blockIdx.x * 256 + threadIdx.x;
    if (idx >= NN * F) return;
    int f = idx % F;
    float mean = sums[f] * (1.0f / NN);
    float var = sums[F + f] * (1.0f / NN) - mean * mean;
    float rstd = rsqrtf(var + BN_EPS);
    float v = (x[idx] - mean) * rstd * gamma[f] + beta[f];
    if (ACT == 1) v = fmaxf(v, 0.f);
    if (ACT == 2) v = (v > 0.f) ? v : expm1f(v);
    out[idx] = v;
}

// ---------------- GAT ----------------
template <int H, int C>
__global__ void k_gat_al(const float* __restrict__ h, const float* __restrict__ as_,
                         const float* __restrict__ ad_, float* __restrict__ alsrc,
                         float* __restrict__ aldst) {
    int idx = blockIdx.x * 256 + threadIdx.x;   // n*H + hh
    if (idx >= NN * H) return;
    int n = idx / H, hh = idx % H;
    const float* hp = h + (size_t)n * H * C + hh * C;
    float s = 0.f, d = 0.f;
#pragma unroll 4
    for (int c = 0; c < C; ++c) {
        float v = hp[c];
        s += v * as_[hh * C + c];
        d += v * ad_[hh * C + c];
    }
    alsrc[idx] = s; aldst[idx] = d;
}

template <int H>
__global__ void k_gat_scores(const int* __restrict__ src, const int* __restrict__ dst,
                             const float* __restrict__ alsrc, const float* __restrict__ aldst,
                             float* __restrict__ score, unsigned* __restrict__ mord) {
    int idx = blockIdx.x * 256 + threadIdx.x;   // (E+N)*H
    if (idx >= (NE + NN) * H) return;
    int e = idx / H, hh = idx % H;
    int s_, d_;
    if (e < NE) { s_ = src[e]; d_ = dst[e]; } else { s_ = d_ = e - NE; }
    float v = alsrc[s_ * H + hh] + aldst[d_ * H + hh];
    v = (v >= 0.f) ? v : 0.2f * v;     // leaky_relu(0.2)
    score[idx] = v;
    atomicMax(&mord[d_ * H + hh], f2ord(v));
}

template <int H>
__global__ void k_gat_exp(const int* __restrict__ dst, const unsigned* __restrict__ mord,
                          float* __restrict__ score, float* __restrict__ denom) {
    int idx = blockIdx.x * 256 + threadIdx.x;   // (E+N)*H
    if (idx >= (NE + NN) * H) return;
    int e = idx / H, hh = idx % H;
    int d_ = (e < NE) ? dst[e] : e - NE;
    float m = ord2f(mord[d_ * H + hh]);
    float ex = __expf(score[idx] - m);
    score[idx] = ex;
    atomicAdd(&denom[d_ * H + hh], ex);
}

template <int H, int C, bool BIAS>
__global__ void k_gat_init(const float* __restrict__ hf, const float* __restrict__ score,
                           const float* __restrict__ denom, const float* __restrict__ bias,
                           float* __restrict__ out) {
    int idx = blockIdx.x * 256 + threadIdx.x;   // NN*H*C
    if (idx >= NN * H * C) return;
    int n = idx / (H * C);
    int hc = idx % (H * C);
    int hh = hc / C;
    float alpha = score[(size_t)(NE + n) * H + hh] / (denom[n * H + hh] + 1e-16f);
    float v = hf[idx] * alpha;
    if (BIAS) v += bias[hc];
    out[idx] = v;
}

template <int H, int C>
__global__ void k_gat_edges(const int* __restrict__ src, const int* __restrict__ dst,
                            const float* __restrict__ score, const float* __restrict__ denom,
                            const float* __restrict__ hf, float* __restrict__ out) {
    int idx = blockIdx.x * 256 + threadIdx.x;   // NE*H*C
    if (idx >= NE * H * C) return;
    int e = idx / (H * C);
    int hc = idx % (H * C);
    int hh = hc / C;
    int d_ = dst[e];
    float alpha = score[(size_t)e * H + hh] / (denom[d_ * H + hh] + 1e-16f);
    atomicAdd(&out[(size_t)d_ * H * C + hc], hf[(size_t)src[e] * H * C + hc] * alpha);
}

// ---------------- SAGE ----------------
template <int F>
__global__ void k_sage_edges(const int* __restrict__ src, const int* __restrict__ dst,
                             const float* __restrict__ x, float* __restrict__ out) {
    int idx = blockIdx.x * 256 + threadIdx.x;   // NE*F
    if (idx >= NE * F) return;
    int e = idx / F, f = idx % F;
    atomicAdd(&out[(size_t)dst[e] * F + f], x[(size_t)src[e] * F + f]);
}

template <int F>
__global__ void k_sage_div(const float* __restrict__ indeg, float* __restrict__ mean) {
    int idx = blockIdx.x * 256 + threadIdx.x;
    if (idx >= NN * F) return;
    int n = idx / F;
    mean[idx] *= 1.0f / fmaxf(indeg[n], 1.0f);
}

// ---------------- pooling / fusion ----------------
template <int F>
__global__ void k_pool(const float* __restrict__ x, const int* __restrict__ batch,
                       float* __restrict__ pooled, int off) {
    int idx = blockIdx.x * 256 + threadIdx.x;   // NN*F
    if (idx >= NN * F) return;
    int n = idx / F, f = idx % F;
    atomicAdd(&pooled[(size_t)batch[n] * 384 + off + f], x[idx]);
}

__global__ void k_fusion(const float* __restrict__ pooled, const float* __restrict__ cntG,
                         const float* __restrict__ W, const float* __restrict__ b,
                         float* __restrict__ out) {
    int idx = blockIdx.x * 256 + threadIdx.x;   // NG*128
    if (idx >= NG * 128) return;
    int g = idx / 128, o = idx % 128;
    float inv = 1.0f / fmaxf(cntG[g], 1.0f);
    float acc = b[o];
#pragma unroll 4
    for (int k = 0; k < 384; ++k)
        acc += pooled[g * 384 + k] * inv * W[k * 128 + o];
    out[idx] = acc;
}

// ---------------- launcher ----------------
static inline int grid1(long long n) { return (int)((n + 255) / 256); }

extern "C" void kernel_launch(void* const* d_in, const int* in_sizes, int n_in,
                              void* d_out, int out_size, void* d_ws, size_t ws_size,
                              hipStream_t stream) {
    const float* x       = (const float*)d_in[0];
    const int*   ei      = (const int*)d_in[1];
    const int*   batch   = (const int*)d_in[2];
    const float* gcn_W0  = (const float*)d_in[3];
    const float* gcn_W1  = (const float*)d_in[5];
    const float* gcn_W2  = (const float*)d_in[7];
    const float* gcn_b2  = (const float*)d_in[8];
    const float* gcn_g0  = (const float*)d_in[9];
    const float* gcn_bb0 = (const float*)d_in[10];
    const float* gcn_g1  = (const float*)d_in[11];
    const float* gcn_bb1 = (const float*)d_in[12];
    const float* gat_W0  = (const float*)d_in[13];
    const float* gat_as0 = (const float*)d_in[14];
    const float* gat_ad0 = (const float*)d_in[15];
    const float* gat_W1  = (const float*)d_in[17];
    const float* gat_as1 = (const float*)d_in[18];
    const float* gat_ad1 = (const float*)d_in[19];
    const float* gat_W2  = (const float*)d_in[21];
    const float* gat_as2 = (const float*)d_in[22];
    const float* gat_ad2 = (const float*)d_in[23];
    const float* gat_b2  = (const float*)d_in[24];
    const float* gat_g0  = (const float*)d_in[25];
    const float* gat_bb0 = (const float*)d_in[26];
    const float* gat_g1  = (const float*)d_in[27];
    const float* gat_bb1 = (const float*)d_in[28];
    const float* sage_Wl0 = (const float*)d_in[29];
    const float* sage_Wr0 = (const float*)d_in[30];
    const float* sage_Wl1 = (const float*)d_in[32];
    const float* sage_Wr1 = (const float*)d_in[33];
    const float* sage_Wl2 = (const float*)d_in[35];
    const float* sage_Wr2 = (const float*)d_in[36];
    const float* sage_b2  = (const float*)d_in[37];
    const float* sage_g0  = (const float*)d_in[38];
    const float* sage_bb0 = (const float*)d_in[39];
    const float* sage_g1  = (const float*)d_in[40];
    const float* sage_bb1 = (const float*)d_in[41];
    const float* fus_W    = (const float*)d_in[42];
    const float* fus_b    = (const float*)d_in[43];

    const int* src = ei;
    const int* dst = ei + NE;

    // workspace layout (floats)
    float* ws = (float*)d_ws;
    size_t off = 0;
    auto alloc = [&](size_t n) { float* p = ws + off; off += n; return p; };
    float* bufA  = alloc((size_t)NN * 128);
    float* bufB  = alloc((size_t)NN * 128);
    float* bufC  = alloc((size_t)NN * 128);
    float* score = alloc((size_t)(NE + NN) * 2);
    float* norm  = alloc((size_t)NE);
    float* indeg = alloc((size_t)NN);
    float* alsrc = alloc((size_t)NN * 2);
    float* aldst = alloc((size_t)NN * 2);
    unsigned* mord = (unsigned*)alloc((size_t)NN * 2);
    float* denom = alloc((size_t)NN * 2);
    float* bnsum = alloc(256);
    float* pooled = alloc((size_t)NG * 384);
    float* cntG  = alloc((size_t)NG);
    (void)ws_size; (void)n_in; (void)in_sizes; (void)out_size;

    // ---- precompute ----
    hipMemsetAsync(indeg, 0, NN * 4, stream);
    hipMemsetAsync(pooled, 0, NG * 384 * 4, stream);
    hipMemsetAsync(cntG, 0, NG * 4, stream);
    k_indeg<<<grid1(NE), 256, 0, stream>>>(dst, indeg);
    k_gcn_norm<<<grid1(NE), 256, 0, stream>>>(src, dst, indeg, norm);
    k_count<<<grid1(NN), 256, 0, stream>>>(batch, cntG);

    // ================= GCN =================
    // L0: 128 -> 64, BN+relu
    k_matmul<128, 64, false, false><<<grid1(NN * 16) , 256, 0, stream>>>(x, gcn_W0, nullptr, bufA);
    k_gcn_init<64, false><<<grid1(NN * 64), 256, 0, stream>>>(bufA, indeg, nullptr, bufB);
    k_gcn_edges<64><<<grid1((long long)NE * 64), 256, 0, stream>>>(src, dst, norm, bufA, bufB);
    hipMemsetAsync(bnsum, 0, 256 * 4, stream);
    k_bn_stats<64><<<512, 256, 0, stream>>>(bufB, bnsum);
    k_bn_apply<64, 1><<<grid1(NN * 64), 256, 0, stream>>>(bufB, bnsum, gcn_g0, gcn_bb0, bufB);
    // L1: 64 -> 64, BN+relu
    k_matmul<64, 64, false, false><<<grid1(NN * 16), 256, 0, stream>>>(bufB, gcn_W1, nullptr, bufA);
    k_gcn_init<64, false><<<grid1(NN * 64), 256, 0, stream>>>(bufA, indeg, nullptr, bufB);
    k_gcn_edges<64><<<grid1((long long)NE * 64), 256, 0, stream>>>(src, dst, norm, bufA, bufB);
    hipMemsetAsync(bnsum, 0, 256 * 4, stream);
    k_bn_stats<64><<<512, 256, 0, stream>>>(bufB, bnsum);
    k_bn_apply<64, 1><<<grid1(NN * 64), 256, 0, stream>>>(bufB, bnsum, gcn_g1, gcn_bb1, bufB);
    // L2: 64 -> 128, +bias, pool
    k_matmul<64, 128, false, false><<<grid1(NN * 32), 256, 0, stream>>>(bufB, gcn_W2, nullptr, bufA);
    k_gcn_init<128, true><<<grid1(NN * 128), 256, 0, stream>>>(bufA, indeg, gcn_b2, bufB);
    k_gcn_edges<128><<<grid1((long long)NE * 128), 256, 0, stream>>>(src, dst, norm, bufA, bufB);
    k_pool<128><<<grid1(NN * 128), 256, 0, stream>>>(bufB, batch, pooled, 0);

    // ================= GAT =================
    // L0: 128 -> (2,64), BN+elu
    k_matmul<128, 128, false, false><<<grid1(NN * 32), 256, 0, stream>>>(x, gat_W0, nullptr, bufA);
    k_gat_al<2, 64><<<grid1(NN * 2), 256, 0, stream>>>(bufA, gat_as0, gat_ad0, alsrc, aldst);
    hipMemsetAsync(mord, 0, NN * 2 * 4, stream);
    hipMemsetAsync(denom, 0, NN * 2 * 4, stream);
    k_gat_scores<2><<<grid1((long long)(NE + NN) * 2), 256, 0, stream>>>(src, dst, alsrc, aldst, score, mord);
    k_gat_exp<2><<<grid1((long long)(NE + NN) * 2), 256, 0, stream>>>(dst, mord, score, denom);
    k_gat_init<2, 64, false><<<grid1(NN * 128), 256, 0, stream>>>(bufA, score, denom, nullptr, bufB);
    k_gat_edges<2, 64><<<grid1((long long)NE * 128), 256, 0, stream>>>(src, dst, score, denom, bufA, bufB);
    hipMemsetAsync(bnsum, 0, 256 * 4, stream);
    k_bn_stats<128><<<512, 256, 0, stream>>>(bufB, bnsum);
    k_bn_apply<128, 2><<<grid1(NN * 128), 256, 0, stream>>>(bufB, bnsum, gat_g0, gat_bb0, bufB);
    // L1: 128 -> (2,64), BN+elu
    k_matmul<128, 128, false, false><<<grid1(NN * 32), 256, 0, stream>>>(bufB, gat_W1, nullptr, bufA);
    k_gat_al<2, 64><<<grid1(NN * 2), 256, 0, stream>>>(bufA, gat_as1, gat_ad1, alsrc, aldst);
    hipMemsetAsync(mord, 0, NN * 2 * 4, stream);
    hipMemsetAsync(denom, 0, NN * 2 * 4, stream);
    k_gat_scores<2><<<grid1((long long)(NE + NN) * 2), 256, 0, stream>>>(src, dst, alsrc, aldst, score, mord);
    k_gat_exp<2><<<grid1((long long)(NE + NN) * 2), 256, 0, stream>>>(dst, mord, score, denom);
    k_gat_init<2, 64, false><<<grid1(NN * 128), 256, 0, stream>>>(bufA, score, denom, nullptr, bufB);
    k_gat_edges<2, 64><<<grid1((long long)NE * 128), 256, 0, stream>>>(src, dst, score, denom, bufA, bufB);
    hipMemsetAsync(bnsum, 0, 256 * 4, stream);
    k_bn_stats<128><<<512, 256, 0, stream>>>(bufB, bnsum);
    k_bn_apply<128, 2><<<grid1(NN * 128), 256, 0, stream>>>(bufB, bnsum, gat_g1, gat_bb1, bufB);
    // L2: 128 -> (1,128), +bias, pool
    k_matmul<128, 128, false, false><<<grid1(NN * 32), 256, 0, stream>>>(bufB, gat_W2, nullptr, bufA);
    k_gat_al<1, 128><<<grid1(NN), 256, 0, stream>>>(bufA, gat_as2, gat_ad2, alsrc, aldst);
    hipMemsetAsync(mord, 0, NN * 4, stream);
    hipMemsetAsync(denom, 0, NN * 4, stream);
    k_gat_scores<1><<<grid1(NE + NN), 256, 0, stream>>>(src, dst, alsrc, aldst, score, mord);
    k_gat_exp<1><<<grid1(NE + NN), 256, 0, stream>>>(dst, mord, score, denom);
    k_gat_init<1, 128, true><<<grid1(NN * 128), 256, 0, stream>>>(bufA, score, denom, gat_b2, bufB);
    k_gat_edges<1, 128><<<grid1((long long)NE * 128), 256, 0, stream>>>(src, dst, score, denom, bufA, bufB);
    k_pool<128><<<grid1(NN * 128), 256, 0, stream>>>(bufB, batch, pooled, 128);

    // ================= SAGE =================
    // L0: 128 -> 64, BN+relu
    hipMemsetAsync(bufA, 0, (size_t)NN * 128 * 4, stream);
    k_sage_edges<128><<<grid1((long long)NE * 128), 256, 0, stream>>>(src, dst, x, bufA);
    k_sage_div<128><<<grid1(NN * 128), 256, 0, stream>>>(indeg, bufA);
    k_matmul<128, 64, false, false><<<grid1(NN * 16), 256, 0, stream>>>(bufA, sage_Wl0, nullptr, bufC);
    k_matmul<128, 64, true, false><<<grid1(NN * 16), 256, 0, stream>>>(x, sage_Wr0, nullptr, bufC);
    hipMemsetAsync(bnsum, 0, 256 * 4, stream);
    k_bn_stats<64><<<512, 256, 0, stream>>>(bufC, bnsum);
    k_bn_apply<64, 1><<<grid1(NN * 64), 256, 0, stream>>>(bufC, bnsum, sage_g0, sage_bb0, bufB);
    // L1: 64 -> 64, BN+relu   (input bufB)
    hipMemsetAsync(bufA, 0, (size_t)NN * 64 * 4, stream);
    k_sage_edges<64><<<grid1((long long)NE * 64), 256, 0, stream>>>(src, dst, bufB, bufA);
    k_sage_div<64><<<grid1(NN * 64), 256, 0, stream>>>(indeg, bufA);
    k_matmul<64, 64, false, false><<<grid1(NN * 16), 256, 0, stream>>>(bufA, sage_Wl1, nullptr, bufC);
    k_matmul<64, 64, true, false><<<grid1(NN * 16), 256, 0, stream>>>(bufB, sage_Wr1, nullptr, bufC);
    hipMemsetAsync(bnsum, 0, 256 * 4, stream);
    k_bn_stats<64><<<512, 256, 0, stream>>>(bufC, bnsum);
    k_bn_apply<64, 1><<<grid1(NN * 64), 256, 0, stream>>>(bufC, bnsum, sage_g1, sage_bb1, bufB);
    // L2: 64 -> 128, +bias, pool   (input bufB)
    hipMemsetAsync(bufA, 0, (size_t)NN * 64 * 4, stream);
    k_sage_edges<64><<<grid1((long long)NE * 64), 256, 0, stream>>>(src, dst, bufB, bufA);
    k_sage_div<64><<<grid1(NN * 64), 256, 0, stream>>>(indeg, bufA);
    k_matmul<64, 128, false, false><<<grid1(NN * 32), 256, 0, stream>>>(bufA, sage_Wl2, nullptr, bufC);
    k_matmul<64, 128, true, true><<<grid1(NN * 32), 256, 0, stream>>>(bufB, sage_Wr2, sage_b2, bufC);
    k_pool<128><<<grid1(NN * 128), 256, 0, stream>>>(bufC, batch, pooled, 256);

    // ================= fusion =================
    k_fusion<<<grid1(NG * 128), 256, 0, stream>>>(pooled, cntG, fus_W, fus_b, (float*)d_out);
}

// Round 2
// 2224.847 us; speedup vs baseline: 1.9688x; 1.9688x over previous
//
#include <hip/hip_runtime.h>

#define NN 50000
#define NE 800000
#define NG 50

static constexpr float BN_EPS = 1e-5f;

// ---------------- degree / CSR build ----------------
__global__ void k_indeg(const int* __restrict__ dst, int* __restrict__ indeg) {
    int e = blockIdx.x * 256 + threadIdx.x;
    if (e < NE) atomicAdd(&indeg[dst[e]], 1);
}

__global__ void k_scan(const int* __restrict__ cnt, int* __restrict__ rowstart) {
    __shared__ int tmp[1024];
    __shared__ int carry;
    if (threadIdx.x == 0) carry = 0;
    __syncthreads();
    for (int base = 0; base < NN; base += 1024) {
        int i = base + threadIdx.x;
        int v = (i < NN) ? cnt[i] : 0;
        tmp[threadIdx.x] = v;
        __syncthreads();
        for (int s = 1; s < 1024; s <<= 1) {
            int t = (threadIdx.x >= (unsigned)s) ? tmp[threadIdx.x - s] : 0;
            __syncthreads();
            tmp[threadIdx.x] += t;
            __syncthreads();
        }
        if (i < NN) rowstart[i] = carry + tmp[threadIdx.x] - v;   // exclusive
        __syncthreads();
        if (threadIdx.x == 1023) carry += tmp[1023];
        __syncthreads();
    }
    if (threadIdx.x == 0) rowstart[NN] = carry;
}

__global__ void k_fill(const int* __restrict__ src, const int* __restrict__ dst,
                       int* __restrict__ cursor, int* __restrict__ csr_src) {
    int e = blockIdx.x * 256 + threadIdx.x;
    if (e < NE) {
        int pos = atomicAdd(&cursor[dst[e]], 1);
        csr_src[pos] = src[e];
    }
}

__global__ void k_dis(const int* __restrict__ indeg, float* __restrict__ dis) {
    int n = blockIdx.x * 256 + threadIdx.x;
    if (n < NN) dis[n] = rsqrtf((float)indeg[n] + 1.0f);
}

__global__ void k_count(const int* __restrict__ batch, float* __restrict__ cntG) {
    int n = blockIdx.x * 256 + threadIdx.x;
    if (n < NN) atomicAdd(&cntG[batch[n]], 1.0f);
}

// ---------------- matmul: out[n][c] = sum_k in[n][k]*W[k][c] (+bias) (+=) -------
template <int FIN, int FOUT, bool ACCUM, bool BIAS>
__global__ void k_matmul(const float* __restrict__ in, const float* __restrict__ W,
                         const float* __restrict__ bias, float* __restrict__ out) {
    constexpr int CT = FOUT / 4;      // threads per row (each does 4 cols)
    constexpr int ROWS = 256 / CT;    // rows per block
    int lane = threadIdx.x % CT;
    int row = blockIdx.x * ROWS + threadIdx.x / CT;
    if (row >= NN) return;
    int col = lane * 4;
    const float* ip = in + (size_t)row * FIN;
    float4 acc = make_float4(0.f, 0.f, 0.f, 0.f);
#pragma unroll 4
    for (int k = 0; k < FIN; ++k) {
        float xv = ip[k];
        float4 w = *(const float4*)&W[k * FOUT + col];
        acc.x += xv * w.x; acc.y += xv * w.y; acc.z += xv * w.z; acc.w += xv * w.w;
    }
    if (BIAS) {
        float4 bb = *(const float4*)&bias[col];
        acc.x += bb.x; acc.y += bb.y; acc.z += bb.z; acc.w += bb.w;
    }
    float* op = &out[(size_t)row * FOUT + col];
    if (ACCUM) {
        float4 prev = *(float4*)op;
        acc.x += prev.x; acc.y += prev.y; acc.z += prev.z; acc.w += prev.w;
    }
    *(float4*)op = acc;
}

// ---------------- GCN aggregation (CSR, wave per node) ----------------
template <int F, bool BIAS>
__global__ __launch_bounds__(256) void k_gcn_agg(
        const int* __restrict__ rowstart, const int* __restrict__ csr_src,
        const float* __restrict__ dis, const float* __restrict__ h,
        const float* __restrict__ bias, float* __restrict__ out) {
    constexpr int VPL = F / 64;
    int wave = threadIdx.x >> 6, lane = threadIdx.x & 63;
    int n = blockIdx.x * 4 + wave;
    if (n >= NN) return;
    int r0 = rowstart[n], r1 = rowstart[n + 1];
    float dn = dis[n];
    float acc[VPL];
    const float* hself = &h[(size_t)n * F + lane * VPL];
#pragma unroll
    for (int v = 0; v < VPL; ++v) acc[v] = hself[v] * (dn * dn);   // self loop
    for (int base = r0; base < r1; base += 64) {
        int cnt = min(64, r1 - base);
        int sl = 0; float dl = 0.f;
        if (base + lane < r1) { sl = csr_src[base + lane]; dl = dis[sl]; }
        for (int j = 0; j < cnt; ++j) {
            int s = __shfl(sl, j);
            float c = __shfl(dl, j) * dn;
            const float* hp = &h[(size_t)s * F + lane * VPL];
#pragma unroll
            for (int v = 0; v < VPL; ++v) acc[v] += c * hp[v];
        }
    }
#pragma unroll
    for (int v = 0; v < VPL; ++v) {
        float val = acc[v];
        if (BIAS) val += bias[lane * VPL + v];
        out[(size_t)n * F + lane * VPL + v] = val;
    }
}

// ---------------- SAGE mean aggregation (CSR) ----------------
template <int F>
__global__ __launch_bounds__(256) void k_sage_agg(
        const int* __restrict__ rowstart, const int* __restrict__ csr_src,
        const float* __restrict__ h, float* __restrict__ out) {
    constexpr int VPL = F / 64;
    int wave = threadIdx.x >> 6, lane = threadIdx.x & 63;
    int n = blockIdx.x * 4 + wave;
    if (n >= NN) return;
    int r0 = rowstart[n], r1 = rowstart[n + 1];
    float acc[VPL];
#pragma unroll
    for (int v = 0; v < VPL; ++v) acc[v] = 0.f;
    for (int base = r0; base < r1; base += 64) {
        int cnt = min(64, r1 - base);
        int sl = 0;
        if (base + lane < r1) sl = csr_src[base + lane];
        for (int j = 0; j < cnt; ++j) {
            int s = __shfl(sl, j);
            const float* hp = &h[(size_t)s * F + lane * VPL];
#pragma unroll
            for (int v = 0; v < VPL; ++v) acc[v] += hp[v];
        }
    }
    float inv = 1.0f / fmaxf((float)(r1 - r0), 1.0f);
#pragma unroll
    for (int v = 0; v < VPL; ++v)
        out[(size_t)n * F + lane * VPL + v] = acc[v] * inv;
}

// ---------------- GAT: per-node attention + aggregation (CSR) ----------------
template <int H, int C>
__global__ void k_gat_al(const float* __restrict__ h, const float* __restrict__ as_,
                         const float* __restrict__ ad_, float* __restrict__ alsrc,
                         float* __restrict__ aldst) {
    int idx = blockIdx.x * 256 + threadIdx.x;   // n*H + hh
    if (idx >= NN * H) return;
    int n = idx / H, hh = idx % H;
    const float* hp = h + (size_t)n * H * C + hh * C;
    float s = 0.f, d = 0.f;
#pragma unroll 4
    for (int c = 0; c < C; ++c) {
        float v = hp[c];
        s += v * as_[hh * C + c];
        d += v * ad_[hh * C + c];
    }
    alsrc[idx] = s; aldst[idx] = d;
}

template <int H, int C, bool BIAS>
__global__ __launch_bounds__(256) void k_gat_agg(
        const int* __restrict__ rowstart, const int* __restrict__ csr_src,
        const float* __restrict__ alsrc, const float* __restrict__ aldst,
        const float* __restrict__ h, const float* __restrict__ bias,
        float* __restrict__ out) {
    constexpr int HC = H * C;   // 128
    int wave = threadIdx.x >> 6, lane = threadIdx.x & 63;
    int n = blockIdx.x * 4 + wave;
    if (n >= NN) return;
    int r0 = rowstart[n], r1 = rowstart[n + 1];
    float adn[H], es[H], m[H], den[H];
#pragma unroll
    for (int hh = 0; hh < H; ++hh) {
        adn[hh] = aldst[n * H + hh];
        float v = alsrc[n * H + hh] + adn[hh];
        es[hh] = (v >= 0.f) ? v : 0.2f * v;   // self-loop score
        m[hh] = es[hh];
    }
    // pass 1: max over incoming edges
    for (int base = r0; base < r1; base += 64) {
        bool valid = (base + lane) < r1;
        int sl = valid ? csr_src[base + lane] : 0;
#pragma unroll
        for (int hh = 0; hh < H; ++hh) {
            float v = alsrc[sl * H + hh] + adn[hh];
            v = (v >= 0.f) ? v : 0.2f * v;
            float mv = valid ? v : -1e30f;
            for (int off = 32; off >= 1; off >>= 1) mv = fmaxf(mv, __shfl_xor(mv, off));
            m[hh] = fmaxf(m[hh], mv);
        }
    }
    // pass 2: denominator
#pragma unroll
    for (int hh = 0; hh < H; ++hh) den[hh] = __expf(es[hh] - m[hh]);
    for (int base = r0; base < r1; base += 64) {
        bool valid = (base + lane) < r1;
        int sl = valid ? csr_src[base + lane] : 0;
#pragma unroll
        for (int hh = 0; hh < H; ++hh) {
            float v = alsrc[sl * H + hh] + adn[hh];
            v = (v >= 0.f) ? v : 0.2f * v;
            float sv = valid ? __expf(v - m[hh]) : 0.f;
            for (int off = 32; off >= 1; off >>= 1) sv += __shfl_xor(sv, off);
            den[hh] += sv;
        }
    }
#pragma unroll
    for (int hh = 0; hh < H; ++hh) den[hh] = 1.0f / (den[hh] + 1e-16f);
    // pass 3: weighted feature gather (lanes = features)
    int f0 = lane * 2;
    int hh = f0 / C;                 // head owning both features of this lane
    float mh = m[hh], dh = den[hh], adh = adn[hh];
    float a_self = __expf(es[hh] - mh) * dh;
    float2 hv = *(const float2*)&h[(size_t)n * HC + f0];
    float acc0 = a_self * hv.x, acc1 = a_self * hv.y;
    for (int base = r0; base < r1; base += 64) {
        int cnt = min(64, r1 - base);
        int sl = 0;
        if (base + lane < r1) sl = csr_src[base + lane];
        float a0l = alsrc[sl * H + 0];
        float a1l = (H > 1) ? alsrc[sl * H + 1] : 0.f;
        for (int j = 0; j < cnt; ++j) {
            int s = __shfl(sl, j);
            float aS0 = __shfl(a0l, j);
            float aS = aS0;
            if (H > 1) {
                float aS1 = __shfl(a1l, j);
                aS = (hh == 0) ? aS0 : aS1;
            }
            float v = aS + adh;
            v = (v >= 0.f) ? v : 0.2f * v;
            float alpha = __expf(v - mh) * dh;
            float2 hs = *(const float2*)&h[(size_t)s * HC + f0];
            acc0 += alpha * hs.x; acc1 += alpha * hs.y;
        }
    }
    if (BIAS) { acc0 += bias[f0]; acc1 += bias[f0 + 1]; }
    out[(size_t)n * HC + f0]     = acc0;
    out[(size_t)n * HC + f0 + 1] = acc1;
}

// ---------------- BatchNorm ----------------
template <int F>
__global__ void k_bn_stats(const float* __restrict__ x, float* __restrict__ sums) {
    constexpr int LANES = 256 / F;
    __shared__ float ls[256], ls2[256];
    int f = threadIdx.x % F;
    int lane = threadIdx.x / F;
    float s = 0.f, s2 = 0.f;
    for (int n = blockIdx.x * LANES + lane; n < NN; n += gridDim.x * LANES) {
        float v = x[(size_t)n * F + f];
        s += v; s2 += v * v;
    }
    ls[threadIdx.x] = s; ls2[threadIdx.x] = s2;
    __syncthreads();
    if (lane == 0) {
#pragma unroll
        for (int l = 1; l < LANES; ++l) { s += ls[l * F + f]; s2 += ls2[l * F + f]; }
        atomicAdd(&sums[f], s);
        atomicAdd(&sums[F + f], s2);
    }
}

// ACT: 0 none, 1 relu, 2 elu
template <int F, int ACT>
__global__ void k_bn_apply(const float* __restrict__ x, const float* __restrict__ sums,
                           const float* __restrict__ gamma, const float* __restrict__ beta,
                           float* __restrict__ out) {
    int idx = blockIdx.x * 256 + threadIdx.x;
    if (idx >= NN * F) return;
    int f = idx % F;
    float mean = sums[f] * (1.0f / NN);
    float var = sums[F + f] * (1.0f / NN) - mean * mean;
    float rstd = rsqrtf(var + BN_EPS);
    float v = (x[idx] - mean) * rstd * gamma[f] + beta[f];
    if (ACT == 1) v = fmaxf(v, 0.f);
    if (ACT == 2) v = (v > 0.f) ? v : expm1f(v);
    out[idx] = v;
}

// ---------------- pooling / fusion ----------------
// block covers 128 consecutive nodes; threads: f = tid%128, node stride 2.
__global__ void k_pool(const float* __restrict__ x, const int* __restrict__ batch,
                       float* __restrict__ pooled, int off) {
    int f = threadIdx.x & 127;
    int half = threadIdx.x >> 7;
    int nend = min(NN, (int)(blockIdx.x + 1) * 128);
    float acc = 0.f; int gcur = -1;
    for (int n = blockIdx.x * 128 + half; n < nend; n += 2) {
        int g = batch[n];
        if (g != gcur) {
            if (gcur >= 0) atomicAdd(&pooled[(size_t)gcur * 384 + off + f], acc);
            gcur = g; acc = 0.f;
        }
        acc += x[(size_t)n * 128 + f];
    }
    if (gcur >= 0) atomicAdd(&pooled[(size_t)gcur * 384 + off + f], acc);
}

__global__ void k_fusion(const float* __restrict__ pooled, const float* __restrict__ cntG,
                         const float* __restrict__ W, const float* __restrict__ b,
                         float* __restrict__ out) {
    int idx = blockIdx.x * 256 + threadIdx.x;   // NG*128
    if (idx >= NG * 128) return;
    int g = idx / 128, o = idx % 128;
    float inv = 1.0f / fmaxf(cntG[g], 1.0f);
    float acc = b[o];
#pragma unroll 4
    for (int k = 0; k < 384; ++k)
        acc += pooled[g * 384 + k] * inv * W[k * 128 + o];
    out[idx] = acc;
}

// ---------------- launcher ----------------
static inline int grid1(long long n) { return (int)((n + 255) / 256); }

extern "C" void kernel_launch(void* const* d_in, const int* in_sizes, int n_in,
                              void* d_out, int out_size, void* d_ws, size_t ws_size,
                              hipStream_t stream) {
    const float* x       = (const float*)d_in[0];
    const int*   ei      = (const int*)d_in[1];
    const int*   batch   = (const int*)d_in[2];
    const float* gcn_W0  = (const float*)d_in[3];
    const float* gcn_W1  = (const float*)d_in[5];
    const float* gcn_W2  = (const float*)d_in[7];
    const float* gcn_b2  = (const float*)d_in[8];
    const float* gcn_g0  = (const float*)d_in[9];
    const float* gcn_bb0 = (const float*)d_in[10];
    const float* gcn_g1  = (const float*)d_in[11];
    const float* gcn_bb1 = (const float*)d_in[12];
    const float* gat_W0  = (const float*)d_in[13];
    const float* gat_as0 = (const float*)d_in[14];
    const float* gat_ad0 = (const float*)d_in[15];
    const float* gat_W1  = (const float*)d_in[17];
    const float* gat_as1 = (const float*)d_in[18];
    const float* gat_ad1 = (const float*)d_in[19];
    const float* gat_W2  = (const float*)d_in[21];
    const float* gat_as2 = (const float*)d_in[22];
    const float* gat_ad2 = (const float*)d_in[23];
    const float* gat_b2  = (const float*)d_in[24];
    const float* gat_g0  = (const float*)d_in[25];
    const float* gat_bb0 = (const float*)d_in[26];
    const float* gat_g1  = (const float*)d_in[27];
    const float* gat_bb1 = (const float*)d_in[28];
    const float* sage_Wl0 = (const float*)d_in[29];
    const float* sage_Wr0 = (const float*)d_in[30];
    const float* sage_Wl1 = (const float*)d_in[32];
    const float* sage_Wr1 = (const float*)d_in[33];
    const float* sage_Wl2 = (const float*)d_in[35];
    const float* sage_Wr2 = (const float*)d_in[36];
    const float* sage_b2  = (const float*)d_in[37];
    const float* sage_g0  = (const float*)d_in[38];
    const float* sage_bb0 = (const float*)d_in[39];
    const float* sage_g1  = (const float*)d_in[40];
    const float* sage_bb1 = (const float*)d_in[41];
    const float* fus_W    = (const float*)d_in[42];
    const float* fus_b    = (const float*)d_in[43];

    const int* src = ei;
    const int* dst = ei + NE;

    // workspace layout (floats)
    float* ws = (float*)d_ws;
    size_t off = 0;
    auto alloc = [&](size_t n) { float* p = ws + off; off += n; return p; };
    float* bufA  = alloc((size_t)NN * 128);
    float* bufB  = alloc((size_t)NN * 128);
    float* bufC  = alloc((size_t)NN * 128);
    int*   indeg    = (int*)alloc(NN);
    int*   rowstart = (int*)alloc(NN + 1);
    int*   cursor   = (int*)alloc(NN);
    int*   csr_src  = (int*)alloc(NE);
    float* dis   = alloc(NN);
    float* alsrc = alloc((size_t)NN * 2);
    float* aldst = alloc((size_t)NN * 2);
    float* bnsum = alloc(256);
    float* pooled = alloc((size_t)NG * 384);
    float* cntG  = alloc((size_t)NG);
    (void)ws_size; (void)n_in; (void)in_sizes; (void)out_size;

    const int gAgg = (NN + 3) / 4;   // wave-per-node kernels

    // ---- CSR build + precompute ----
    hipMemsetAsync(indeg, 0, NN * 4, stream);
    hipMemsetAsync(pooled, 0, NG * 384 * 4, stream);
    hipMemsetAsync(cntG, 0, NG * 4, stream);
    k_indeg<<<grid1(NE), 256, 0, stream>>>(dst, indeg);
    k_scan<<<1, 1024, 0, stream>>>(indeg, rowstart);
    hipMemcpyAsync(cursor, rowstart, NN * 4, hipMemcpyDeviceToDevice, stream);
    k_fill<<<grid1(NE), 256, 0, stream>>>(src, dst, cursor, csr_src);
    k_dis<<<grid1(NN), 256, 0, stream>>>(indeg, dis);
    k_count<<<grid1(NN), 256, 0, stream>>>(batch, cntG);

    // ================= GCN =================
    k_matmul<128, 64, false, false><<<grid1(NN * 16), 256, 0, stream>>>(x, gcn_W0, nullptr, bufA);
    k_gcn_agg<64, false><<<gAgg, 256, 0, stream>>>(rowstart, csr_src, dis, bufA, nullptr, bufB);
    hipMemsetAsync(bnsum, 0, 256 * 4, stream);
    k_bn_stats<64><<<512, 256, 0, stream>>>(bufB, bnsum);
    k_bn_apply<64, 1><<<grid1(NN * 64), 256, 0, stream>>>(bufB, bnsum, gcn_g0, gcn_bb0, bufB);

    k_matmul<64, 64, false, false><<<grid1(NN * 16), 256, 0, stream>>>(bufB, gcn_W1, nullptr, bufA);
    k_gcn_agg<64, false><<<gAgg, 256, 0, stream>>>(rowstart, csr_src, dis, bufA, nullptr, bufB);
    hipMemsetAsync(bnsum, 0, 256 * 4, stream);
    k_bn_stats<64><<<512, 256, 0, stream>>>(bufB, bnsum);
    k_bn_apply<64, 1><<<grid1(NN * 64), 256, 0, stream>>>(bufB, bnsum, gcn_g1, gcn_bb1, bufB);

    k_matmul<64, 128, false, false><<<grid1(NN * 32), 256, 0, stream>>>(bufB, gcn_W2, nullptr, bufA);
    k_gcn_agg<128, true><<<gAgg, 256, 0, stream>>>(rowstart, csr_src, dis, bufA, gcn_b2, bufB);
    k_pool<<<(NN + 127) / 128, 256, 0, stream>>>(bufB, batch, pooled, 0);

    // ================= GAT =================
    k_matmul<128, 128, false, false><<<grid1(NN * 32), 256, 0, stream>>>(x, gat_W0, nullptr, bufA);
    k_gat_al<2, 64><<<grid1(NN * 2), 256, 0, stream>>>(bufA, gat_as0, gat_ad0, alsrc, aldst);
    k_gat_agg<2, 64, false><<<gAgg, 256, 0, stream>>>(rowstart, csr_src, alsrc, aldst, bufA, nullptr, bufB);
    hipMemsetAsync(bnsum, 0, 256 * 4, stream);
    k_bn_stats<128><<<512, 256, 0, stream>>>(bufB, bnsum);
    k_bn_apply<128, 2><<<grid1(NN * 128), 256, 0, stream>>>(bufB, bnsum, gat_g0, gat_bb0, bufB);

    k_matmul<128, 128, false, false><<<grid1(NN * 32), 256, 0, stream>>>(bufB, gat_W1, nullptr, bufA);
    k_gat_al<2, 64><<<grid1(NN * 2), 256, 0, stream>>>(bufA, gat_as1, gat_ad1, alsrc, aldst);
    k_gat_agg<2, 64, false><<<gAgg, 256, 0, stream>>>(rowstart, csr_src, alsrc, aldst, bufA, nullptr, bufB);
    hipMemsetAsync(bnsum, 0, 256 * 4, stream);
    k_bn_stats<128><<<512, 256, 0, stream>>>(bufB, bnsum);
    k_bn_apply<128, 2><<<grid1(NN * 128), 256, 0, stream>>>(bufB, bnsum, gat_g1, gat_bb1, bufB);

    k_matmul<128, 128, false, false><<<grid1(NN * 32), 256, 0, stream>>>(bufB, gat_W2, nullptr, bufA);
    k_gat_al<1, 128><<<grid1(NN), 256, 0, stream>>>(bufA, gat_as2, gat_ad2, alsrc, aldst);
    k_gat_agg<1, 128, true><<<gAgg, 256, 0, stream>>>(rowstart, csr_src, alsrc, aldst, bufA, gat_b2, bufB);
    k_pool<<<(NN + 127) / 128, 256, 0, stream>>>(bufB, batch, pooled, 128);

    // ================= SAGE =================
    k_sage_agg<128><<<gAgg, 256, 0, stream>>>(rowstart, csr_src, x, bufA);
    k_matmul<128, 64, false, false><<<grid1(NN * 16), 256, 0, stream>>>(bufA, sage_Wl0, nullptr, bufC);
    k_matmul<128, 64, true, false><<<grid1(NN * 16), 256, 0, stream>>>(x, sage_Wr0, nullptr, bufC);
    hipMemsetAsync(bnsum, 0, 256 * 4, stream);
    k_bn_stats<64><<<512, 256, 0, stream>>>(bufC, bnsum);
    k_bn_apply<64, 1><<<grid1(NN * 64), 256, 0, stream>>>(bufC, bnsum, sage_g0, sage_bb0, bufB);

    k_sage_agg<64><<<gAgg, 256, 0, stream>>>(rowstart, csr_src, bufB, bufA);
    k_matmul<64, 64, false, false><<<grid1(NN * 16), 256, 0, stream>>>(bufA, sage_Wl1, nullptr, bufC);
    k_matmul<64, 64, true, false><<<grid1(NN * 16), 256, 0, stream>>>(bufB, sage_Wr1, nullptr, bufC);
    hipMemsetAsync(bnsum, 0, 256 * 4, stream);
    k_bn_stats<64><<<512, 256, 0, stream>>>(bufC, bnsum);
    k_bn_apply<64, 1><<<grid1(NN * 64), 256, 0, stream>>>(bufC, bnsum, sage_g1, sage_bb1, bufB);

    k_sage_agg<64><<<gAgg, 256, 0, stream>>>(rowstart, csr_src, bufB, bufA);
    k_matmul<64, 128, false, false><<<grid1(NN * 32), 256, 0, stream>>>(bufA, sage_Wl2, nullptr, bufC);
    k_matmul<64, 128, true, true><<<grid1(NN * 32), 256, 0, stream>>>(bufB, sage_Wr2, sage_b2, bufC);
    k_pool<<<(NN + 127) / 128, 256, 0, stream>>>(bufC, batch, pooled, 256);

    // ================= fusion =================
    k_fusion<<<grid1(NG * 128), 256, 0, stream>>>(pooled, cntG, fus_W, fus_b, (float*)d_out);
}

// Round 3
// 1384.687 us; speedup vs baseline: 3.1634x; 1.6068x over previous
//
#include <hip/hip_runtime.h>

#define NN 50000
#define NE 800000
#define NG 50

static constexpr float BN_EPS = 1e-5f;

// ---------------- degree / CSR build ----------------
__global__ void k_indeg(const int* __restrict__ dst, int* __restrict__ indeg) {
    int e = blockIdx.x * 256 + threadIdx.x;
    if (e < NE) atomicAdd(&indeg[dst[e]], 1);
}

__global__ void k_scan(const int* __restrict__ cnt, int* __restrict__ rowstart) {
    __shared__ int tmp[1024];
    __shared__ int carry;
    if (threadIdx.x == 0) carry = 0;
    __syncthreads();
    for (int base = 0; base < NN; base += 1024) {
        int i = base + threadIdx.x;
        int v = (i < NN) ? cnt[i] : 0;
        tmp[threadIdx.x] = v;
        __syncthreads();
        for (int s = 1; s < 1024; s <<= 1) {
            int t = (threadIdx.x >= (unsigned)s) ? tmp[threadIdx.x - s] : 0;
            __syncthreads();
            tmp[threadIdx.x] += t;
            __syncthreads();
        }
        if (i < NN) rowstart[i] = carry + tmp[threadIdx.x] - v;   // exclusive
        __syncthreads();
        if (threadIdx.x == 1023) carry += tmp[1023];
        __syncthreads();
    }
    if (threadIdx.x == 0) rowstart[NN] = carry;
}

__global__ void k_fill(const int* __restrict__ src, const int* __restrict__ dst,
                       int* __restrict__ cursor, int* __restrict__ csr_src) {
    int e = blockIdx.x * 256 + threadIdx.x;
    if (e < NE) {
        int pos = atomicAdd(&cursor[dst[e]], 1);
        csr_src[pos] = src[e];
    }
}

__global__ void k_dis(const int* __restrict__ indeg, float* __restrict__ dis) {
    int n = blockIdx.x * 256 + threadIdx.x;
    if (n < NN) dis[n] = rsqrtf((float)indeg[n] + 1.0f);
}

// LDS histogram: one global atomic per (block, group) instead of per node.
__global__ void k_count(const int* __restrict__ batch, float* __restrict__ cntG) {
    __shared__ int hist[NG];
    for (int i = threadIdx.x; i < NG; i += 256) hist[i] = 0;
    __syncthreads();
    for (int n = blockIdx.x * 256 + threadIdx.x; n < NN; n += gridDim.x * 256)
        atomicAdd(&hist[batch[n]], 1);
    __syncthreads();
    for (int i = threadIdx.x; i < NG; i += 256)
        if (hist[i]) atomicAdd(&cntG[i], (float)hist[i]);
}

// ---------------- matmul: 4 rows x 4 cols per thread ----------------
template <int FIN, int FOUT, bool ACCUM, bool BIAS>
__global__ void k_matmul(const float* __restrict__ in, const float* __restrict__ W,
                         const float* __restrict__ bias, float* __restrict__ out) {
    constexpr int CT = FOUT / 4;      // threads per row-group (each 4 cols)
    constexpr int RG = 256 / CT;      // row-groups per block (each 4 rows)
    int lane = threadIdx.x % CT;
    int rg = blockIdx.x * RG + threadIdx.x / CT;
    int row0 = rg * 4;                // NN % 4 == 0
    if (row0 >= NN) return;
    int col = lane * 4;
    const float* ip = in + (size_t)row0 * FIN;
    float4 a0 = {0,0,0,0}, a1 = {0,0,0,0}, a2 = {0,0,0,0}, a3 = {0,0,0,0};
#pragma unroll 4
    for (int k = 0; k < FIN; ++k) {
        float4 w = *(const float4*)&W[k * FOUT + col];
        float x0 = ip[k], x1 = ip[FIN + k], x2 = ip[2 * FIN + k], x3 = ip[3 * FIN + k];
        a0.x += x0 * w.x; a0.y += x0 * w.y; a0.z += x0 * w.z; a0.w += x0 * w.w;
        a1.x += x1 * w.x; a1.y += x1 * w.y; a1.z += x1 * w.z; a1.w += x1 * w.w;
        a2.x += x2 * w.x; a2.y += x2 * w.y; a2.z += x2 * w.z; a2.w += x2 * w.w;
        a3.x += x3 * w.x; a3.y += x3 * w.y; a3.z += x3 * w.z; a3.w += x3 * w.w;
    }
    if (BIAS) {
        float4 bb = *(const float4*)&bias[col];
        a0.x += bb.x; a0.y += bb.y; a0.z += bb.z; a0.w += bb.w;
        a1.x += bb.x; a1.y += bb.y; a1.z += bb.z; a1.w += bb.w;
        a2.x += bb.x; a2.y += bb.y; a2.z += bb.z; a2.w += bb.w;
        a3.x += bb.x; a3.y += bb.y; a3.z += bb.z; a3.w += bb.w;
    }
    float* op = &out[(size_t)row0 * FOUT + col];
    if (ACCUM) {
        float4 p0 = *(float4*)op, p1 = *(float4*)(op + FOUT),
               p2 = *(float4*)(op + 2 * FOUT), p3 = *(float4*)(op + 3 * FOUT);
        a0.x += p0.x; a0.y += p0.y; a0.z += p0.z; a0.w += p0.w;
        a1.x += p1.x; a1.y += p1.y; a1.z += p1.z; a1.w += p1.w;
        a2.x += p2.x; a2.y += p2.y; a2.z += p2.z; a2.w += p2.w;
        a3.x += p3.x; a3.y += p3.y; a3.z += p3.z; a3.w += p3.w;
    }
    *(float4*)op = a0;
    *(float4*)(op + FOUT) = a1;
    *(float4*)(op + 2 * FOUT) = a2;
    *(float4*)(op + 3 * FOUT) = a3;
}

// ---------------- GCN aggregation (CSR, wave per node, EPW edge-groups) -----
template <int F, bool BIAS>
__global__ __launch_bounds__(256) void k_gcn_agg(
        const int* __restrict__ rowstart, const int* __restrict__ csr_src,
        const float* __restrict__ dis, const float* __restrict__ h,
        const float* __restrict__ bias, float* __restrict__ out) {
    constexpr int LPE = F / 4;        // lanes per edge-group
    constexpr int EPW = 64 / LPE;     // edge-groups per wave
    int wave = threadIdx.x >> 6, lane = threadIdx.x & 63;
    int n = blockIdx.x * 4 + wave;    // NN % 4 == 0
    if (n >= NN) return;
    int r0 = rowstart[n], r1 = rowstart[n + 1];
    float dn = dis[n];
    int fl = lane % LPE, eg = lane / LPE;
    int f0 = fl * 4;
    float4 acc = {0, 0, 0, 0};
    if (eg == 0) {
        float c = dn * dn;
        float4 hv = *(const float4*)&h[(size_t)n * F + f0];
        acc.x = c * hv.x; acc.y = c * hv.y; acc.z = c * hv.z; acc.w = c * hv.w;
    }
    for (int base = r0; base < r1; base += 64) {
        int cnt = min(64, r1 - base);
        bool valid = (base + lane) < r1;
        int sl = valid ? csr_src[base + lane] : 0;
        float dl = valid ? dis[sl] : 0.f;
        int iters = (cnt + EPW - 1) / EPW;
        for (int j = 0; j < iters; ++j) {
            int srcl = j * EPW + eg;
            bool ok = srcl < cnt;
            int s = __shfl(sl, srcl);
            float c = __shfl(dl, srcl) * dn;
            if (ok) {
                float4 hs = *(const float4*)&h[(size_t)s * F + f0];
                acc.x += c * hs.x; acc.y += c * hs.y; acc.z += c * hs.z; acc.w += c * hs.w;
            }
        }
    }
    for (int off = LPE; off < 64; off <<= 1) {
        acc.x += __shfl_xor(acc.x, off);
        acc.y += __shfl_xor(acc.y, off);
        acc.z += __shfl_xor(acc.z, off);
        acc.w += __shfl_xor(acc.w, off);
    }
    if (eg == 0) {
        if (BIAS) {
            float4 bb = *(const float4*)&bias[f0];
            acc.x += bb.x; acc.y += bb.y; acc.z += bb.z; acc.w += bb.w;
        }
        *(float4*)&out[(size_t)n * F + f0] = acc;
    }
}

// ---------------- SAGE mean aggregation (CSR) ----------------
template <int F>
__global__ __launch_bounds__(256) void k_sage_agg(
        const int* __restrict__ rowstart, const int* __restrict__ csr_src,
        const float* __restrict__ h, float* __restrict__ out) {
    constexpr int LPE = F / 4;
    constexpr int EPW = 64 / LPE;
    int wave = threadIdx.x >> 6, lane = threadIdx.x & 63;
    int n = blockIdx.x * 4 + wave;
    if (n >= NN) return;
    int r0 = rowstart[n], r1 = rowstart[n + 1];
    int fl = lane % LPE, eg = lane / LPE;
    int f0 = fl * 4;
    float4 acc = {0, 0, 0, 0};
    for (int base = r0; base < r1; base += 64) {
        int cnt = min(64, r1 - base);
        bool valid = (base + lane) < r1;
        int sl = valid ? csr_src[base + lane] : 0;
        int iters = (cnt + EPW - 1) / EPW;
        for (int j = 0; j < iters; ++j) {
            int srcl = j * EPW + eg;
            bool ok = srcl < cnt;
            int s = __shfl(sl, srcl);
            if (ok) {
                float4 hs = *(const float4*)&h[(size_t)s * F + f0];
                acc.x += hs.x; acc.y += hs.y; acc.z += hs.z; acc.w += hs.w;
            }
        }
    }
    for (int off = LPE; off < 64; off <<= 1) {
        acc.x += __shfl_xor(acc.x, off);
        acc.y += __shfl_xor(acc.y, off);
        acc.z += __shfl_xor(acc.z, off);
        acc.w += __shfl_xor(acc.w, off);
    }
    if (eg == 0) {
        float inv = 1.0f / fmaxf((float)(r1 - r0), 1.0f);
        acc.x *= inv; acc.y *= inv; acc.z *= inv; acc.w *= inv;
        *(float4*)&out[(size_t)n * F + f0] = acc;
    }
}

// ---------------- GAT: online softmax + weighted gather (CSR) ----------------
template <int H, int C>
__global__ void k_gat_al(const float* __restrict__ h, const float* __restrict__ as_,
                         const float* __restrict__ ad_, float* __restrict__ alsrc,
                         float* __restrict__ aldst) {
    int idx = blockIdx.x * 256 + threadIdx.x;   // n*H + hh
    if (idx >= NN * H) return;
    int n = idx / H, hh = idx % H;
    const float* hp = h + (size_t)n * H * C + hh * C;
    float s = 0.f, d = 0.f;
#pragma unroll 4
    for (int c = 0; c < C; ++c) {
        float v = hp[c];
        s += v * as_[hh * C + c];
        d += v * ad_[hh * C + c];
    }
    alsrc[idx] = s; aldst[idx] = d;
}

template <int H, int C, bool BIAS>
__global__ __launch_bounds__(256) void k_gat_agg(
        const int* __restrict__ rowstart, const int* __restrict__ csr_src,
        const float* __restrict__ alsrc, const float* __restrict__ aldst,
        const float* __restrict__ h, const float* __restrict__ bias,
        float* __restrict__ escore, float* __restrict__ out) {
    constexpr int HC = H * C;     // 128
    constexpr int LPE = HC / 4;   // 32
    constexpr int EPW = 64 / LPE; // 2
    int wave = threadIdx.x >> 6, lane = threadIdx.x & 63;
    int n = blockIdx.x * 4 + wave;
    if (n >= NN) return;
    int r0 = rowstart[n], r1 = rowstart[n + 1];
    float adn0 = aldst[n * H], adn1 = (H > 1) ? aldst[n * H + 1] : 0.f;
    float t0 = alsrc[n * H] + adn0;
    float es0 = (t0 >= 0.f) ? t0 : 0.2f * t0;
    float m0 = es0, den0 = 1.f;
    float es1 = 0.f, m1 = 0.f, den1 = 0.f;
    if (H > 1) {
        float t1 = alsrc[n * H + 1] + adn1;
        es1 = (t1 >= 0.f) ? t1 : 0.2f * t1;
        m1 = es1; den1 = 1.f;
    }
    // pass A: online softmax (max+denom in one sweep), store raw scores
    for (int base = r0; base < r1; base += 64) {
        bool valid = (base + lane) < r1;
        int sl = valid ? csr_src[base + lane] : 0;
        {
            float v = alsrc[sl * H + 0] + adn0;
            v = (v >= 0.f) ? v : 0.2f * v;
            if (valid) escore[(size_t)(base + lane) * H + 0] = v;
            float mv = valid ? v : -1e30f;
            for (int off = 32; off >= 1; off >>= 1) mv = fmaxf(mv, __shfl_xor(mv, off));
            float mn = fmaxf(m0, mv);
            float ex = valid ? __expf(v - mn) : 0.f;
            for (int off = 32; off >= 1; off >>= 1) ex += __shfl_xor(ex, off);
            den0 = den0 * __expf(m0 - mn) + ex;
            m0 = mn;
        }
        if (H > 1) {
            float v = alsrc[sl * H + 1] + adn1;
            v = (v >= 0.f) ? v : 0.2f * v;
            if (valid) escore[(size_t)(base + lane) * H + 1] = v;
            float mv = valid ? v : -1e30f;
            for (int off = 32; off >= 1; off >>= 1) mv = fmaxf(mv, __shfl_xor(mv, off));
            float mn = fmaxf(m1, mv);
            float ex = valid ? __expf(v - mn) : 0.f;
            for (int off = 32; off >= 1; off >>= 1) ex += __shfl_xor(ex, off);
            den1 = den1 * __expf(m1 - mn) + ex;
            m1 = mn;
        }
    }
    float dinv0 = 1.f / (den0 + 1e-16f);
    float dinv1 = (H > 1) ? 1.f / (den1 + 1e-16f) : 0.f;
    // pass B: weighted feature gather, EPW edges in parallel
    int fl = lane & (LPE - 1), eg = lane / LPE;
    int f0 = fl * 4;
    int hh = f0 / C;
    float mh  = (H > 1 && hh) ? m1 : m0;
    float dh  = (H > 1 && hh) ? dinv1 : dinv0;
    float esh = (H > 1 && hh) ? es1 : es0;
    float4 acc = {0, 0, 0, 0};
    if (eg == 0) {
        float a_self = __expf(esh - mh) * dh;
        float4 hv = *(const float4*)&h[(size_t)n * HC + f0];
        acc.x = a_self * hv.x; acc.y = a_self * hv.y;
        acc.z = a_self * hv.z; acc.w = a_self * hv.w;
    }
    for (int base = r0; base < r1; base += 64) {
        int cnt = min(64, r1 - base);
        bool valid = (base + lane) < r1;
        int sl = valid ? csr_src[base + lane] : 0;
        float el0 = valid ? escore[(size_t)(base + lane) * H + 0] : 0.f;
        float el1 = (H > 1 && valid) ? escore[(size_t)(base + lane) * H + 1] : 0.f;
        int iters = (cnt + EPW - 1) / EPW;
        for (int j = 0; j < iters; ++j) {
            int srcl = j * EPW + eg;
            bool ok = srcl < cnt;
            int s = __shfl(sl, srcl);
            float v0 = __shfl(el0, srcl);
            float v = v0;
            if (H > 1) {
                float v1 = __shfl(el1, srcl);
                v = hh ? v1 : v0;
            }
            if (ok) {
                float alpha = __expf(v - mh) * dh;
                float4 hs = *(const float4*)&h[(size_t)s * HC + f0];
                acc.x += alpha * hs.x; acc.y += alpha * hs.y;
                acc.z += alpha * hs.z; acc.w += alpha * hs.w;
            }
        }
    }
    for (int off = LPE; off < 64; off <<= 1) {
        acc.x += __shfl_xor(acc.x, off);
        acc.y += __shfl_xor(acc.y, off);
        acc.z += __shfl_xor(acc.z, off);
        acc.w += __shfl_xor(acc.w, off);
    }
    if (eg == 0) {
        if (BIAS) {
            float4 bb = *(const float4*)&bias[f0];
            acc.x += bb.x; acc.y += bb.y; acc.z += bb.z; acc.w += bb.w;
        }
        *(float4*)&out[(size_t)n * HC + f0] = acc;
    }
}

// ---------------- BatchNorm ----------------
template <int F>
__global__ void k_bn_stats(const float* __restrict__ x, float* __restrict__ sums) {
    constexpr int LANES = 256 / F;
    __shared__ float ls[256], ls2[256];
    int f = threadIdx.x % F;
    int lane = threadIdx.x / F;
    float s = 0.f, s2 = 0.f;
    for (int n = blockIdx.x * LANES + lane; n < NN; n += gridDim.x * LANES) {
        float v = x[(size_t)n * F + f];
        s += v; s2 += v * v;
    }
    ls[threadIdx.x] = s; ls2[threadIdx.x] = s2;
    __syncthreads();
    if (lane == 0) {
#pragma unroll
        for (int l = 1; l < LANES; ++l) { s += ls[l * F + f]; s2 += ls2[l * F + f]; }
        atomicAdd(&sums[f], s);
        atomicAdd(&sums[F + f], s2);
    }
}

// ACT: 0 none, 1 relu, 2 elu
template <int F, int ACT>
__global__ void k_bn_apply(const float* __restrict__ x, const float* __restrict__ sums,
                           const float* __restrict__ gamma, const float* __restrict__ beta,
                           float* __restrict__ out) {
    int idx = blockIdx.x * 256 + threadIdx.x;
    if (idx >= NN * F) return;
    int f = idx % F;
    float mean = sums[f] * (1.0f / NN);
    float var = sums[F + f] * (1.0f / NN) - mean * mean;
    float rstd = rsqrtf(var + BN_EPS);
    float v = (x[idx] - mean) * rstd * gamma[f] + beta[f];
    if (ACT == 1) v = fmaxf(v, 0.f);
    if (ACT == 2) v = (v > 0.f) ? v : expm1f(v);
    out[idx] = v;
}

// ---------------- pooling / fusion ----------------
__global__ void k_pool(const float* __restrict__ x, const int* __restrict__ batch,
                       float* __restrict__ pooled, int off) {
    int f = threadIdx.x & 127;
    int half = threadIdx.x >> 7;
    int nend = min(NN, (int)(blockIdx.x + 1) * 128);
    float acc = 0.f; int gcur = -1;
    for (int n = blockIdx.x * 128 + half; n < nend; n += 2) {
        int g = batch[n];
        if (g != gcur) {
            if (gcur >= 0) atomicAdd(&pooled[(size_t)gcur * 384 + off + f], acc);
            gcur = g; acc = 0.f;
        }
        acc += x[(size_t)n * 128 + f];
    }
    if (gcur >= 0) atomicAdd(&pooled[(size_t)gcur * 384 + off + f], acc);
}

__global__ void k_fusion(const float* __restrict__ pooled, const float* __restrict__ cntG,
                         const float* __restrict__ W, const float* __restrict__ b,
                         float* __restrict__ out) {
    int idx = blockIdx.x * 256 + threadIdx.x;   // NG*128
    if (idx >= NG * 128) return;
    int g = idx / 128, o = idx % 128;
    float inv = 1.0f / fmaxf(cntG[g], 1.0f);
    float acc = b[o];
#pragma unroll 4
    for (int k = 0; k < 384; ++k)
        acc += pooled[g * 384 + k] * inv * W[k * 128 + o];
    out[idx] = acc;
}

// ---------------- launcher ----------------
static inline int grid1(long long n) { return (int)((n + 255) / 256); }

extern "C" void kernel_launch(void* const* d_in, const int* in_sizes, int n_in,
                              void* d_out, int out_size, void* d_ws, size_t ws_size,
                              hipStream_t stream) {
    const float* x       = (const float*)d_in[0];
    const int*   ei      = (const int*)d_in[1];
    const int*   batch   = (const int*)d_in[2];
    const float* gcn_W0  = (const float*)d_in[3];
    const float* gcn_W1  = (const float*)d_in[5];
    const float* gcn_W2  = (const float*)d_in[7];
    const float* gcn_b2  = (const float*)d_in[8];
    const float* gcn_g0  = (const float*)d_in[9];
    const float* gcn_bb0 = (const float*)d_in[10];
    const float* gcn_g1  = (const float*)d_in[11];
    const float* gcn_bb1 = (const float*)d_in[12];
    const float* gat_W0  = (const float*)d_in[13];
    const float* gat_as0 = (const float*)d_in[14];
    const float* gat_ad0 = (const float*)d_in[15];
    const float* gat_W1  = (const float*)d_in[17];
    const float* gat_as1 = (const float*)d_in[18];
    const float* gat_ad1 = (const float*)d_in[19];
    const float* gat_W2  = (const float*)d_in[21];
    const float* gat_as2 = (const float*)d_in[22];
    const float* gat_ad2 = (const float*)d_in[23];
    const float* gat_b2  = (const float*)d_in[24];
    const float* gat_g0  = (const float*)d_in[25];
    const float* gat_bb0 = (const float*)d_in[26];
    const float* gat_g1  = (const float*)d_in[27];
    const float* gat_bb1 = (const float*)d_in[28];
    const float* sage_Wl0 = (const float*)d_in[29];
    const float* sage_Wr0 = (const float*)d_in[30];
    const float* sage_Wl1 = (const float*)d_in[32];
    const float* sage_Wr1 = (const float*)d_in[33];
    const float* sage_Wl2 = (const float*)d_in[35];
    const float* sage_Wr2 = (const float*)d_in[36];
    const float* sage_b2  = (const float*)d_in[37];
    const float* sage_g0  = (const float*)d_in[38];
    const float* sage_bb0 = (const float*)d_in[39];
    const float* sage_g1  = (const float*)d_in[40];
    const float* sage_bb1 = (const float*)d_in[41];
    const float* fus_W    = (const float*)d_in[42];
    const float* fus_b    = (const float*)d_in[43];

    const int* src = ei;
    const int* dst = ei + NE;

    // workspace layout (floats)
    float* ws = (float*)d_ws;
    size_t off = 0;
    auto alloc = [&](size_t n) { float* p = ws + off; off += n; return p; };
    float* bufA  = alloc((size_t)NN * 128);
    float* bufB  = alloc((size_t)NN * 128);
    float* bufC  = alloc((size_t)NN * 128);
    int*   indeg    = (int*)alloc(NN);
    int*   rowstart = (int*)alloc(NN + 1);
    int*   cursor   = (int*)alloc(NN);
    int*   csr_src  = (int*)alloc(NE);
    float* escore = alloc((size_t)NE * 2);
    float* dis   = alloc(NN);
    float* alsrc = alloc((size_t)NN * 2);
    float* aldst = alloc((size_t)NN * 2);
    float* bnsumAll = alloc(6 * 256);
    float* pooled = alloc((size_t)NG * 384);
    float* cntG  = alloc((size_t)NG);
    (void)ws_size; (void)n_in; (void)in_sizes; (void)out_size;

    const int gAgg = NN / 4;   // wave-per-node kernels (NN % 4 == 0)

    // ---- CSR build + precompute ----
    hipMemsetAsync(indeg, 0, NN * 4, stream);
    hipMemsetAsync(pooled, 0, NG * 384 * 4, stream);
    hipMemsetAsync(cntG, 0, NG * 4, stream);
    hipMemsetAsync(bnsumAll, 0, 6 * 256 * 4, stream);
    k_indeg<<<grid1(NE), 256, 0, stream>>>(dst, indeg);
    k_scan<<<1, 1024, 0, stream>>>(indeg, rowstart);
    hipMemcpyAsync(cursor, rowstart, NN * 4, hipMemcpyDeviceToDevice, stream);
    k_fill<<<grid1(NE), 256, 0, stream>>>(src, dst, cursor, csr_src);
    k_dis<<<grid1(NN), 256, 0, stream>>>(indeg, dis);
    k_count<<<128, 256, 0, stream>>>(batch, cntG);

    // ================= GCN =================
    k_matmul<128, 64, false, false><<<(NN/4 + 15) / 16, 256, 0, stream>>>(x, gcn_W0, nullptr, bufA);
    k_gcn_agg<64, false><<<gAgg, 256, 0, stream>>>(rowstart, csr_src, dis, bufA, nullptr, bufB);
    k_bn_stats<64><<<512, 256, 0, stream>>>(bufB, bnsumAll + 0 * 256);
    k_bn_apply<64, 1><<<grid1(NN * 64), 256, 0, stream>>>(bufB, bnsumAll + 0 * 256, gcn_g0, gcn_bb0, bufB);

    k_matmul<64, 64, false, false><<<(NN/4 + 15) / 16, 256, 0, stream>>>(bufB, gcn_W1, nullptr, bufA);
    k_gcn_agg<64, false><<<gAgg, 256, 0, stream>>>(rowstart, csr_src, dis, bufA, nullptr, bufB);
    k_bn_stats<64><<<512, 256, 0, stream>>>(bufB, bnsumAll + 1 * 256);
    k_bn_apply<64, 1><<<grid1(NN * 64), 256, 0, stream>>>(bufB, bnsumAll + 1 * 256, gcn_g1, gcn_bb1, bufB);

    k_matmul<64, 128, false, false><<<(NN/4 + 7) / 8, 256, 0, stream>>>(bufB, gcn_W2, nullptr, bufA);
    k_gcn_agg<128, true><<<gAgg, 256, 0, stream>>>(rowstart, csr_src, dis, bufA, gcn_b2, bufB);
    k_pool<<<(NN + 127) / 128, 256, 0, stream>>>(bufB, batch, pooled, 0);

    // ================= GAT =================
    k_matmul<128, 128, false, false><<<(NN/4 + 7) / 8, 256, 0, stream>>>(x, gat_W0, nullptr, bufA);
    k_gat_al<2, 64><<<grid1(NN * 2), 256, 0, stream>>>(bufA, gat_as0, gat_ad0, alsrc, aldst);
    k_gat_agg<2, 64, false><<<gAgg, 256, 0, stream>>>(rowstart, csr_src, alsrc, aldst, bufA, nullptr, escore, bufB);
    k_bn_stats<128><<<512, 256, 0, stream>>>(bufB, bnsumAll + 2 * 256);
    k_bn_apply<128, 2><<<grid1(NN * 128), 256, 0, stream>>>(bufB, bnsumAll + 2 * 256, gat_g0, gat_bb0, bufB);

    k_matmul<128, 128, false, false><<<(NN/4 + 7) / 8, 256, 0, stream>>>(bufB, gat_W1, nullptr, bufA);
    k_gat_al<2, 64><<<grid1(NN * 2), 256, 0, stream>>>(bufA, gat_as1, gat_ad1, alsrc, aldst);
    k_gat_agg<2, 64, false><<<gAgg, 256, 0, stream>>>(rowstart, csr_src, alsrc, aldst, bufA, nullptr, escore, bufB);
    k_bn_stats<128><<<512, 256, 0, stream>>>(bufB, bnsumAll + 3 * 256);
    k_bn_apply<128, 2><<<grid1(NN * 128), 256, 0, stream>>>(bufB, bnsumAll + 3 * 256, gat_g1, gat_bb1, bufB);

    k_matmul<128, 128, false, false><<<(NN/4 + 7) / 8, 256, 0, stream>>>(bufB, gat_W2, nullptr, bufA);
    k_gat_al<1, 128><<<grid1(NN), 256, 0, stream>>>(bufA, gat_as2, gat_ad2, alsrc, aldst);
    k_gat_agg<1, 128, true><<<gAgg, 256, 0, stream>>>(rowstart, csr_src, alsrc, aldst, bufA, gat_b2, escore, bufB);
    k_pool<<<(NN + 127) / 128, 256, 0, stream>>>(bufB, batch, pooled, 128);

    // ================= SAGE =================
    k_sage_agg<128><<<gAgg, 256, 0, stream>>>(rowstart, csr_src, x, bufA);
    k_matmul<128, 64, false, false><<<(NN/4 + 15) / 16, 256, 0, stream>>>(bufA, sage_Wl0, nullptr, bufC);
    k_matmul<128, 64, true, false><<<(NN/4 + 15) / 16, 256, 0, stream>>>(x, sage_Wr0, nullptr, bufC);
    k_bn_stats<64><<<512, 256, 0, stream>>>(bufC, bnsumAll + 4 * 256);
    k_bn_apply<64, 1><<<grid1(NN * 64), 256, 0, stream>>>(bufC, bnsumAll + 4 * 256, sage_g0, sage_bb0, bufB);

    k_sage_agg<64><<<gAgg, 256, 0, stream>>>(rowstart, csr_src, bufB, bufA);
    k_matmul<64, 64, false, false><<<(NN/4 + 15) / 16, 256, 0, stream>>>(bufA, sage_Wl1, nullptr, bufC);
    k_matmul<64, 64, true, false><<<(NN/4 + 15) / 16, 256, 0, stream>>>(bufB, sage_Wr1, nullptr, bufC);
    k_bn_stats<64><<<512, 256, 0, stream>>>(bufC, bnsumAll + 5 * 256);
    k_bn_apply<64, 1><<<grid1(NN * 64), 256, 0, stream>>>(bufC, bnsumAll + 5 * 256, sage_g1, sage_bb1, bufB);

    k_sage_agg<64><<<gAgg, 256, 0, stream>>>(rowstart, csr_src, bufB, bufA);
    k_matmul<64, 128, false, false><<<(NN/4 + 7) / 8, 256, 0, stream>>>(bufA, sage_Wl2, nullptr, bufC);
    k_matmul<64, 128, true, true><<<(NN/4 + 7) / 8, 256, 0, stream>>>(bufB, sage_Wr2, sage_b2, bufC);
    k_pool<<<(NN + 127) / 128, 256, 0, stream>>>(bufC, batch, pooled, 256);

    // ================= fusion =================
    k_fusion<<<grid1(NG * 128), 256, 0, stream>>>(pooled, cntG, fus_W, fus_b, (float*)d_out);
}

// Round 4
// 878.747 us; speedup vs baseline: 4.9848x; 1.5758x over previous
//
#include <hip/hip_runtime.h>

#define NN 50000
#define NE 800000
#define NG 50
#define NB 196   // ceil(NN/256)

static constexpr float BN_EPS = 1e-5f;

typedef __attribute__((ext_vector_type(8))) short  bf16x8;
typedef __attribute__((ext_vector_type(8))) unsigned short u16x8;
typedef __attribute__((ext_vector_type(4))) float  f32x4;

// ---------------- bf16 helpers ----------------
__device__ __forceinline__ float bf2f(unsigned short u) {
    return __uint_as_float(((unsigned)u) << 16);
}
__device__ __forceinline__ unsigned short f2bf(float f) {
    unsigned u = __float_as_uint(f);
    unsigned r = (u + 0x7fffu + ((u >> 16) & 1u)) >> 16;   // RNE
    return (unsigned short)r;
}

// ---------------- degree / CSR build ----------------
__global__ void k_indeg(const int* __restrict__ dst, int* __restrict__ indeg) {
    int e = blockIdx.x * 256 + threadIdx.x;
    if (e < NE) atomicAdd(&indeg[dst[e]], 1);
}

// block-local exclusive scan, block sums out
__global__ void k_scan1(const int* __restrict__ cnt, int* __restrict__ rowstart,
                        int* __restrict__ bsum) {
    int i = blockIdx.x * 256 + threadIdx.x;
    int lane = threadIdx.x & 63, wv = threadIdx.x >> 6;
    int v = (i < NN) ? cnt[i] : 0;
    int s = v;
#pragma unroll
    for (int d = 1; d < 64; d <<= 1) {
        int t = __shfl_up(s, d);
        if (lane >= d) s += t;
    }
    __shared__ int wtot[4];
    if (lane == 63) wtot[wv] = s;
    __syncthreads();
    int woff = 0;
    for (int w = 0; w < wv; ++w) woff += wtot[w];
    if (i < NN) rowstart[i] = woff + s - v;
    if (threadIdx.x == 255) bsum[blockIdx.x] = woff + s;
}

__global__ void k_scan2(const int* __restrict__ bsum, int* __restrict__ boff) {
    int lane = threadIdx.x & 63, wv = threadIdx.x >> 6;
    int v = (threadIdx.x < NB) ? bsum[threadIdx.x] : 0;
    int s = v;
#pragma unroll
    for (int d = 1; d < 64; d <<= 1) {
        int t = __shfl_up(s, d);
        if (lane >= d) s += t;
    }
    __shared__ int wtot[4];
    if (lane == 63) wtot[wv] = s;
    __syncthreads();
    int woff = 0;
    for (int w = 0; w < wv; ++w) woff += wtot[w];
    if (threadIdx.x < NB) boff[threadIdx.x] = woff + s - v;
}

__global__ void k_scan3(int* __restrict__ rowstart, const int* __restrict__ boff) {
    int i = blockIdx.x * 256 + threadIdx.x;
    if (i < NN) rowstart[i] += boff[blockIdx.x];
    if (i == 0) rowstart[NN] = NE;
}

__global__ void k_fill(const int* __restrict__ src, const int* __restrict__ dst,
                       int* __restrict__ cursor, int* __restrict__ csr_src) {
    int e = blockIdx.x * 256 + threadIdx.x;
    if (e < NE) {
        int pos = atomicAdd(&cursor[dst[e]], 1);
        csr_src[pos] = src[e];
    }
}

__global__ void k_dis(const int* __restrict__ indeg, float* __restrict__ dis) {
    int n = blockIdx.x * 256 + threadIdx.x;
    if (n < NN) dis[n] = rsqrtf((float)indeg[n] + 1.0f);
}

__global__ void k_count(const int* __restrict__ batch, float* __restrict__ cntG) {
    __shared__ int hist[NG];
    for (int i = threadIdx.x; i < NG; i += 256) hist[i] = 0;
    __syncthreads();
    for (int n = blockIdx.x * 256 + threadIdx.x; n < NN; n += gridDim.x * 256)
        atomicAdd(&hist[batch[n]], 1);
    __syncthreads();
    for (int i = threadIdx.x; i < NG; i += 256)
        if (hist[i]) atomicAdd(&cntG[i], (float)hist[i]);
}

// ---------------- conversions ----------------
__global__ void k_convx(const float* __restrict__ x, unsigned short* __restrict__ xb) {
    int i = blockIdx.x * 256 + threadIdx.x;   // units of 8 elems
    if (i >= NN * 128 / 8) return;
    float4 v0 = ((const float4*)x)[i * 2];
    float4 v1 = ((const float4*)x)[i * 2 + 1];
    u16x8 o;
    o[0] = f2bf(v0.x); o[1] = f2bf(v0.y); o[2] = f2bf(v0.z); o[3] = f2bf(v0.w);
    o[4] = f2bf(v1.x); o[5] = f2bf(v1.y); o[6] = f2bf(v1.z); o[7] = f2bf(v1.w);
    ((u16x8*)xb)[i] = o;
}

struct WDesc { const float* s; unsigned short* d; int fin; int fout; };
struct WTable { WDesc w[12]; };

// convert + transpose: dst[c*fin + k] = bf16(src[k*fout + c])
__global__ void k_convw(WTable t) {
    WDesc wd = t.w[blockIdx.x];
    int total = wd.fin * wd.fout;
    for (int i = threadIdx.x; i < total; i += 256) {
        int c = i / wd.fin, k = i % wd.fin;
        wd.d[i] = f2bf(wd.s[(size_t)k * wd.fout + c]);
    }
}

// ---------------- MFMA matmul: out[n][c] = A1@W1t (+A2@W2t) (+bias), bf16 ----
template <int FIN, int FOUT, bool DUAL, bool BIAS>
__global__ __launch_bounds__(256) void k_mm(
        const unsigned short* __restrict__ A1, const unsigned short* __restrict__ W1t,
        const unsigned short* __restrict__ A2, const unsigned short* __restrict__ W2t,
        const float* __restrict__ bias, unsigned short* __restrict__ out) {
    constexpr int NCT = FOUT / 16;
    int wave = threadIdx.x >> 6, lane = threadIdx.x & 63;
    int rowbase = (blockIdx.x * 4 + wave) * 16;
    if (rowbase >= NN) return;            // NN % 16 == 0, full tiles
    int lr = lane & 15, lg = lane >> 4;
    int arow = rowbase + lr;
    f32x4 acc[NCT] = {};
    const unsigned short* a1p = A1 + (size_t)arow * FIN + lg * 8;
    const unsigned short* a2p = DUAL ? (A2 + (size_t)arow * FIN + lg * 8) : nullptr;
#pragma unroll
    for (int k0 = 0; k0 < FIN; k0 += 32) {
        bf16x8 a1 = *(const bf16x8*)(a1p + k0);
        bf16x8 a2v = {};
        if (DUAL) a2v = *(const bf16x8*)(a2p + k0);
#pragma unroll
        for (int ct = 0; ct < NCT; ++ct) {
            int wcol = ct * 16 + lr;
            bf16x8 b1 = *(const bf16x8*)(W1t + (size_t)wcol * FIN + k0 + lg * 8);
            acc[ct] = __builtin_amdgcn_mfma_f32_16x16x32_bf16(a1, b1, acc[ct], 0, 0, 0);
            if (DUAL) {
                bf16x8 b2 = *(const bf16x8*)(W2t + (size_t)wcol * FIN + k0 + lg * 8);
                acc[ct] = __builtin_amdgcn_mfma_f32_16x16x32_bf16(a2v, b2, acc[ct], 0, 0, 0);
            }
        }
    }
#pragma unroll
    for (int ct = 0; ct < NCT; ++ct) {
        int col = ct * 16 + lr;
        float bv = BIAS ? bias[col] : 0.f;
#pragma unroll
        for (int j = 0; j < 4; ++j) {
            int row = rowbase + lg * 4 + j;
            out[(size_t)row * FOUT + col] = f2bf(acc[ct][j] + bv);
        }
    }
}

// ---------------- GCN aggregation (CSR, wave/node, bf16 features) ----------
template <int F, bool BIAS>
__global__ __launch_bounds__(256) void k_gcn_agg(
        const int* __restrict__ rowstart, const int* __restrict__ csr_src,
        const float* __restrict__ dis, const unsigned short* __restrict__ h,
        const float* __restrict__ bias, unsigned short* __restrict__ out) {
    constexpr int LPE = F / 8;        // lanes per edge (8 feats each)
    constexpr int EPW = 64 / LPE;     // edges in parallel per wave
    int wave = threadIdx.x >> 6, lane = threadIdx.x & 63;
    int n = blockIdx.x * 4 + wave;
    if (n >= NN) return;
    int r0 = rowstart[n], r1 = rowstart[n + 1];
    float dn = dis[n];
    int fl = lane % LPE, eg = lane / LPE;
    int f0 = fl * 8;
    float acc[8] = {};
    if (eg == 0) {
        u16x8 hv = *(const u16x8*)&h[(size_t)n * F + f0];
        float c = dn * dn;
#pragma unroll
        for (int j = 0; j < 8; ++j) acc[j] = c * bf2f(hv[j]);
    }
    for (int base = r0; base < r1; base += 64) {
        int cnt = min(64, r1 - base);
        bool valid = (base + lane) < r1;
        int sl = valid ? csr_src[base + lane] : 0;
        float dl = valid ? dis[sl] : 0.f;
        int iters = (cnt + EPW - 1) / EPW;
        for (int j = 0; j < iters; ++j) {
            int srcl = j * EPW + eg;
            bool ok = srcl < cnt;
            int s = __shfl(sl, srcl);
            float c = __shfl(dl, srcl) * dn;
            if (ok) {
                u16x8 hs = *(const u16x8*)&h[(size_t)s * F + f0];
#pragma unroll
                for (int jj = 0; jj < 8; ++jj) acc[jj] += c * bf2f(hs[jj]);
            }
        }
    }
#pragma unroll
    for (int off = LPE; off < 64; off <<= 1)
#pragma unroll
        for (int jj = 0; jj < 8; ++jj) acc[jj] += __shfl_xor(acc[jj], off);
    if (eg == 0) {
        u16x8 o;
#pragma unroll
        for (int jj = 0; jj < 8; ++jj) {
            float v = acc[jj];
            if (BIAS) v += bias[f0 + jj];
            o[jj] = f2bf(v);
        }
        *(u16x8*)&out[(size_t)n * F + f0] = o;
    }
}

// ---------------- SAGE mean aggregation (CSR, bf16) ----------------
template <int F>
__global__ __launch_bounds__(256) void k_sage_agg(
        const int* __restrict__ rowstart, const int* __restrict__ csr_src,
        const unsigned short* __restrict__ h, unsigned short* __restrict__ out) {
    constexpr int LPE = F / 8;
    constexpr int EPW = 64 / LPE;
    int wave = threadIdx.x >> 6, lane = threadIdx.x & 63;
    int n = blockIdx.x * 4 + wave;
    if (n >= NN) return;
    int r0 = rowstart[n], r1 = rowstart[n + 1];
    int fl = lane % LPE, eg = lane / LPE;
    int f0 = fl * 8;
    float acc[8] = {};
    for (int base = r0; base < r1; base += 64) {
        int cnt = min(64, r1 - base);
        bool valid = (base + lane) < r1;
        int sl = valid ? csr_src[base + lane] : 0;
        int iters = (cnt + EPW - 1) / EPW;
        for (int j = 0; j < iters; ++j) {
            int srcl = j * EPW + eg;
            bool ok = srcl < cnt;
            int s = __shfl(sl, srcl);
            if (ok) {
                u16x8 hs = *(const u16x8*)&h[(size_t)s * F + f0];
#pragma unroll
                for (int jj = 0; jj < 8; ++jj) acc[jj] += bf2f(hs[jj]);
            }
        }
    }
#pragma unroll
    for (int off = LPE; off < 64; off <<= 1)
#pragma unroll
        for (int jj = 0; jj < 8; ++jj) acc[jj] += __shfl_xor(acc[jj], off);
    if (eg == 0) {
        float inv = 1.0f / fmaxf((float)(r1 - r0), 1.0f);
        u16x8 o;
#pragma unroll
        for (int jj = 0; jj < 8; ++jj) o[jj] = f2bf(acc[jj] * inv);
        *(u16x8*)&out[(size_t)n * F + f0] = o;
    }
}

// ---------------- GAT ----------------
template <int H, int C>
__global__ void k_gat_al(const unsigned short* __restrict__ h, const float* __restrict__ as_,
                         const float* __restrict__ ad_, float* __restrict__ alsrc,
                         float* __restrict__ aldst) {
    int idx = blockIdx.x * 256 + threadIdx.x;   // n*H + hh
    if (idx >= NN * H) return;
    int n = idx / H, hh = idx % H;
    const unsigned short* hp = h + (size_t)n * H * C + hh * C;
    float s = 0.f, d = 0.f;
    for (int c = 0; c < C; c += 8) {
        u16x8 v = *(const u16x8*)&hp[c];
#pragma unroll
        for (int j = 0; j < 8; ++j) {
            float f = bf2f(v[j]);
            s += f * as_[hh * C + c + j];
            d += f * ad_[hh * C + c + j];
        }
    }
    alsrc[idx] = s; aldst[idx] = d;
}

template <int H, int C, bool BIAS>
__global__ __launch_bounds__(256) void k_gat_agg(
        const int* __restrict__ rowstart, const int* __restrict__ csr_src,
        const float* __restrict__ alsrc, const float* __restrict__ aldst,
        const unsigned short* __restrict__ h, const float* __restrict__ bias,
        float* __restrict__ escore, unsigned short* __restrict__ out) {
    constexpr int HC = H * C;     // 128
    constexpr int LPE = HC / 8;   // 16
    constexpr int EPW = 64 / LPE; // 4
    int wave = threadIdx.x >> 6, lane = threadIdx.x & 63;
    int n = blockIdx.x * 4 + wave;
    if (n >= NN) return;
    int r0 = rowstart[n], r1 = rowstart[n + 1];
    float adn0 = aldst[n * H], adn1 = (H > 1) ? aldst[n * H + 1] : 0.f;
    float t0 = alsrc[n * H] + adn0;
    float es0 = (t0 >= 0.f) ? t0 : 0.2f * t0;
    float m0 = es0, den0 = 1.f;
    float es1 = 0.f, m1 = 0.f, den1 = 0.f;
    if (H > 1) {
        float t1 = alsrc[n * H + 1] + adn1;
        es1 = (t1 >= 0.f) ? t1 : 0.2f * t1;
        m1 = es1; den1 = 1.f;
    }
    // pass A: online softmax over incoming edges; stash raw scores
    for (int base = r0; base < r1; base += 64) {
        bool valid = (base + lane) < r1;
        int sl = valid ? csr_src[base + lane] : 0;
        {
            float v = alsrc[sl * H + 0] + adn0;
            v = (v >= 0.f) ? v : 0.2f * v;
            if (valid) escore[(size_t)(base + lane) * H + 0] = v;
            float mv = valid ? v : -1e30f;
            for (int off = 32; off >= 1; off >>= 1) mv = fmaxf(mv, __shfl_xor(mv, off));
            float mn = fmaxf(m0, mv);
            float ex = valid ? __expf(v - mn) : 0.f;
            for (int off = 32; off >= 1; off >>= 1) ex += __shfl_xor(ex, off);
            den0 = den0 * __expf(m0 - mn) + ex;
            m0 = mn;
        }
        if (H > 1) {
            float v = alsrc[sl * H + 1] + adn1;
            v = (v >= 0.f) ? v : 0.2f * v;
            if (valid) escore[(size_t)(base + lane) * H + 1] = v;
            float mv = valid ? v : -1e30f;
            for (int off = 32; off >= 1; off >>= 1) mv = fmaxf(mv, __shfl_xor(mv, off));
            float mn = fmaxf(m1, mv);
            float ex = valid ? __expf(v - mn) : 0.f;
            for (int off = 32; off >= 1; off >>= 1) ex += __shfl_xor(ex, off);
            den1 = den1 * __expf(m1 - mn) + ex;
            m1 = mn;
        }
    }
    float dinv0 = 1.f / (den0 + 1e-16f);
    float dinv1 = (H > 1) ? 1.f / (den1 + 1e-16f) : 0.f;
    // pass B: weighted bf16 feature gather
    int fl = lane % LPE, eg = lane / LPE;
    int f0 = fl * 8;
    int hh = f0 / C;
    float mh  = (H > 1 && hh) ? m1 : m0;
    float dh  = (H > 1 && hh) ? dinv1 : dinv0;
    float esh = (H > 1 && hh) ? es1 : es0;
    float acc[8] = {};
    if (eg == 0) {
        float a_self = __expf(esh - mh) * dh;
        u16x8 hv = *(const u16x8*)&h[(size_t)n * HC + f0];
#pragma unroll
        for (int j = 0; j < 8; ++j) acc[j] = a_self * bf2f(hv[j]);
    }
    for (int base = r0; base < r1; base += 64) {
        int cnt = min(64, r1 - base);
        bool valid = (base + lane) < r1;
        int sl = valid ? csr_src[base + lane] : 0;
        float el0 = valid ? escore[(size_t)(base + lane) * H + 0] : 0.f;
        float el1 = (H > 1 && valid) ? escore[(size_t)(base + lane) * H + 1] : 0.f;
        int iters = (cnt + EPW - 1) / EPW;
        for (int j = 0; j < iters; ++j) {
            int srcl = j * EPW + eg;
            bool ok = srcl < cnt;
            int s = __shfl(sl, srcl);
            float v0 = __shfl(el0, srcl);
            float v = v0;
            if (H > 1) {
                float v1 = __shfl(el1, srcl);
                v = hh ? v1 : v0;
            }
            if (ok) {
                float alpha = __expf(v - mh) * dh;
                u16x8 hs = *(const u16x8*)&h[(size_t)s * HC + f0];
#pragma unroll
                for (int jj = 0; jj < 8; ++jj) acc[jj] += alpha * bf2f(hs[jj]);
            }
        }
    }
#pragma unroll
    for (int off = LPE; off < 64; off <<= 1)
#pragma unroll
        for (int jj = 0; jj < 8; ++jj) acc[jj] += __shfl_xor(acc[jj], off);
    if (eg == 0) {
        u16x8 o;
#pragma unroll
        for (int jj = 0; jj < 8; ++jj) {
            float v = acc[jj];
            if (BIAS) v += bias[f0 + jj];
            o[jj] = f2bf(v);
        }
        *(u16x8*)&out[(size_t)n * HC + f0] = o;
    }
}

// ---------------- BatchNorm (bf16 in, stats fp32) ----------------
template <int F>
__global__ void k_bn_stats(const unsigned short* __restrict__ x, float* __restrict__ sums) {
    constexpr int TPR = F / 8;          // threads per row
    constexpr int RPB = 256 / TPR;      // rows per block
    __shared__ float lsum[F], lsq[F];
    for (int i = threadIdx.x; i < F; i += 256) { lsum[i] = 0.f; lsq[i] = 0.f; }
    __syncthreads();
    int fl = threadIdx.x % TPR, rl = threadIdx.x / TPR;
    int f0 = fl * 8;
    float s[8] = {}, s2[8] = {};
    for (int n = blockIdx.x * RPB + rl; n < NN; n += gridDim.x * RPB) {
        u16x8 v = *(const u16x8*)&x[(size_t)n * F + f0];
#pragma unroll
        for (int j = 0; j < 8; ++j) { float f = bf2f(v[j]); s[j] += f; s2[j] += f * f; }
    }
#pragma unroll
    for (int off = TPR; off < 64; off <<= 1)
#pragma unroll
        for (int j = 0; j < 8; ++j) { s[j] += __shfl_xor(s[j], off); s2[j] += __shfl_xor(s2[j], off); }
    if ((threadIdx.x & 63) < TPR) {
#pragma unroll
        for (int j = 0; j < 8; ++j) {
            atomicAdd(&lsum[f0 + j], s[j]);
            atomicAdd(&lsq[f0 + j], s2[j]);
        }
    }
    __syncthreads();
    for (int i = threadIdx.x; i < F; i += 256) {
        atomicAdd(&sums[i], lsum[i]);
        atomicAdd(&sums[F + i], lsq[i]);
    }
}

// ACT: 1 relu, 2 elu. bf16 in/out.
template <int F, int ACT>
__global__ void k_bn_apply(const unsigned short* __restrict__ x, const float* __restrict__ sums,
                           const float* __restrict__ gamma, const float* __restrict__ beta,
                           unsigned short* __restrict__ out) {
    int idx = blockIdx.x * 256 + threadIdx.x;   // units of 8 elems
    if (idx >= NN * F / 8) return;
    int f0 = (idx % (F / 8)) * 8;
    u16x8 v = *(const u16x8*)&x[(size_t)idx * 8];
    u16x8 o;
#pragma unroll
    for (int j = 0; j < 8; ++j) {
        int f = f0 + j;
        float mean = sums[f] * (1.0f / NN);
        float var = sums[F + f] * (1.0f / NN) - mean * mean;
        float rstd = rsqrtf(var + BN_EPS);
        float val = (bf2f(v[j]) - mean) * rstd * gamma[f] + beta[f];
        if (ACT == 1) val = fmaxf(val, 0.f);
        if (ACT == 2) val = (val > 0.f) ? val : expm1f(val);
        o[j] = f2bf(val);
    }
    *(u16x8*)&out[(size_t)idx * 8] = o;
}

// ---------------- pooling / fusion ----------------
__global__ void k_pool(const unsigned short* __restrict__ x, const int* __restrict__ batch,
                       float* __restrict__ pooled, int off) {
    int f = threadIdx.x & 127;
    int half = threadIdx.x >> 7;
    int nend = min(NN, (int)(blockIdx.x + 1) * 128);
    float acc = 0.f; int gcur = -1;
    for (int n = blockIdx.x * 128 + half; n < nend; n += 2) {
        int g = batch[n];
        if (g != gcur) {
            if (gcur >= 0) atomicAdd(&pooled[(size_t)gcur * 384 + off + f], acc);
            gcur = g; acc = 0.f;
        }
        acc += bf2f(x[(size_t)n * 128 + f]);
    }
    if (gcur >= 0) atomicAdd(&pooled[(size_t)gcur * 384 + off + f], acc);
}

__global__ void k_fusion(const float* __restrict__ pooled, const float* __restrict__ cntG,
                         const float* __restrict__ W, const float* __restrict__ b,
                         float* __restrict__ out) {
    int idx = blockIdx.x * 256 + threadIdx.x;   // NG*128
    if (idx >= NG * 128) return;
    int g = idx / 128, o = idx % 128;
    float inv = 1.0f / fmaxf(cntG[g], 1.0f);
    float acc = b[o];
#pragma unroll 4
    for (int k = 0; k < 384; ++k)
        acc += pooled[g * 384 + k] * inv * W[k * 128 + o];
    out[idx] = acc;
}

// ---------------- launcher ----------------
static inline int grid1(long long n) { return (int)((n + 255) / 256); }

extern "C" void kernel_launch(void* const* d_in, const int* in_sizes, int n_in,
                              void* d_out, int out_size, void* d_ws, size_t ws_size,
                              hipStream_t stream) {
    const float* x       = (const float*)d_in[0];
    const int*   ei      = (const int*)d_in[1];
    const int*   batch   = (const int*)d_in[2];
    const float* gcn_W0  = (const float*)d_in[3];
    const float* gcn_W1  = (const float*)d_in[5];
    const float* gcn_W2  = (const float*)d_in[7];
    const float* gcn_b2  = (const float*)d_in[8];
    const float* gcn_g0  = (const float*)d_in[9];
    const float* gcn_bb0 = (const float*)d_in[10];
    const float* gcn_g1  = (const float*)d_in[11];
    const float* gcn_bb1 = (const float*)d_in[12];
    const float* gat_W0  = (const float*)d_in[13];
    const float* gat_as0 = (const float*)d_in[14];
    const float* gat_ad0 = (const float*)d_in[15];
    const float* gat_W1  = (const float*)d_in[17];
    const float* gat_as1 = (const float*)d_in[18];
    const float* gat_ad1 = (const float*)d_in[19];
    const float* gat_W2  = (const float*)d_in[21];
    const float* gat_as2 = (const float*)d_in[22];
    const float* gat_ad2 = (const float*)d_in[23];
    const float* gat_b2  = (const float*)d_in[24];
    const float* gat_g0  = (const float*)d_in[25];
    const float* gat_bb0 = (const float*)d_in[26];
    const float* gat_g1  = (const float*)d_in[27];
    const float* gat_bb1 = (const float*)d_in[28];
    const float* sage_Wl0 = (const float*)d_in[29];
    const float* sage_Wr0 = (const float*)d_in[30];
    const float* sage_Wl1 = (const float*)d_in[32];
    const float* sage_Wr1 = (const float*)d_in[33];
    const float* sage_Wl2 = (const float*)d_in[35];
    const float* sage_Wr2 = (const float*)d_in[36];
    const float* sage_b2  = (const float*)d_in[37];
    const float* sage_g0  = (const float*)d_in[38];
    const float* sage_bb0 = (const float*)d_in[39];
    const float* sage_g1  = (const float*)d_in[40];
    const float* sage_bb1 = (const float*)d_in[41];
    const float* fus_W    = (const float*)d_in[42];
    const float* fus_b    = (const float*)d_in[43];

    const int* src = ei;
    const int* dst = ei + NE;

    // workspace layout (float units, 16B-aligned chunks)
    float* ws = (float*)d_ws;
    size_t off = 0;
    auto alloc = [&](size_t n) { float* p = ws + off; off += (n + 3) & ~(size_t)3; return p; };
    unsigned short* xb    = (unsigned short*)alloc((size_t)NN * 64);   // NN*128 bf16
    unsigned short* bufAb = (unsigned short*)alloc((size_t)NN * 64);
    unsigned short* bufBb = (unsigned short*)alloc((size_t)NN * 64);
    unsigned short* bufCb = (unsigned short*)alloc((size_t)NN * 64);
    unsigned short* wt    = (unsigned short*)alloc(110592 / 2);        // 12 transposed bf16 weights
    int*   indeg    = (int*)alloc(NN);
    int*   rowstart = (int*)alloc(NN + 1);
    int*   cursor   = (int*)alloc(NN);
    int*   csr_src  = (int*)alloc(NE);
    int*   bsum     = (int*)alloc(NB);
    int*   boff     = (int*)alloc(NB);
    float* escore = alloc((size_t)NE * 2);
    float* dis   = alloc(NN);
    float* alsrc = alloc((size_t)NN * 2);
    float* aldst = alloc((size_t)NN * 2);
    float* bnsum = alloc(6 * 256);
    float* pooled = alloc((size_t)NG * 384);
    float* cntG  = alloc((size_t)NG);
    (void)ws_size; (void)n_in; (void)in_sizes; (void)out_size;

    // transposed weight offsets (elements)
    unsigned short* gcn_W0t  = wt;                 // 128x64  -> 8192
    unsigned short* gcn_W1t  = gcn_W0t + 8192;     // 64x64   -> 4096
    unsigned short* gcn_W2t  = gcn_W1t + 4096;     // 64x128  -> 8192
    unsigned short* gat_W0t  = gcn_W2t + 8192;     // 128x128 -> 16384
    unsigned short* gat_W1t  = gat_W0t + 16384;
    unsigned short* gat_W2t  = gat_W1t + 16384;
    unsigned short* sage_Wl0t = gat_W2t + 16384;   // 128x64
    unsigned short* sage_Wr0t = sage_Wl0t + 8192;
    unsigned short* sage_Wl1t = sage_Wr0t + 8192;  // 64x64
    unsigned short* sage_Wr1t = sage_Wl1t + 4096;
    unsigned short* sage_Wl2t = sage_Wr1t + 4096;  // 64x128
    unsigned short* sage_Wr2t = sage_Wl2t + 8192;

    const int gAgg = NN / 4;          // wave-per-node kernels
    const int gMM  = (NN + 63) / 64;  // 16-row wave tiles, 4 waves/block

    // ---- CSR build + precompute ----
    hipMemsetAsync(indeg, 0, NN * 4, stream);
    hipMemsetAsync(pooled, 0, NG * 384 * 4, stream);
    hipMemsetAsync(cntG, 0, NG * 4, stream);
    hipMemsetAsync(bnsum, 0, 6 * 256 * 4, stream);
    k_indeg<<<grid1(NE), 256, 0, stream>>>(dst, indeg);
    k_scan1<<<NB, 256, 0, stream>>>(indeg, rowstart, bsum);
    k_scan2<<<1, 256, 0, stream>>>(bsum, boff);
    k_scan3<<<NB, 256, 0, stream>>>(rowstart, boff);
    hipMemcpyAsync(cursor, rowstart, NN * 4, hipMemcpyDeviceToDevice, stream);
    k_fill<<<grid1(NE), 256, 0, stream>>>(src, dst, cursor, csr_src);
    k_dis<<<grid1(NN), 256, 0, stream>>>(indeg, dis);
    k_count<<<128, 256, 0, stream>>>(batch, cntG);
    k_convx<<<grid1(NN * 16), 256, 0, stream>>>(x, xb);
    WTable wtab = {{
        { gcn_W0, gcn_W0t, 128, 64 }, { gcn_W1, gcn_W1t, 64, 64 }, { gcn_W2, gcn_W2t, 64, 128 },
        { gat_W0, gat_W0t, 128, 128 }, { gat_W1, gat_W1t, 128, 128 }, { gat_W2, gat_W2t, 128, 128 },
        { sage_Wl0, sage_Wl0t, 128, 64 }, { sage_Wr0, sage_Wr0t, 128, 64 },
        { sage_Wl1, sage_Wl1t, 64, 64 }, { sage_Wr1, sage_Wr1t, 64, 64 },
        { sage_Wl2, sage_Wl2t, 64, 128 }, { sage_Wr2, sage_Wr2t, 64, 128 },
    }};
    k_convw<<<12, 256, 0, stream>>>(wtab);

    // ================= GCN =================
    k_mm<128, 64, false, false><<<gMM, 256, 0, stream>>>(xb, gcn_W0t, nullptr, nullptr, nullptr, bufAb);
    k_gcn_agg<64, false><<<gAgg, 256, 0, stream>>>(rowstart, csr_src, dis, bufAb, nullptr, bufBb);
    k_bn_stats<64><<<120, 256, 0, stream>>>(bufBb, bnsum + 0 * 256);
    k_bn_apply<64, 1><<<grid1(NN * 8), 256, 0, stream>>>(bufBb, bnsum + 0 * 256, gcn_g0, gcn_bb0, bufBb);

    k_mm<64, 64, false, false><<<gMM, 256, 0, stream>>>(bufBb, gcn_W1t, nullptr, nullptr, nullptr, bufAb);
    k_gcn_agg<64, false><<<gAgg, 256, 0, stream>>>(rowstart, csr_src, dis, bufAb, nullptr, bufBb);
    k_bn_stats<64><<<120, 256, 0, stream>>>(bufBb, bnsum + 1 * 256);
    k_bn_apply<64, 1><<<grid1(NN * 8), 256, 0, stream>>>(bufBb, bnsum + 1 * 256, gcn_g1, gcn_bb1, bufBb);

    k_mm<64, 128, false, false><<<gMM, 256, 0, stream>>>(bufBb, gcn_W2t, nullptr, nullptr, nullptr, bufAb);
    k_gcn_agg<128, true><<<gAgg, 256, 0, stream>>>(rowstart, csr_src, dis, bufAb, gcn_b2, bufBb);
    k_pool<<<(NN + 127) / 128, 256, 0, stream>>>(bufBb, batch, pooled, 0);

    // ================= GAT =================
    k_mm<128, 128, false, false><<<gMM, 256, 0, stream>>>(xb, gat_W0t, nullptr, nullptr, nullptr, bufAb);
    k_gat_al<2, 64><<<grid1(NN * 2), 256, 0, stream>>>(bufAb, gat_as0, gat_ad0, alsrc, aldst);
    k_gat_agg<2, 64, false><<<gAgg, 256, 0, stream>>>(rowstart, csr_src, alsrc, aldst, bufAb, nullptr, escore, bufBb);
    k_bn_stats<128><<<120, 256, 0, stream>>>(bufBb, bnsum + 2 * 256);
    k_bn_apply<128, 2><<<grid1(NN * 16), 256, 0, stream>>>(bufBb, bnsum + 2 * 256, gat_g0, gat_bb0, bufBb);

    k_mm<128, 128, false, false><<<gMM, 256, 0, stream>>>(bufBb, gat_W1t, nullptr, nullptr, nullptr, bufAb);
    k_gat_al<2, 64><<<grid1(NN * 2), 256, 0, stream>>>(bufAb, gat_as1, gat_ad1, alsrc, aldst);
    k_gat_agg<2, 64, false><<<gAgg, 256, 0, stream>>>(rowstart, csr_src, alsrc, aldst, bufAb, nullptr, escore, bufBb);
    k_bn_stats<128><<<120, 256, 0, stream>>>(bufBb, bnsum + 3 * 256);
    k_bn_apply<128, 2><<<grid1(NN * 16), 256, 0, stream>>>(bufBb, bnsum + 3 * 256, gat_g1, gat_bb1, bufBb);

    k_mm<128, 128, false, false><<<gMM, 256, 0, stream>>>(bufBb, gat_W2t, nullptr, nullptr, nullptr, bufAb);
    k_gat_al<1, 128><<<grid1(NN), 256, 0, stream>>>(bufAb, gat_as2, gat_ad2, alsrc, aldst);
    k_gat_agg<1, 128, true><<<gAgg, 256, 0, stream>>>(rowstart, csr_src, alsrc, aldst, bufAb, gat_b2, escore, bufBb);
    k_pool<<<(NN + 127) / 128, 256, 0, stream>>>(bufBb, batch, pooled, 128);

    // ================= SAGE =================
    k_sage_agg<128><<<gAgg, 256, 0, stream>>>(rowstart, csr_src, xb, bufAb);
    k_mm<128, 64, true, false><<<gMM, 256, 0, stream>>>(bufAb, sage_Wl0t, xb, sage_Wr0t, nullptr, bufCb);
    k_bn_stats<64><<<120, 256, 0, stream>>>(bufCb, bnsum + 4 * 256);
    k_bn_apply<64, 1><<<grid1(NN * 8), 256, 0, stream>>>(bufCb, bnsum + 4 * 256, sage_g0, sage_bb0, bufBb);

    k_sage_agg<64><<<gAgg, 256, 0, stream>>>(rowstart, csr_src, bufBb, bufAb);
    k_mm<64, 64, true, false><<<gMM, 256, 0, stream>>>(bufAb, sage_Wl1t, bufBb, sage_Wr1t, nullptr, bufCb);
    k_bn_stats<64><<<120, 256, 0, stream>>>(bufCb, bnsum + 5 * 256);
    k_bn_apply<64, 1><<<grid1(NN * 8), 256, 0, stream>>>(bufCb, bnsum + 5 * 256, sage_g1, sage_bb1, bufBb);

    k_sage_agg<64><<<gAgg, 256, 0, stream>>>(rowstart, csr_src, bufBb, bufAb);
    k_mm<64, 128, true, true><<<gMM, 256, 0, stream>>>(bufAb, sage_Wl2t, bufBb, sage_Wr2t, sage_b2, bufCb);
    k_pool<<<(NN + 127) / 128, 256, 0, stream>>>(bufCb, batch, pooled, 256);

    // ================= fusion =================
    k_fusion<<<grid1(NG * 128), 256, 0, stream>>>(pooled, cntG, fus_W, fus_b, (float*)d_out);
}

// Round 5
// 821.727 us; speedup vs baseline: 5.3307x; 1.0694x over previous
//
#include <hip/hip_runtime.h>

#define NN 50000
#define NE 800000
#define NG 50
#define NB 196   // ceil(NN/256)

static constexpr float BN_EPS = 1e-5f;

typedef __attribute__((ext_vector_type(8))) short  bf16x8;
typedef __attribute__((ext_vector_type(8))) unsigned short u16x8;
typedef __attribute__((ext_vector_type(4))) float  f32x4;

// ---------------- bf16 helpers ----------------
__device__ __forceinline__ float bf2f(unsigned short u) {
    return __uint_as_float(((unsigned)u) << 16);
}
__device__ __forceinline__ unsigned short f2bf(float f) {
    unsigned u = __float_as_uint(f);
    unsigned r = (u + 0x7fffu + ((u >> 16) & 1u)) >> 16;   // RNE
    return (unsigned short)r;
}

// ---------------- degree / CSR build ----------------
__global__ void k_indeg(const int* __restrict__ dst, int* __restrict__ indeg) {
    int e = blockIdx.x * 256 + threadIdx.x;
    if (e < NE) atomicAdd(&indeg[dst[e]], 1);
}

// block-local exclusive scan + dis computation
__global__ void k_scan1(const int* __restrict__ cnt, int* __restrict__ rowstart,
                        int* __restrict__ bsum, float* __restrict__ dis) {
    int i = blockIdx.x * 256 + threadIdx.x;
    int lane = threadIdx.x & 63, wv = threadIdx.x >> 6;
    int v = (i < NN) ? cnt[i] : 0;
    if (i < NN) dis[i] = rsqrtf((float)v + 1.0f);
    int s = v;
#pragma unroll
    for (int d = 1; d < 64; d <<= 1) {
        int t = __shfl_up(s, d);
        if (lane >= d) s += t;
    }
    __shared__ int wtot[4];
    if (lane == 63) wtot[wv] = s;
    __syncthreads();
    int woff = 0;
    for (int w = 0; w < wv; ++w) woff += wtot[w];
    if (i < NN) rowstart[i] = woff + s - v;
    if (threadIdx.x == 255) bsum[blockIdx.x] = woff + s;
}

__global__ void k_scan2(const int* __restrict__ bsum, int* __restrict__ boff) {
    int lane = threadIdx.x & 63, wv = threadIdx.x >> 6;
    int v = (threadIdx.x < NB) ? bsum[threadIdx.x] : 0;
    int s = v;
#pragma unroll
    for (int d = 1; d < 64; d <<= 1) {
        int t = __shfl_up(s, d);
        if (lane >= d) s += t;
    }
    __shared__ int wtot[4];
    if (lane == 63) wtot[wv] = s;
    __syncthreads();
    int woff = 0;
    for (int w = 0; w < wv; ++w) woff += wtot[w];
    if (threadIdx.x < NB) boff[threadIdx.x] = woff + s - v;
}

__global__ void k_scan3(int* __restrict__ rowstart, const int* __restrict__ boff,
                        int* __restrict__ cursor) {
    int i = blockIdx.x * 256 + threadIdx.x;
    if (i < NN) {
        int v = rowstart[i] + boff[blockIdx.x];
        rowstart[i] = v;
        cursor[i] = v;
    }
    if (i == 0) rowstart[NN] = NE;
}

__global__ void k_fill(const int* __restrict__ src, const int* __restrict__ dst,
                       int* __restrict__ cursor, int* __restrict__ csr_src) {
    int e = blockIdx.x * 256 + threadIdx.x;
    if (e < NE) {
        int pos = atomicAdd(&cursor[dst[e]], 1);
        csr_src[pos] = src[e];
    }
}

__global__ void k_count(const int* __restrict__ batch, float* __restrict__ cntG) {
    __shared__ int hist[NG];
    for (int i = threadIdx.x; i < NG; i += 256) hist[i] = 0;
    __syncthreads();
    for (int n = blockIdx.x * 256 + threadIdx.x; n < NN; n += gridDim.x * 256)
        atomicAdd(&hist[batch[n]], 1);
    __syncthreads();
    for (int i = threadIdx.x; i < NG; i += 256)
        if (hist[i]) atomicAdd(&cntG[i], (float)hist[i]);
}

// ---------------- conversions ----------------
__global__ void k_convx(const float* __restrict__ x, unsigned short* __restrict__ xb) {
    int i = blockIdx.x * 256 + threadIdx.x;   // units of 8 elems
    if (i >= NN * 128 / 8) return;
    float4 v0 = ((const float4*)x)[i * 2];
    float4 v1 = ((const float4*)x)[i * 2 + 1];
    u16x8 o;
    o[0] = f2bf(v0.x); o[1] = f2bf(v0.y); o[2] = f2bf(v0.z); o[3] = f2bf(v0.w);
    o[4] = f2bf(v1.x); o[5] = f2bf(v1.y); o[6] = f2bf(v1.z); o[7] = f2bf(v1.w);
    ((u16x8*)xb)[i] = o;
}

struct WDesc { const float* s; unsigned short* d; int fin; int fout; };
struct WTable { WDesc w[12]; };

// convert + transpose: dst[c*fin + k] = bf16(src[k*fout + c])
__global__ void k_convw(WTable t) {
    WDesc wd = t.w[blockIdx.x];
    int total = wd.fin * wd.fout;
    for (int i = threadIdx.x; i < total; i += 256) {
        int c = i / wd.fin, k = i % wd.fin;
        wd.d[i] = f2bf(wd.s[(size_t)k * wd.fout + c]);
    }
}

// ---------------- MFMA matmul ----------------
// out = A1@W1t (+A2@W2t) (+ADD) (+bias); optional GAT al epilogue (ALH heads)
template <int FIN, int FOUT, bool DUAL, bool BIAS, bool ADDIN, int ALH>
__global__ __launch_bounds__(256) void k_mm(
        const unsigned short* __restrict__ A1, const unsigned short* __restrict__ W1t,
        const unsigned short* __restrict__ A2, const unsigned short* __restrict__ W2t,
        const unsigned short* __restrict__ ADD, const float* __restrict__ bias,
        const float* __restrict__ as_, const float* __restrict__ ad_,
        float* __restrict__ alsrc, float* __restrict__ aldst,
        unsigned short* __restrict__ out) {
    constexpr int NCT = FOUT / 16;
    int wave = threadIdx.x >> 6, lane = threadIdx.x & 63;
    int rowbase = (blockIdx.x * 4 + wave) * 16;
    if (rowbase >= NN) return;
    int lr = lane & 15, lg = lane >> 4;
    int arow = rowbase + lr;
    f32x4 acc[NCT] = {};
    const unsigned short* a1p = A1 + (size_t)arow * FIN + lg * 8;
    const unsigned short* a2p = DUAL ? (A2 + (size_t)arow * FIN + lg * 8) : nullptr;
#pragma unroll
    for (int k0 = 0; k0 < FIN; k0 += 32) {
        bf16x8 a1 = *(const bf16x8*)(a1p + k0);
        bf16x8 a2v = {};
        if (DUAL) a2v = *(const bf16x8*)(a2p + k0);
#pragma unroll
        for (int ct = 0; ct < NCT; ++ct) {
            int wcol = ct * 16 + lr;
            bf16x8 b1 = *(const bf16x8*)(W1t + (size_t)wcol * FIN + k0 + lg * 8);
            acc[ct] = __builtin_amdgcn_mfma_f32_16x16x32_bf16(a1, b1, acc[ct], 0, 0, 0);
            if (DUAL) {
                bf16x8 b2 = *(const bf16x8*)(W2t + (size_t)wcol * FIN + k0 + lg * 8);
                acc[ct] = __builtin_amdgcn_mfma_f32_16x16x32_bf16(a2v, b2, acc[ct], 0, 0, 0);
            }
        }
    }
    if (ADDIN) {
#pragma unroll
        for (int ct = 0; ct < NCT; ++ct) {
            int col = ct * 16 + lr;
#pragma unroll
            for (int j = 0; j < 4; ++j) {
                int row = rowbase + lg * 4 + j;
                acc[ct][j] += bf2f(ADD[(size_t)row * FOUT + col]);
            }
        }
    }
    // GAT attention-logit epilogue (on pre-bias h)
    if (ALH > 0) {
        constexpr int NH = (ALH > 0) ? ALH : 1;
        float ps[NH][4] = {}, pd[NH][4] = {};
#pragma unroll
        for (int ct = 0; ct < NCT; ++ct) {
            int hh = (ALH == 2 && ct >= NCT / 2) ? 1 : 0;
            int col = ct * 16 + lr;
            float cs = as_[col], cd = ad_[col];
#pragma unroll
            for (int j = 0; j < 4; ++j) {
                ps[hh][j] += acc[ct][j] * cs;
                pd[hh][j] += acc[ct][j] * cd;
            }
        }
#pragma unroll
        for (int m = 1; m < 16; m <<= 1) {
#pragma unroll
            for (int hh = 0; hh < NH; ++hh)
#pragma unroll
                for (int j = 0; j < 4; ++j) {
                    ps[hh][j] += __shfl_xor(ps[hh][j], m);
                    pd[hh][j] += __shfl_xor(pd[hh][j], m);
                }
        }
        if (lr == 0) {
#pragma unroll
            for (int j = 0; j < 4; ++j) {
                int row = rowbase + lg * 4 + j;
#pragma unroll
                for (int hh = 0; hh < NH; ++hh) {
                    alsrc[(size_t)row * ALH + hh] = ps[hh][j];
                    aldst[(size_t)row * ALH + hh] = pd[hh][j];
                }
            }
        }
    }
#pragma unroll
    for (int ct = 0; ct < NCT; ++ct) {
        int col = ct * 16 + lr;
        float bv = BIAS ? bias[col] : 0.f;
#pragma unroll
        for (int j = 0; j < 4; ++j) {
            int row = rowbase + lg * 4 + j;
            out[(size_t)row * FOUT + col] = f2bf(acc[ct][j] + bv);
        }
    }
}

// ---------------- GCN aggregation (CSR, wave/node, bf16 features) ----------
template <int F, bool BIAS>
__global__ __launch_bounds__(256) void k_gcn_agg(
        const int* __restrict__ rowstart, const int* __restrict__ csr_src,
        const float* __restrict__ dis, const unsigned short* __restrict__ h,
        const float* __restrict__ bias, unsigned short* __restrict__ out) {
    constexpr int LPE = F / 8;
    constexpr int EPW = 64 / LPE;
    int wave = threadIdx.x >> 6, lane = threadIdx.x & 63;
    int n = blockIdx.x * 4 + wave;
    if (n >= NN) return;
    int r0 = rowstart[n], r1 = rowstart[n + 1];
    float dn = dis[n];
    int fl = lane % LPE, eg = lane / LPE;
    int f0 = fl * 8;
    float acc[8] = {};
    if (eg == 0) {
        u16x8 hv = *(const u16x8*)&h[(size_t)n * F + f0];
        float c = dn * dn;
#pragma unroll
        for (int j = 0; j < 8; ++j) acc[j] = c * bf2f(hv[j]);
    }
    for (int base = r0; base < r1; base += 64) {
        int cnt = min(64, r1 - base);
        bool valid = (base + lane) < r1;
        int sl = valid ? csr_src[base + lane] : 0;
        float dl = valid ? dis[sl] : 0.f;
        int iters = (cnt + EPW - 1) / EPW;
        for (int j = 0; j < iters; ++j) {
            int srcl = j * EPW + eg;
            bool ok = srcl < cnt;
            int s = __shfl(sl, srcl);
            float c = __shfl(dl, srcl) * dn;
            if (ok) {
                u16x8 hs = *(const u16x8*)&h[(size_t)s * F + f0];
#pragma unroll
                for (int jj = 0; jj < 8; ++jj) acc[jj] += c * bf2f(hs[jj]);
            }
        }
    }
#pragma unroll
    for (int off = LPE; off < 64; off <<= 1)
#pragma unroll
        for (int jj = 0; jj < 8; ++jj) acc[jj] += __shfl_xor(acc[jj], off);
    if (eg == 0) {
        u16x8 o;
#pragma unroll
        for (int jj = 0; jj < 8; ++jj) {
            float v = acc[jj];
            if (BIAS) v += bias[f0 + jj];
            o[jj] = f2bf(v);
        }
        *(u16x8*)&out[(size_t)n * F + f0] = o;
    }
}

// ---------------- SAGE mean aggregation (CSR, bf16) ----------------
template <int F>
__global__ __launch_bounds__(256) void k_sage_agg(
        const int* __restrict__ rowstart, const int* __restrict__ csr_src,
        const unsigned short* __restrict__ h, unsigned short* __restrict__ out) {
    constexpr int LPE = F / 8;
    constexpr int EPW = 64 / LPE;
    int wave = threadIdx.x >> 6, lane = threadIdx.x & 63;
    int n = blockIdx.x * 4 + wave;
    if (n >= NN) return;
    int r0 = rowstart[n], r1 = rowstart[n + 1];
    int fl = lane % LPE, eg = lane / LPE;
    int f0 = fl * 8;
    float acc[8] = {};
    for (int base = r0; base < r1; base += 64) {
        int cnt = min(64, r1 - base);
        bool valid = (base + lane) < r1;
        int sl = valid ? csr_src[base + lane] : 0;
        int iters = (cnt + EPW - 1) / EPW;
        for (int j = 0; j < iters; ++j) {
            int srcl = j * EPW + eg;
            bool ok = srcl < cnt;
            int s = __shfl(sl, srcl);
            if (ok) {
                u16x8 hs = *(const u16x8*)&h[(size_t)s * F + f0];
#pragma unroll
                for (int jj = 0; jj < 8; ++jj) acc[jj] += bf2f(hs[jj]);
            }
        }
    }
#pragma unroll
    for (int off = LPE; off < 64; off <<= 1)
#pragma unroll
        for (int jj = 0; jj < 8; ++jj) acc[jj] += __shfl_xor(acc[jj], off);
    if (eg == 0) {
        float inv = 1.0f / fmaxf((float)(r1 - r0), 1.0f);
        u16x8 o;
#pragma unroll
        for (int jj = 0; jj < 8; ++jj) o[jj] = f2bf(acc[jj] * inv);
        *(u16x8*)&out[(size_t)n * F + f0] = o;
    }
}

// ---------------- GAT: single-pass unnormalized softmax + gather ----------
// Scores bounded (|v| < ~30) so exp without max-subtraction is exact-safe in fp32.
template <int H, int C, bool BIAS>
__global__ __launch_bounds__(256) void k_gat_agg(
        const int* __restrict__ rowstart, const int* __restrict__ csr_src,
        const float* __restrict__ alsrc, const float* __restrict__ aldst,
        const unsigned short* __restrict__ h, const float* __restrict__ bias,
        unsigned short* __restrict__ out) {
    constexpr int HC = H * C;     // 128
    constexpr int LPE = HC / 8;   // 16
    constexpr int EPW = 64 / LPE; // 4
    int wave = threadIdx.x >> 6, lane = threadIdx.x & 63;
    int n = blockIdx.x * 4 + wave;
    if (n >= NN) return;
    int r0 = rowstart[n], r1 = rowstart[n + 1];
    float adn0 = aldst[n * H], adn1 = (H > 1) ? aldst[n * H + 1] : 0.f;
    float t0 = alsrc[n * H] + adn0;
    float ws0 = __expf((t0 >= 0.f) ? t0 : 0.2f * t0);   // self weight
    float ws1 = 0.f;
    if (H > 1) {
        float t1 = alsrc[n * H + 1] + adn1;
        ws1 = __expf((t1 >= 0.f) ? t1 : 0.2f * t1);
    }
    int fl = lane % LPE, eg = lane / LPE;
    int f0 = fl * 8;
    int hh = f0 / C;
    float acc[8] = {};
    float dsum0 = 0.f, dsum1 = 0.f;   // per-lane partial denominators
    if (eg == 0) {
        float a_self = (H > 1 && hh) ? ws1 : ws0;
        u16x8 hv = *(const u16x8*)&h[(size_t)n * HC + f0];
#pragma unroll
        for (int j = 0; j < 8; ++j) acc[j] = a_self * bf2f(hv[j]);
    }
    for (int base = r0; base < r1; base += 64) {
        int cnt = min(64, r1 - base);
        bool valid = (base + lane) < r1;
        int sl = valid ? csr_src[base + lane] : 0;
        float w0 = 0.f, w1 = 0.f;
        if (valid) {
            float v = alsrc[sl * H + 0] + adn0;
            w0 = __expf((v >= 0.f) ? v : 0.2f * v);
            if (H > 1) {
                float v1 = alsrc[sl * H + 1] + adn1;
                w1 = __expf((v1 >= 0.f) ? v1 : 0.2f * v1);
            }
        }
        dsum0 += w0; dsum1 += w1;
        int iters = (cnt + EPW - 1) / EPW;
        for (int j = 0; j < iters; ++j) {
            int srcl = j * EPW + eg;
            bool ok = srcl < cnt;
            int s = __shfl(sl, srcl);
            float a0 = __shfl(w0, srcl);
            float a = a0;
            if (H > 1) {
                float a1 = __shfl(w1, srcl);
                a = hh ? a1 : a0;
            }
            if (ok) {
                u16x8 hs = *(const u16x8*)&h[(size_t)s * HC + f0];
#pragma unroll
                for (int jj = 0; jj < 8; ++jj) acc[jj] += a * bf2f(hs[jj]);
            }
        }
    }
    // full-wave reduce of denominators (each lane owned distinct edges)
#pragma unroll
    for (int off = 1; off < 64; off <<= 1) {
        dsum0 += __shfl_xor(dsum0, off);
        if (H > 1) dsum1 += __shfl_xor(dsum1, off);
    }
    // feature reduce across edge-groups
#pragma unroll
    for (int off = LPE; off < 64; off <<= 1)
#pragma unroll
        for (int jj = 0; jj < 8; ++jj) acc[jj] += __shfl_xor(acc[jj], off);
    if (eg == 0) {
        float den = (H > 1 && hh) ? (ws1 + dsum1) : (ws0 + dsum0);
        float dinv = 1.0f / (den + 1e-16f);
        u16x8 o;
#pragma unroll
        for (int jj = 0; jj < 8; ++jj) {
            float v = acc[jj] * dinv;
            if (BIAS) v += bias[f0 + jj];
            o[jj] = f2bf(v);
        }
        *(u16x8*)&out[(size_t)n * HC + f0] = o;
    }
}

// ---------------- BatchNorm (bf16 in, stats fp32) ----------------
template <int F>
__global__ void k_bn_stats(const unsigned short* __restrict__ x, float* __restrict__ sums) {
    constexpr int TPR = F / 8;
    constexpr int RPB = 256 / TPR;
    __shared__ float lsum[F], lsq[F];
    for (int i = threadIdx.x; i < F; i += 256) { lsum[i] = 0.f; lsq[i] = 0.f; }
    __syncthreads();
    int fl = threadIdx.x % TPR, rl = threadIdx.x / TPR;
    int f0 = fl * 8;
    float s[8] = {}, s2[8] = {};
    for (int n = blockIdx.x * RPB + rl; n < NN; n += gridDim.x * RPB) {
        u16x8 v = *(const u16x8*)&x[(size_t)n * F + f0];
#pragma unroll
        for (int j = 0; j < 8; ++j) { float f = bf2f(v[j]); s[j] += f; s2[j] += f * f; }
    }
#pragma unroll
    for (int off = TPR; off < 64; off <<= 1)
#pragma unroll
        for (int j = 0; j < 8; ++j) { s[j] += __shfl_xor(s[j], off); s2[j] += __shfl_xor(s2[j], off); }
    if ((threadIdx.x & 63) < TPR) {
#pragma unroll
        for (int j = 0; j < 8; ++j) {
            atomicAdd(&lsum[f0 + j], s[j]);
            atomicAdd(&lsq[f0 + j], s2[j]);
        }
    }
    __syncthreads();
    for (int i = threadIdx.x; i < F; i += 256) {
        atomicAdd(&sums[i], lsum[i]);
        atomicAdd(&sums[F + i], lsq[i]);
    }
}

// ACT: 1 relu, 2 elu. bf16 in/out.
template <int F, int ACT>
__global__ void k_bn_apply(const unsigned short* __restrict__ x, const float* __restrict__ sums,
                           const float* __restrict__ gamma, const float* __restrict__ beta,
                           unsigned short* __restrict__ out) {
    int idx = blockIdx.x * 256 + threadIdx.x;   // units of 8 elems
    if (idx >= NN * F / 8) return;
    int f0 = (idx % (F / 8)) * 8;
    u16x8 v = *(const u16x8*)&x[(size_t)idx * 8];
    u16x8 o;
#pragma unroll
    for (int j = 0; j < 8; ++j) {
        int f = f0 + j;
        float mean = sums[f] * (1.0f / NN);
        float var = sums[F + f] * (1.0f / NN) - mean * mean;
        float rstd = rsqrtf(var + BN_EPS);
        float val = (bf2f(v[j]) - mean) * rstd * gamma[f] + beta[f];
        if (ACT == 1) val = fmaxf(val, 0.f);
        if (ACT == 2) val = (val > 0.f) ? val : expm1f(val);
        o[j] = f2bf(val);
    }
    *(u16x8*)&out[(size_t)idx * 8] = o;
}

// ---------------- pooling / fusion ----------------
__global__ void k_pool(const unsigned short* __restrict__ x, const int* __restrict__ batch,
                       float* __restrict__ pooled, int off) {
    int f = threadIdx.x & 127;
    int half = threadIdx.x >> 7;
    int nend = min(NN, (int)(blockIdx.x + 1) * 128);
    float acc = 0.f; int gcur = -1;
    for (int n = blockIdx.x * 128 + half; n < nend; n += 2) {
        int g = batch[n];
        if (g != gcur) {
            if (gcur >= 0) atomicAdd(&pooled[(size_t)gcur * 384 + off + f], acc);
            gcur = g; acc = 0.f;
        }
        acc += bf2f(x[(size_t)n * 128 + f]);
    }
    if (gcur >= 0) atomicAdd(&pooled[(size_t)gcur * 384 + off + f], acc);
}

__global__ void k_fusion(const float* __restrict__ pooled, const float* __restrict__ cntG,
                         const float* __restrict__ W, const float* __restrict__ b,
                         float* __restrict__ out) {
    int idx = blockIdx.x * 256 + threadIdx.x;   // NG*128
    if (idx >= NG * 128) return;
    int g = idx / 128, o = idx % 128;
    float inv = 1.0f / fmaxf(cntG[g], 1.0f);
    float acc = b[o];
#pragma unroll 4
    for (int k = 0; k < 384; ++k)
        acc += pooled[g * 384 + k] * inv * W[k * 128 + o];
    out[idx] = acc;
}

// ---------------- launcher ----------------
static inline int grid1(long long n) { return (int)((n + 255) / 256); }

extern "C" void kernel_launch(void* const* d_in, const int* in_sizes, int n_in,
                              void* d_out, int out_size, void* d_ws, size_t ws_size,
                              hipStream_t stream) {
    const float* x       = (const float*)d_in[0];
    const int*   ei      = (const int*)d_in[1];
    const int*   batch   = (const int*)d_in[2];
    const float* gcn_W0  = (const float*)d_in[3];
    const float* gcn_W1  = (const float*)d_in[5];
    const float* gcn_W2  = (const float*)d_in[7];
    const float* gcn_b2  = (const float*)d_in[8];
    const float* gcn_g0  = (const float*)d_in[9];
    const float* gcn_bb0 = (const float*)d_in[10];
    const float* gcn_g1  = (const float*)d_in[11];
    const float* gcn_bb1 = (const float*)d_in[12];
    const float* gat_W0  = (const float*)d_in[13];
    const float* gat_as0 = (const float*)d_in[14];
    const float* gat_ad0 = (const float*)d_in[15];
    const float* gat_W1  = (const float*)d_in[17];
    const float* gat_as1 = (const float*)d_in[18];
    const float* gat_ad1 = (const float*)d_in[19];
    const float* gat_W2  = (const float*)d_in[21];
    const float* gat_as2 = (const float*)d_in[22];
    const float* gat_ad2 = (const float*)d_in[23];
    const float* gat_b2  = (const float*)d_in[24];
    const float* gat_g0  = (const float*)d_in[25];
    const float* gat_bb0 = (const float*)d_in[26];
    const float* gat_g1  = (const float*)d_in[27];
    const float* gat_bb1 = (const float*)d_in[28];
    const float* sage_Wl0 = (const float*)d_in[29];
    const float* sage_Wr0 = (const float*)d_in[30];
    const float* sage_Wl1 = (const float*)d_in[32];
    const float* sage_Wr1 = (const float*)d_in[33];
    const float* sage_Wl2 = (const float*)d_in[35];
    const float* sage_Wr2 = (const float*)d_in[36];
    const float* sage_b2  = (const float*)d_in[37];
    const float* sage_g0  = (const float*)d_in[38];
    const float* sage_bb0 = (const float*)d_in[39];
    const float* sage_g1  = (const float*)d_in[40];
    const float* sage_bb1 = (const float*)d_in[41];
    const float* fus_W    = (const float*)d_in[42];
    const float* fus_b    = (const float*)d_in[43];

    const int* src = ei;
    const int* dst = ei + NE;

    // workspace layout (float units, 16B-aligned chunks)
    float* ws = (float*)d_ws;
    size_t off = 0;
    auto alloc = [&](size_t n) { float* p = ws + off; off += (n + 3) & ~(size_t)3; return p; };
    unsigned short* xb    = (unsigned short*)alloc((size_t)NN * 64);   // NN*128 bf16
    unsigned short* bufAb = (unsigned short*)alloc((size_t)NN * 64);
    unsigned short* bufBb = (unsigned short*)alloc((size_t)NN * 64);
    unsigned short* bufCb = (unsigned short*)alloc((size_t)NN * 64);
    unsigned short* wt    = (unsigned short*)alloc(110592 / 2);        // 12 transposed bf16 weights
    int*   indeg    = (int*)alloc(NN);
    int*   rowstart = (int*)alloc(NN + 1);
    int*   cursor   = (int*)alloc(NN);
    int*   csr_src  = (int*)alloc(NE);
    int*   bsum     = (int*)alloc(NB);
    int*   boff     = (int*)alloc(NB);
    float* dis   = alloc(NN);
    float* alsrc = alloc((size_t)NN * 2);
    float* aldst = alloc((size_t)NN * 2);
    float* bnsum = alloc(6 * 256);
    float* pooled = alloc((size_t)NG * 384);   // cntG appended right after
    float* cntG  = alloc((size_t)NG);
    (void)ws_size; (void)n_in; (void)in_sizes; (void)out_size;

    // transposed weight offsets (elements)
    unsigned short* gcn_W0t  = wt;                 // 128x64  -> 8192
    unsigned short* gcn_W1t  = gcn_W0t + 8192;     // 64x64   -> 4096
    unsigned short* gcn_W2t  = gcn_W1t + 4096;     // 64x128  -> 8192
    unsigned short* gat_W0t  = gcn_W2t + 8192;     // 128x128 -> 16384
    unsigned short* gat_W1t  = gat_W0t + 16384;
    unsigned short* gat_W2t  = gat_W1t + 16384;
    unsigned short* sage_Wl0t = gat_W2t + 16384;   // 128x64
    unsigned short* sage_Wr0t = sage_Wl0t + 8192;
    unsigned short* sage_Wl1t = sage_Wr0t + 8192;  // 64x64
    unsigned short* sage_Wr1t = sage_Wl1t + 4096;
    unsigned short* sage_Wl2t = sage_Wr1t + 4096;  // 64x128
    unsigned short* sage_Wr2t = sage_Wl2t + 8192;

    const int gAgg = NN / 4;          // wave-per-node kernels
    const int gMM  = (NN + 63) / 64;  // 16-row wave tiles, 4 waves/block

    // ---- CSR build + precompute ----
    hipMemsetAsync(indeg, 0, NN * 4, stream);
    hipMemsetAsync(pooled, 0, (NG * 384 + NG) * 4, stream);   // pooled + cntG
    hipMemsetAsync(bnsum, 0, 6 * 256 * 4, stream);
    k_indeg<<<grid1(NE), 256, 0, stream>>>(dst, indeg);
    k_scan1<<<NB, 256, 0, stream>>>(indeg, rowstart, bsum, dis);
    k_scan2<<<1, 256, 0, stream>>>(bsum, boff);
    k_scan3<<<NB, 256, 0, stream>>>(rowstart, boff, cursor);
    k_fill<<<grid1(NE), 256, 0, stream>>>(src, dst, cursor, csr_src);
    k_count<<<128, 256, 0, stream>>>(batch, cntG);
    k_convx<<<grid1(NN * 16), 256, 0, stream>>>(x, xb);
    WTable wtab = {{
        { gcn_W0, gcn_W0t, 128, 64 }, { gcn_W1, gcn_W1t, 64, 64 }, { gcn_W2, gcn_W2t, 64, 128 },
        { gat_W0, gat_W0t, 128, 128 }, { gat_W1, gat_W1t, 128, 128 }, { gat_W2, gat_W2t, 128, 128 },
        { sage_Wl0, sage_Wl0t, 128, 64 }, { sage_Wr0, sage_Wr0t, 128, 64 },
        { sage_Wl1, sage_Wl1t, 64, 64 }, { sage_Wr1, sage_Wr1t, 64, 64 },
        { sage_Wl2, sage_Wl2t, 64, 128 }, { sage_Wr2, sage_Wr2t, 64, 128 },
    }};
    k_convw<<<12, 256, 0, stream>>>(wtab);

    // ================= GCN =================
    k_mm<128, 64, false, false, false, 0><<<gMM, 256, 0, stream>>>(
        xb, gcn_W0t, nullptr, nullptr, nullptr, nullptr, nullptr, nullptr, nullptr, nullptr, bufAb);
    k_gcn_agg<64, false><<<gAgg, 256, 0, stream>>>(rowstart, csr_src, dis, bufAb, nullptr, bufBb);
    k_bn_stats<64><<<120, 256, 0, stream>>>(bufBb, bnsum + 0 * 256);
    k_bn_apply<64, 1><<<grid1(NN * 8), 256, 0, stream>>>(bufBb, bnsum + 0 * 256, gcn_g0, gcn_bb0, bufBb);

    k_mm<64, 64, false, false, false, 0><<<gMM, 256, 0, stream>>>(
        bufBb, gcn_W1t, nullptr, nullptr, nullptr, nullptr, nullptr, nullptr, nullptr, nullptr, bufAb);
    k_gcn_agg<64, false><<<gAgg, 256, 0, stream>>>(rowstart, csr_src, dis, bufAb, nullptr, bufBb);
    k_bn_stats<64><<<120, 256, 0, stream>>>(bufBb, bnsum + 1 * 256);
    k_bn_apply<64, 1><<<grid1(NN * 8), 256, 0, stream>>>(bufBb, bnsum + 1 * 256, gcn_g1, gcn_bb1, bufBb);

    // L2: aggregate 64-dim first (commutes with W), then matmul+bias
    k_gcn_agg<64, false><<<gAgg, 256, 0, stream>>>(rowstart, csr_src, dis, bufBb, nullptr, bufAb);
    k_mm<64, 128, false, true, false, 0><<<gMM, 256, 0, stream>>>(
        bufAb, gcn_W2t, nullptr, nullptr, nullptr, gcn_b2, nullptr, nullptr, nullptr, nullptr, bufCb);
    k_pool<<<(NN + 127) / 128, 256, 0, stream>>>(bufCb, batch, pooled, 0);

    // ================= GAT =================
    k_mm<128, 128, false, false, false, 2><<<gMM, 256, 0, stream>>>(
        xb, gat_W0t, nullptr, nullptr, nullptr, nullptr, gat_as0, gat_ad0, alsrc, aldst, bufAb);
    k_gat_agg<2, 64, false><<<gAgg, 256, 0, stream>>>(rowstart, csr_src, alsrc, aldst, bufAb, nullptr, bufBb);
    k_bn_stats<128><<<120, 256, 0, stream>>>(bufBb, bnsum + 2 * 256);
    k_bn_apply<128, 2><<<grid1(NN * 16), 256, 0, stream>>>(bufBb, bnsum + 2 * 256, gat_g0, gat_bb0, bufBb);

    k_mm<128, 128, false, false, false, 2><<<gMM, 256, 0, stream>>>(
        bufBb, gat_W1t, nullptr, nullptr, nullptr, nullptr, gat_as1, gat_ad1, alsrc, aldst, bufAb);
    k_gat_agg<2, 64, false><<<gAgg, 256, 0, stream>>>(rowstart, csr_src, alsrc, aldst, bufAb, nullptr, bufBb);
    k_bn_stats<128><<<120, 256, 0, stream>>>(bufBb, bnsum + 3 * 256);
    k_bn_apply<128, 2><<<grid1(NN * 16), 256, 0, stream>>>(bufBb, bnsum + 3 * 256, gat_g1, gat_bb1, bufBb);

    k_mm<128, 128, false, false, false, 1><<<gMM, 256, 0, stream>>>(
        bufBb, gat_W2t, nullptr, nullptr, nullptr, nullptr, gat_as2, gat_ad2, alsrc, aldst, bufAb);
    k_gat_agg<1, 128, true><<<gAgg, 256, 0, stream>>>(rowstart, csr_src, alsrc, aldst, bufAb, gat_b2, bufBb);
    k_pool<<<(NN + 127) / 128, 256, 0, stream>>>(bufBb, batch, pooled, 128);

    // ================= SAGE =================
    // L0: matmul to 64-d first, aggregate small, add x@Wr
    k_mm<128, 64, false, false, false, 0><<<gMM, 256, 0, stream>>>(
        xb, sage_Wl0t, nullptr, nullptr, nullptr, nullptr, nullptr, nullptr, nullptr, nullptr, bufCb);
    k_sage_agg<64><<<gAgg, 256, 0, stream>>>(rowstart, csr_src, bufCb, bufAb);
    k_mm<128, 64, false, false, true, 0><<<gMM, 256, 0, stream>>>(
        xb, sage_Wr0t, nullptr, nullptr, bufAb, nullptr, nullptr, nullptr, nullptr, nullptr, bufCb);
    k_bn_stats<64><<<120, 256, 0, stream>>>(bufCb, bnsum + 4 * 256);
    k_bn_apply<64, 1><<<grid1(NN * 8), 256, 0, stream>>>(bufCb, bnsum + 4 * 256, sage_g0, sage_bb0, bufBb);

    k_sage_agg<64><<<gAgg, 256, 0, stream>>>(rowstart, csr_src, bufBb, bufAb);
    k_mm<64, 64, true, false, false, 0><<<gMM, 256, 0, stream>>>(
        bufAb, sage_Wl1t, bufBb, sage_Wr1t, nullptr, nullptr, nullptr, nullptr, nullptr, nullptr, bufCb);
    k_bn_stats<64><<<120, 256, 0, stream>>>(bufCb, bnsum + 5 * 256);
    k_bn_apply<64, 1><<<grid1(NN * 8), 256, 0, stream>>>(bufCb, bnsum + 5 * 256, sage_g1, sage_bb1, bufBb);

    k_sage_agg<64><<<gAgg, 256, 0, stream>>>(rowstart, csr_src, bufBb, bufAb);
    k_mm<64, 128, true, true, false, 0><<<gMM, 256, 0, stream>>>(
        bufAb, sage_Wl2t, bufBb, sage_Wr2t, nullptr, sage_b2, nullptr, nullptr, nullptr, nullptr, bufCb);
    k_pool<<<(NN + 127) / 128, 256, 0, stream>>>(bufCb, batch, pooled, 256);

    // ================= fusion =================
    k_fusion<<<grid1(NG * 128), 256, 0, stream>>>(pooled, cntG, fus_W, fus_b, (float*)d_out);
}

// Round 6
// 761.666 us; speedup vs baseline: 5.7510x; 1.0789x over previous
//
#include <hip/hip_runtime.h>

#define NN 50000
#define NE 800000
#define NG 50
#define NB 196   // ceil(NN/256)

static constexpr float BN_EPS = 1e-5f;

typedef __attribute__((ext_vector_type(8))) short  bf16x8;
typedef __attribute__((ext_vector_type(8))) unsigned short u16x8;
typedef __attribute__((ext_vector_type(4))) float  f32x4;

// ---------------- bf16 helpers ----------------
__device__ __forceinline__ float bf2f(unsigned short u) {
    return __uint_as_float(((unsigned)u) << 16);
}
__device__ __forceinline__ unsigned short f2bf(float f) {
    unsigned u = __float_as_uint(f);
    unsigned r = (u + 0x7fffu + ((u >> 16) & 1u)) >> 16;   // RNE
    return (unsigned short)r;
}

// ---------------- degree / CSR build ----------------
__global__ void k_indeg(const int* __restrict__ dst, int* __restrict__ indeg) {
    int e = blockIdx.x * 256 + threadIdx.x;
    if (e < NE) atomicAdd(&indeg[dst[e]], 1);
}

// block-local exclusive scan + dis computation
__global__ void k_scan1(const int* __restrict__ cnt, int* __restrict__ rowstart,
                        int* __restrict__ bsum, float* __restrict__ dis) {
    int i = blockIdx.x * 256 + threadIdx.x;
    int lane = threadIdx.x & 63, wv = threadIdx.x >> 6;
    int v = (i < NN) ? cnt[i] : 0;
    if (i < NN) dis[i] = rsqrtf((float)v + 1.0f);
    int s = v;
#pragma unroll
    for (int d = 1; d < 64; d <<= 1) {
        int t = __shfl_up(s, d);
        if (lane >= d) s += t;
    }
    __shared__ int wtot[4];
    if (lane == 63) wtot[wv] = s;
    __syncthreads();
    int woff = 0;
    for (int w = 0; w < wv; ++w) woff += wtot[w];
    if (i < NN) rowstart[i] = woff + s - v;
    if (threadIdx.x == 255) bsum[blockIdx.x] = woff + s;
}

__global__ void k_scan2(const int* __restrict__ bsum, int* __restrict__ boff) {
    int lane = threadIdx.x & 63, wv = threadIdx.x >> 6;
    int v = (threadIdx.x < NB) ? bsum[threadIdx.x] : 0;
    int s = v;
#pragma unroll
    for (int d = 1; d < 64; d <<= 1) {
        int t = __shfl_up(s, d);
        if (lane >= d) s += t;
    }
    __shared__ int wtot[4];
    if (lane == 63) wtot[wv] = s;
    __syncthreads();
    int woff = 0;
    for (int w = 0; w < wv; ++w) woff += wtot[w];
    if (threadIdx.x < NB) boff[threadIdx.x] = woff + s - v;
}

__global__ void k_scan3(int* __restrict__ rowstart, const int* __restrict__ boff,
                        int* __restrict__ cursor) {
    int i = blockIdx.x * 256 + threadIdx.x;
    if (i < NN) {
        int v = rowstart[i] + boff[blockIdx.x];
        rowstart[i] = v;
        cursor[i] = v;
    }
    if (i == 0) rowstart[NN] = NE;
}

__global__ void k_fill(const int* __restrict__ src, const int* __restrict__ dst,
                       int* __restrict__ cursor, int* __restrict__ csr_src) {
    int e = blockIdx.x * 256 + threadIdx.x;
    if (e < NE) {
        int pos = atomicAdd(&cursor[dst[e]], 1);
        csr_src[pos] = src[e];
    }
}

// pack {src, dis[src]} per CSR slot for shfl-free GCN/SAGE inner loops
__global__ void k_pack(const int* __restrict__ csr_src, const float* __restrict__ dis,
                       int2* __restrict__ pair) {
    int e = blockIdx.x * 256 + threadIdx.x;
    if (e < NE) {
        int s = csr_src[e];
        pair[e] = make_int2(s, __float_as_int(dis[s]));
    }
}

__global__ void k_count(const int* __restrict__ batch, float* __restrict__ cntG) {
    __shared__ int hist[NG];
    for (int i = threadIdx.x; i < NG; i += 256) hist[i] = 0;
    __syncthreads();
    for (int n = blockIdx.x * 256 + threadIdx.x; n < NN; n += gridDim.x * 256)
        atomicAdd(&hist[batch[n]], 1);
    __syncthreads();
    for (int i = threadIdx.x; i < NG; i += 256)
        if (hist[i]) atomicAdd(&cntG[i], (float)hist[i]);
}

// ---------------- conversions ----------------
__global__ void k_convx(const float* __restrict__ x, unsigned short* __restrict__ xb) {
    int i = blockIdx.x * 256 + threadIdx.x;   // units of 8 elems
    if (i >= NN * 128 / 8) return;
    float4 v0 = ((const float4*)x)[i * 2];
    float4 v1 = ((const float4*)x)[i * 2 + 1];
    u16x8 o;
    o[0] = f2bf(v0.x); o[1] = f2bf(v0.y); o[2] = f2bf(v0.z); o[3] = f2bf(v0.w);
    o[4] = f2bf(v1.x); o[5] = f2bf(v1.y); o[6] = f2bf(v1.z); o[7] = f2bf(v1.w);
    ((u16x8*)xb)[i] = o;
}

struct WDesc { const float* s; unsigned short* d; int fin; int fout; };
struct WTable { WDesc w[12]; };

// convert + transpose: dst[c*fin + k] = bf16(src[k*fout + c])
__global__ void k_convw(WTable t) {
    WDesc wd = t.w[blockIdx.x];
    int total = wd.fin * wd.fout;
    for (int i = threadIdx.x; i < total; i += 256) {
        int c = i / wd.fin, k = i % wd.fin;
        wd.d[i] = f2bf(wd.s[(size_t)k * wd.fout + c]);
    }
}

// ---------------- MFMA matmul ----------------
// out = A1@W1t (+A2@W2t) (+ADD) (+bias); optional GAT al epilogue (ALH heads)
template <int FIN, int FOUT, bool DUAL, bool BIAS, bool ADDIN, int ALH>
__global__ __launch_bounds__(256) void k_mm(
        const unsigned short* __restrict__ A1, const unsigned short* __restrict__ W1t,
        const unsigned short* __restrict__ A2, const unsigned short* __restrict__ W2t,
        const unsigned short* __restrict__ ADD, const float* __restrict__ bias,
        const float* __restrict__ as_, const float* __restrict__ ad_,
        float* __restrict__ alsrc, float* __restrict__ aldst,
        unsigned short* __restrict__ out) {
    constexpr int NCT = FOUT / 16;
    int wave = threadIdx.x >> 6, lane = threadIdx.x & 63;
    int rowbase = (blockIdx.x * 4 + wave) * 16;
    if (rowbase >= NN) return;
    int lr = lane & 15, lg = lane >> 4;
    int arow = rowbase + lr;
    f32x4 acc[NCT] = {};
    const unsigned short* a1p = A1 + (size_t)arow * FIN + lg * 8;
    const unsigned short* a2p = DUAL ? (A2 + (size_t)arow * FIN + lg * 8) : nullptr;
#pragma unroll
    for (int k0 = 0; k0 < FIN; k0 += 32) {
        bf16x8 a1 = *(const bf16x8*)(a1p + k0);
        bf16x8 a2v = {};
        if (DUAL) a2v = *(const bf16x8*)(a2p + k0);
#pragma unroll
        for (int ct = 0; ct < NCT; ++ct) {
            int wcol = ct * 16 + lr;
            bf16x8 b1 = *(const bf16x8*)(W1t + (size_t)wcol * FIN + k0 + lg * 8);
            acc[ct] = __builtin_amdgcn_mfma_f32_16x16x32_bf16(a1, b1, acc[ct], 0, 0, 0);
            if (DUAL) {
                bf16x8 b2 = *(const bf16x8*)(W2t + (size_t)wcol * FIN + k0 + lg * 8);
                acc[ct] = __builtin_amdgcn_mfma_f32_16x16x32_bf16(a2v, b2, acc[ct], 0, 0, 0);
            }
        }
    }
    if (ADDIN) {
#pragma unroll
        for (int ct = 0; ct < NCT; ++ct) {
            int col = ct * 16 + lr;
#pragma unroll
            for (int j = 0; j < 4; ++j) {
                int row = rowbase + lg * 4 + j;
                acc[ct][j] += bf2f(ADD[(size_t)row * FOUT + col]);
            }
        }
    }
    // GAT attention-logit epilogue (on pre-bias h)
    if (ALH > 0) {
        constexpr int NH = (ALH > 0) ? ALH : 1;
        float ps[NH][4] = {}, pd[NH][4] = {};
#pragma unroll
        for (int ct = 0; ct < NCT; ++ct) {
            int hh = (ALH == 2 && ct >= NCT / 2) ? 1 : 0;
            int col = ct * 16 + lr;
            float cs = as_[col], cd = ad_[col];
#pragma unroll
            for (int j = 0; j < 4; ++j) {
                ps[hh][j] += acc[ct][j] * cs;
                pd[hh][j] += acc[ct][j] * cd;
            }
        }
#pragma unroll
        for (int m = 1; m < 16; m <<= 1) {
#pragma unroll
            for (int hh = 0; hh < NH; ++hh)
#pragma unroll
                for (int j = 0; j < 4; ++j) {
                    ps[hh][j] += __shfl_xor(ps[hh][j], m);
                    pd[hh][j] += __shfl_xor(pd[hh][j], m);
                }
        }
        if (lr == 0) {
#pragma unroll
            for (int j = 0; j < 4; ++j) {
                int row = rowbase + lg * 4 + j;
#pragma unroll
                for (int hh = 0; hh < NH; ++hh) {
                    alsrc[(size_t)row * ALH + hh] = ps[hh][j];
                    aldst[(size_t)row * ALH + hh] = pd[hh][j];
                }
            }
        }
    }
#pragma unroll
    for (int ct = 0; ct < NCT; ++ct) {
        int col = ct * 16 + lr;
        float bv = BIAS ? bias[col] : 0.f;
#pragma unroll
        for (int j = 0; j < 4; ++j) {
            int row = rowbase + lg * 4 + j;
            out[(size_t)row * FOUT + col] = f2bf(acc[ct][j] + bv);
        }
    }
}

// ---------------- GCN aggregation (CSR, wave/node, shfl-free) ----------
template <int F, bool BIAS>
__global__ __launch_bounds__(256) void k_gcn_agg(
        const int* __restrict__ rowstart, const int2* __restrict__ pair,
        const float* __restrict__ dis, const unsigned short* __restrict__ h,
        const float* __restrict__ bias, unsigned short* __restrict__ out) {
    constexpr int LPE = F / 8;
    constexpr int EPW = 64 / LPE;
    int wave = threadIdx.x >> 6, lane = threadIdx.x & 63;
    int n = blockIdx.x * 4 + wave;
    if (n >= NN) return;
    int r0 = rowstart[n], r1 = rowstart[n + 1];
    float dn = dis[n];
    int fl = lane % LPE, eg = lane / LPE;
    int f0 = fl * 8;
    float acc[8] = {};
    if (eg == 0) {
        u16x8 hv = *(const u16x8*)&h[(size_t)n * F + f0];
        float c = dn * dn;
#pragma unroll
        for (int j = 0; j < 8; ++j) acc[j] = c * bf2f(hv[j]);
    }
#pragma unroll 4
    for (int e = r0 + eg; e < r1; e += EPW) {
        int2 p = pair[e];
        float c = __int_as_float(p.y) * dn;
        u16x8 hs = *(const u16x8*)&h[(size_t)p.x * F + f0];
#pragma unroll
        for (int jj = 0; jj < 8; ++jj) acc[jj] += c * bf2f(hs[jj]);
    }
#pragma unroll
    for (int off = LPE; off < 64; off <<= 1)
#pragma unroll
        for (int jj = 0; jj < 8; ++jj) acc[jj] += __shfl_xor(acc[jj], off);
    if (eg == 0) {
        u16x8 o;
#pragma unroll
        for (int jj = 0; jj < 8; ++jj) {
            float v = acc[jj];
            if (BIAS) v += bias[f0 + jj];
            o[jj] = f2bf(v);
        }
        *(u16x8*)&out[(size_t)n * F + f0] = o;
    }
}

// ---------------- SAGE mean aggregation (CSR, shfl-free) ----------------
template <int F>
__global__ __launch_bounds__(256) void k_sage_agg(
        const int* __restrict__ rowstart, const int2* __restrict__ pair,
        const unsigned short* __restrict__ h, unsigned short* __restrict__ out) {
    constexpr int LPE = F / 8;
    constexpr int EPW = 64 / LPE;
    int wave = threadIdx.x >> 6, lane = threadIdx.x & 63;
    int n = blockIdx.x * 4 + wave;
    if (n >= NN) return;
    int r0 = rowstart[n], r1 = rowstart[n + 1];
    int fl = lane % LPE, eg = lane / LPE;
    int f0 = fl * 8;
    float acc[8] = {};
#pragma unroll 4
    for (int e = r0 + eg; e < r1; e += EPW) {
        int2 p = pair[e];
        u16x8 hs = *(const u16x8*)&h[(size_t)p.x * F + f0];
#pragma unroll
        for (int jj = 0; jj < 8; ++jj) acc[jj] += bf2f(hs[jj]);
    }
#pragma unroll
    for (int off = LPE; off < 64; off <<= 1)
#pragma unroll
        for (int jj = 0; jj < 8; ++jj) acc[jj] += __shfl_xor(acc[jj], off);
    if (eg == 0) {
        float inv = 1.0f / fmaxf((float)(r1 - r0), 1.0f);
        u16x8 o;
#pragma unroll
        for (int jj = 0; jj < 8; ++jj) o[jj] = f2bf(acc[jj] * inv);
        *(u16x8*)&out[(size_t)n * F + f0] = o;
    }
}

// ---------------- GAT: single-pass softmax + gather, shfl-free inner -------
// Each lane computes its own head's edge weight (redundant across the C/8
// lanes of an edge-group; denominator recovered by masked butterfly + exact /8 or /16).
template <int H, int C, bool BIAS>
__global__ __launch_bounds__(256) void k_gat_agg(
        const int* __restrict__ rowstart, const int* __restrict__ csr_src,
        const float* __restrict__ alsrc, const float* __restrict__ aldst,
        const unsigned short* __restrict__ h, const float* __restrict__ bias,
        unsigned short* __restrict__ out) {
    constexpr int HC = H * C;      // 128
    constexpr int LPE = HC / 8;    // 16
    constexpr int EPW = 64 / LPE;  // 4
    constexpr int HL = C / 8;      // lanes per head within a group (8 or 16)
    int wave = threadIdx.x >> 6, lane = threadIdx.x & 63;
    int n = blockIdx.x * 4 + wave;
    if (n >= NN) return;
    int r0 = rowstart[n], r1 = rowstart[n + 1];
    int fl = lane % LPE, eg = lane / LPE;
    int f0 = fl * 8;
    int hh = (H > 1) ? (fl / HL) : 0;
    float adn = aldst[n * H + hh];
    float t = alsrc[n * H + hh] + adn;
    float ws = __expf((t >= 0.f) ? t : 0.2f * t);   // self weight (my head)
    float acc[8] = {};
    float dsum = 0.f;
    if (eg == 0) {
        u16x8 hv = *(const u16x8*)&h[(size_t)n * HC + f0];
#pragma unroll
        for (int j = 0; j < 8; ++j) acc[j] = ws * bf2f(hv[j]);
    }
#pragma unroll 4
    for (int e = r0 + eg; e < r1; e += EPW) {
        int s = csr_src[e];
        float al = alsrc[(size_t)s * H + hh];
        float v = al + adn;
        v = (v >= 0.f) ? v : 0.2f * v;
        float w = __expf(v);
        dsum += w;
        u16x8 hs = *(const u16x8*)&h[(size_t)s * HC + f0];
#pragma unroll
        for (int jj = 0; jj < 8; ++jj) acc[jj] += w * bf2f(hs[jj]);
    }
    // denominator: sum over same-head lanes (each edge counted HL times)
    if (H > 1) {
#pragma unroll
        for (int off = 1; off < HL; off <<= 1) dsum += __shfl_xor(dsum, off);   // {1,2,4}
#pragma unroll
        for (int off = LPE; off < 64; off <<= 1) dsum += __shfl_xor(dsum, off); // {16,32}
    } else {
#pragma unroll
        for (int off = 1; off < 64; off <<= 1) dsum += __shfl_xor(dsum, off);
    }
    float den = ws + dsum * (1.0f / HL);
    float dinv = 1.0f / (den + 1e-16f);
    // feature reduce across edge-groups
#pragma unroll
    for (int off = LPE; off < 64; off <<= 1)
#pragma unroll
        for (int jj = 0; jj < 8; ++jj) acc[jj] += __shfl_xor(acc[jj], off);
    if (eg == 0) {
        u16x8 o;
#pragma unroll
        for (int jj = 0; jj < 8; ++jj) {
            float v = acc[jj] * dinv;
            if (BIAS) v += bias[f0 + jj];
            o[jj] = f2bf(v);
        }
        *(u16x8*)&out[(size_t)n * HC + f0] = o;
    }
}

// ---------------- BatchNorm (bf16 in, stats fp32) ----------------
template <int F>
__global__ void k_bn_stats(const unsigned short* __restrict__ x, float* __restrict__ sums) {
    constexpr int TPR = F / 8;
    constexpr int RPB = 256 / TPR;
    __shared__ float lsum[F], lsq[F];
    for (int i = threadIdx.x; i < F; i += 256) { lsum[i] = 0.f; lsq[i] = 0.f; }
    __syncthreads();
    int fl = threadIdx.x % TPR, rl = threadIdx.x / TPR;
    int f0 = fl * 8;
    float s[8] = {}, s2[8] = {};
    for (int n = blockIdx.x * RPB + rl; n < NN; n += gridDim.x * RPB) {
        u16x8 v = *(const u16x8*)&x[(size_t)n * F + f0];
#pragma unroll
        for (int j = 0; j < 8; ++j) { float f = bf2f(v[j]); s[j] += f; s2[j] += f * f; }
    }
#pragma unroll
    for (int off = TPR; off < 64; off <<= 1)
#pragma unroll
        for (int j = 0; j < 8; ++j) { s[j] += __shfl_xor(s[j], off); s2[j] += __shfl_xor(s2[j], off); }
    if ((threadIdx.x & 63) < TPR) {
#pragma unroll
        for (int j = 0; j < 8; ++j) {
            atomicAdd(&lsum[f0 + j], s[j]);
            atomicAdd(&lsq[f0 + j], s2[j]);
        }
    }
    __syncthreads();
    for (int i = threadIdx.x; i < F; i += 256) {
        atomicAdd(&sums[i], lsum[i]);
        atomicAdd(&sums[F + i], lsq[i]);
    }
}

// ACT: 1 relu, 2 elu. bf16 in/out.
template <int F, int ACT>
__global__ void k_bn_apply(const unsigned short* __restrict__ x, const float* __restrict__ sums,
                           const float* __restrict__ gamma, const float* __restrict__ beta,
                           unsigned short* __restrict__ out) {
    int idx = blockIdx.x * 256 + threadIdx.x;   // units of 8 elems
    if (idx >= NN * F / 8) return;
    int f0 = (idx % (F / 8)) * 8;
    u16x8 v = *(const u16x8*)&x[(size_t)idx * 8];
    u16x8 o;
#pragma unroll
    for (int j = 0; j < 8; ++j) {
        int f = f0 + j;
        float mean = sums[f] * (1.0f / NN);
        float var = sums[F + f] * (1.0f / NN) - mean * mean;
        float rstd = rsqrtf(var + BN_EPS);
        float val = (bf2f(v[j]) - mean) * rstd * gamma[f] + beta[f];
        if (ACT == 1) val = fmaxf(val, 0.f);
        if (ACT == 2) val = (val > 0.f) ? val : (__expf(val) - 1.0f);
        o[j] = f2bf(val);
    }
    *(u16x8*)&out[(size_t)idx * 8] = o;
}

// ---------------- pooling / fusion ----------------
__global__ void k_pool(const unsigned short* __restrict__ x, const int* __restrict__ batch,
                       float* __restrict__ pooled, int off) {
    int f = threadIdx.x & 127;
    int half = threadIdx.x >> 7;
    int nend = min(NN, (int)(blockIdx.x + 1) * 128);
    float acc = 0.f; int gcur = -1;
    for (int n = blockIdx.x * 128 + half; n < nend; n += 2) {
        int g = batch[n];
        if (g != gcur) {
            if (gcur >= 0) atomicAdd(&pooled[(size_t)gcur * 384 + off + f], acc);
            gcur = g; acc = 0.f;
        }
        acc += bf2f(x[(size_t)n * 128 + f]);
    }
    if (gcur >= 0) atomicAdd(&pooled[(size_t)gcur * 384 + off + f], acc);
}

__global__ void k_fusion(const float* __restrict__ pooled, const float* __restrict__ cntG,
                         const float* __restrict__ W, const float* __restrict__ b,
                         float* __restrict__ out) {
    int idx = blockIdx.x * 256 + threadIdx.x;   // NG*128
    if (idx >= NG * 128) return;
    int g = idx / 128, o = idx % 128;
    float inv = 1.0f / fmaxf(cntG[g], 1.0f);
    float acc = b[o];
#pragma unroll 4
    for (int k = 0; k < 384; ++k)
        acc += pooled[g * 384 + k] * inv * W[k * 128 + o];
    out[idx] = acc;
}

// ---------------- launcher ----------------
static inline int grid1(long long n) { return (int)((n + 255) / 256); }

extern "C" void kernel_launch(void* const* d_in, const int* in_sizes, int n_in,
                              void* d_out, int out_size, void* d_ws, size_t ws_size,
                              hipStream_t stream) {
    const float* x       = (const float*)d_in[0];
    const int*   ei      = (const int*)d_in[1];
    const int*   batch   = (const int*)d_in[2];
    const float* gcn_W0  = (const float*)d_in[3];
    const float* gcn_W1  = (const float*)d_in[5];
    const float* gcn_W2  = (const float*)d_in[7];
    const float* gcn_b2  = (const float*)d_in[8];
    const float* gcn_g0  = (const float*)d_in[9];
    const float* gcn_bb0 = (const float*)d_in[10];
    const float* gcn_g1  = (const float*)d_in[11];
    const float* gcn_bb1 = (const float*)d_in[12];
    const float* gat_W0  = (const float*)d_in[13];
    const float* gat_as0 = (const float*)d_in[14];
    const float* gat_ad0 = (const float*)d_in[15];
    const float* gat_W1  = (const float*)d_in[17];
    const float* gat_as1 = (const float*)d_in[18];
    const float* gat_ad1 = (const float*)d_in[19];
    const float* gat_W2  = (const float*)d_in[21];
    const float* gat_as2 = (const float*)d_in[22];
    const float* gat_ad2 = (const float*)d_in[23];
    const float* gat_b2  = (const float*)d_in[24];
    const float* gat_g0  = (const float*)d_in[25];
    const float* gat_bb0 = (const float*)d_in[26];
    const float* gat_g1  = (const float*)d_in[27];
    const float* gat_bb1 = (const float*)d_in[28];
    const float* sage_Wl0 = (const float*)d_in[29];
    const float* sage_Wr0 = (const float*)d_in[30];
    const float* sage_Wl1 = (const float*)d_in[32];
    const float* sage_Wr1 = (const float*)d_in[33];
    const float* sage_Wl2 = (const float*)d_in[35];
    const float* sage_Wr2 = (const float*)d_in[36];
    const float* sage_b2  = (const float*)d_in[37];
    const float* sage_g0  = (const float*)d_in[38];
    const float* sage_bb0 = (const float*)d_in[39];
    const float* sage_g1  = (const float*)d_in[40];
    const float* sage_bb1 = (const float*)d_in[41];
    const float* fus_W    = (const float*)d_in[42];
    const float* fus_b    = (const float*)d_in[43];

    const int* src = ei;
    const int* dst = ei + NE;

    // workspace layout (float units, 16B-aligned chunks)
    float* ws = (float*)d_ws;
    size_t off = 0;
    auto alloc = [&](size_t n) { float* p = ws + off; off += (n + 3) & ~(size_t)3; return p; };
    unsigned short* xb    = (unsigned short*)alloc((size_t)NN * 64);   // NN*128 bf16
    unsigned short* bufAb = (unsigned short*)alloc((size_t)NN * 64);
    unsigned short* bufBb = (unsigned short*)alloc((size_t)NN * 64);
    unsigned short* bufCb = (unsigned short*)alloc((size_t)NN * 64);
    unsigned short* wt    = (unsigned short*)alloc(110592 / 2);        // 12 transposed bf16 weights
    int*   indeg    = (int*)alloc(NN);
    int*   rowstart = (int*)alloc(NN + 1);
    int*   cursor   = (int*)alloc(NN);
    int*   csr_src  = (int*)alloc(NE);
    int2*  pair     = (int2*)alloc((size_t)NE * 2);
    int*   bsum     = (int*)alloc(NB);
    int*   boff     = (int*)alloc(NB);
    float* dis   = alloc(NN);
    float* alsrc = alloc((size_t)NN * 2);
    float* aldst = alloc((size_t)NN * 2);
    float* bnsum = alloc(6 * 256);
    float* pooled = alloc((size_t)NG * 384);   // cntG appended right after
    float* cntG  = alloc((size_t)NG);
    (void)ws_size; (void)n_in; (void)in_sizes; (void)out_size;

    // transposed weight offsets (elements)
    unsigned short* gcn_W0t  = wt;                 // 128x64  -> 8192
    unsigned short* gcn_W1t  = gcn_W0t + 8192;     // 64x64   -> 4096
    unsigned short* gcn_W2t  = gcn_W1t + 4096;     // 64x128  -> 8192
    unsigned short* gat_W0t  = gcn_W2t + 8192;     // 128x128 -> 16384
    unsigned short* gat_W1t  = gat_W0t + 16384;
    unsigned short* gat_W2t  = gat_W1t + 16384;
    unsigned short* sage_Wl0t = gat_W2t + 16384;   // 128x64
    unsigned short* sage_Wr0t = sage_Wl0t + 8192;
    unsigned short* sage_Wl1t = sage_Wr0t + 8192;  // 64x64
    unsigned short* sage_Wr1t = sage_Wl1t + 4096;
    unsigned short* sage_Wl2t = sage_Wr1t + 4096;  // 64x128
    unsigned short* sage_Wr2t = sage_Wl2t + 8192;

    const int gAgg = NN / 4;          // wave-per-node kernels
    const int gMM  = (NN + 63) / 64;  // 16-row wave tiles, 4 waves/block

    // ---- CSR build + precompute ----
    hipMemsetAsync(indeg, 0, NN * 4, stream);
    hipMemsetAsync(pooled, 0, (NG * 384 + NG) * 4, stream);   // pooled + cntG
    hipMemsetAsync(bnsum, 0, 6 * 256 * 4, stream);
    k_indeg<<<grid1(NE), 256, 0, stream>>>(dst, indeg);
    k_scan1<<<NB, 256, 0, stream>>>(indeg, rowstart, bsum, dis);
    k_scan2<<<1, 256, 0, stream>>>(bsum, boff);
    k_scan3<<<NB, 256, 0, stream>>>(rowstart, boff, cursor);
    k_fill<<<grid1(NE), 256, 0, stream>>>(src, dst, cursor, csr_src);
    k_pack<<<grid1(NE), 256, 0, stream>>>(csr_src, dis, pair);
    k_count<<<128, 256, 0, stream>>>(batch, cntG);
    k_convx<<<grid1(NN * 16), 256, 0, stream>>>(x, xb);
    WTable wtab = {{
        { gcn_W0, gcn_W0t, 128, 64 }, { gcn_W1, gcn_W1t, 64, 64 }, { gcn_W2, gcn_W2t, 64, 128 },
        { gat_W0, gat_W0t, 128, 128 }, { gat_W1, gat_W1t, 128, 128 }, { gat_W2, gat_W2t, 128, 128 },
        { sage_Wl0, sage_Wl0t, 128, 64 }, { sage_Wr0, sage_Wr0t, 128, 64 },
        { sage_Wl1, sage_Wl1t, 64, 64 }, { sage_Wr1, sage_Wr1t, 64, 64 },
        { sage_Wl2, sage_Wl2t, 64, 128 }, { sage_Wr2, sage_Wr2t, 64, 128 },
    }};
    k_convw<<<12, 256, 0, stream>>>(wtab);

    // ================= GCN =================
    k_mm<128, 64, false, false, false, 0><<<gMM, 256, 0, stream>>>(
        xb, gcn_W0t, nullptr, nullptr, nullptr, nullptr, nullptr, nullptr, nullptr, nullptr, bufAb);
    k_gcn_agg<64, false><<<gAgg, 256, 0, stream>>>(rowstart, pair, dis, bufAb, nullptr, bufBb);
    k_bn_stats<64><<<250, 256, 0, stream>>>(bufBb, bnsum + 0 * 256);
    k_bn_apply<64, 1><<<grid1(NN * 8), 256, 0, stream>>>(bufBb, bnsum + 0 * 256, gcn_g0, gcn_bb0, bufBb);

    k_mm<64, 64, false, false, false, 0><<<gMM, 256, 0, stream>>>(
        bufBb, gcn_W1t, nullptr, nullptr, nullptr, nullptr, nullptr, nullptr, nullptr, nullptr, bufAb);
    k_gcn_agg<64, false><<<gAgg, 256, 0, stream>>>(rowstart, pair, dis, bufAb, nullptr, bufBb);
    k_bn_stats<64><<<250, 256, 0, stream>>>(bufBb, bnsum + 1 * 256);
    k_bn_apply<64, 1><<<grid1(NN * 8), 256, 0, stream>>>(bufBb, bnsum + 1 * 256, gcn_g1, gcn_bb1, bufBb);

    // L2: aggregate 64-dim first (commutes with W), then matmul+bias
    k_gcn_agg<64, false><<<gAgg, 256, 0, stream>>>(rowstart, pair, dis, bufBb, nullptr, bufAb);
    k_mm<64, 128, false, true, false, 0><<<gMM, 256, 0, stream>>>(
        bufAb, gcn_W2t, nullptr, nullptr, nullptr, gcn_b2, nullptr, nullptr, nullptr, nullptr, bufCb);
    k_pool<<<(NN + 127) / 128, 256, 0, stream>>>(bufCb, batch, pooled, 0);

    // ================= GAT =================
    k_mm<128, 128, false, false, false, 2><<<gMM, 256, 0, stream>>>(
        xb, gat_W0t, nullptr, nullptr, nullptr, nullptr, gat_as0, gat_ad0, alsrc, aldst, bufAb);
    k_gat_agg<2, 64, false><<<gAgg, 256, 0, stream>>>(rowstart, csr_src, alsrc, aldst, bufAb, nullptr, bufBb);
    k_bn_stats<128><<<250, 256, 0, stream>>>(bufBb, bnsum + 2 * 256);
    k_bn_apply<128, 2><<<grid1(NN * 16), 256, 0, stream>>>(bufBb, bnsum + 2 * 256, gat_g0, gat_bb0, bufBb);

    k_mm<128, 128, false, false, false, 2><<<gMM, 256, 0, stream>>>(
        bufBb, gat_W1t, nullptr, nullptr, nullptr, nullptr, gat_as1, gat_ad1, alsrc, aldst, bufAb);
    k_gat_agg<2, 64, false><<<gAgg, 256, 0, stream>>>(rowstart, csr_src, alsrc, aldst, bufAb, nullptr, bufBb);
    k_bn_stats<128><<<250, 256, 0, stream>>>(bufBb, bnsum + 3 * 256);
    k_bn_apply<128, 2><<<grid1(NN * 16), 256, 0, stream>>>(bufBb, bnsum + 3 * 256, gat_g1, gat_bb1, bufBb);

    k_mm<128, 128, false, false, false, 1><<<gMM, 256, 0, stream>>>(
        bufBb, gat_W2t, nullptr, nullptr, nullptr, nullptr, gat_as2, gat_ad2, alsrc, aldst, bufAb);
    k_gat_agg<1, 128, true><<<gAgg, 256, 0, stream>>>(rowstart, csr_src, alsrc, aldst, bufAb, gat_b2, bufBb);
    k_pool<<<(NN + 127) / 128, 256, 0, stream>>>(bufBb, batch, pooled, 128);

    // ================= SAGE =================
    // L0: matmul to 64-d first, aggregate small, add x@Wr
    k_mm<128, 64, false, false, false, 0><<<gMM, 256, 0, stream>>>(
        xb, sage_Wl0t, nullptr, nullptr, nullptr, nullptr, nullptr, nullptr, nullptr, nullptr, bufCb);
    k_sage_agg<64><<<gAgg, 256, 0, stream>>>(rowstart, pair, bufCb, bufAb);
    k_mm<128, 64, false, false, true, 0><<<gMM, 256, 0, stream>>>(
        xb, sage_Wr0t, nullptr, nullptr, bufAb, nullptr, nullptr, nullptr, nullptr, nullptr, bufCb);
    k_bn_stats<64><<<250, 256, 0, stream>>>(bufCb, bnsum + 4 * 256);
    k_bn_apply<64, 1><<<grid1(NN * 8), 256, 0, stream>>>(bufCb, bnsum + 4 * 256, sage_g0, sage_bb0, bufBb);

    k_sage_agg<64><<<gAgg, 256, 0, stream>>>(rowstart, pair, bufBb, bufAb);
    k_mm<64, 64, true, false, false, 0><<<gMM, 256, 0, stream>>>(
        bufAb, sage_Wl1t, bufBb, sage_Wr1t, nullptr, nullptr, nullptr, nullptr, nullptr, nullptr, bufCb);
    k_bn_stats<64><<<250, 256, 0, stream>>>(bufCb, bnsum + 5 * 256);
    k_bn_apply<64, 1><<<grid1(NN * 8), 256, 0, stream>>>(bufCb, bnsum + 5 * 256, sage_g1, sage_bb1, bufBb);

    k_sage_agg<64><<<gAgg, 256, 0, stream>>>(rowstart, pair, bufBb, bufAb);
    k_mm<64, 128, true, true, false, 0><<<gMM, 256, 0, stream>>>(
        bufAb, sage_Wl2t, bufBb, sage_Wr2t, nullptr, sage_b2, nullptr, nullptr, nullptr, nullptr, bufCb);
    k_pool<<<(NN + 127) / 128, 256, 0, stream>>>(bufCb, batch, pooled, 256);

    // ================= fusion =================
    k_fusion<<<grid1(NG * 128), 256, 0, stream>>>(pooled, cntG, fus_W, fus_b, (float*)d_out);
}

// Round 7
// 725.844 us; speedup vs baseline: 6.0349x; 1.0494x over previous
//
#include <hip/hip_runtime.h>

#define NN 50000
#define NE 800000
#define NG 50
#define NB 196   // ceil(NN/256)

static constexpr float BN_EPS = 1e-5f;

typedef __attribute__((ext_vector_type(8))) short  bf16x8;
typedef __attribute__((ext_vector_type(8))) unsigned short u16x8;
typedef __attribute__((ext_vector_type(4))) float  f32x4;

// ---------------- bf16 helpers ----------------
__device__ __forceinline__ float bf2f(unsigned short u) {
    return __uint_as_float(((unsigned)u) << 16);
}
__device__ __forceinline__ unsigned short f2bf(float f) {
    unsigned u = __float_as_uint(f);
    unsigned r = (u + 0x7fffu + ((u >> 16) & 1u)) >> 16;   // RNE
    return (unsigned short)r;
}

// ---------------- degree / CSR build ----------------
__global__ void k_indeg(const int* __restrict__ dst, int* __restrict__ indeg) {
    int e = blockIdx.x * 256 + threadIdx.x;
    if (e < NE) atomicAdd(&indeg[dst[e]], 1);
}

__global__ void k_scan1(const int* __restrict__ cnt, int* __restrict__ rowstart,
                        int* __restrict__ bsum, float* __restrict__ dis) {
    int i = blockIdx.x * 256 + threadIdx.x;
    int lane = threadIdx.x & 63, wv = threadIdx.x >> 6;
    int v = (i < NN) ? cnt[i] : 0;
    if (i < NN) dis[i] = rsqrtf((float)v + 1.0f);
    int s = v;
#pragma unroll
    for (int d = 1; d < 64; d <<= 1) {
        int t = __shfl_up(s, d);
        if (lane >= d) s += t;
    }
    __shared__ int wtot[4];
    if (lane == 63) wtot[wv] = s;
    __syncthreads();
    int woff = 0;
    for (int w = 0; w < wv; ++w) woff += wtot[w];
    if (i < NN) rowstart[i] = woff + s - v;
    if (threadIdx.x == 255) bsum[blockIdx.x] = woff + s;
}

__global__ void k_scan2(const int* __restrict__ bsum, int* __restrict__ boff) {
    int lane = threadIdx.x & 63, wv = threadIdx.x >> 6;
    int v = (threadIdx.x < NB) ? bsum[threadIdx.x] : 0;
    int s = v;
#pragma unroll
    for (int d = 1; d < 64; d <<= 1) {
        int t = __shfl_up(s, d);
        if (lane >= d) s += t;
    }
    __shared__ int wtot[4];
    if (lane == 63) wtot[wv] = s;
    __syncthreads();
    int woff = 0;
    for (int w = 0; w < wv; ++w) woff += wtot[w];
    if (threadIdx.x < NB) boff[threadIdx.x] = woff + s - v;
}

__global__ void k_scan3(int* __restrict__ rowstart, const int* __restrict__ boff,
                        int* __restrict__ cursor) {
    int i = blockIdx.x * 256 + threadIdx.x;
    if (i < NN) {
        int v = rowstart[i] + boff[blockIdx.x];
        rowstart[i] = v;
        cursor[i] = v;
    }
    if (i == 0) rowstart[NN] = NE;
}

// CSR fill, writing {src, dis[src]} pairs directly
__global__ void k_fill(const int* __restrict__ src, const int* __restrict__ dst,
                       const float* __restrict__ dis, int* __restrict__ cursor,
                       int2* __restrict__ pair) {
    int e = blockIdx.x * 256 + threadIdx.x;
    if (e < NE) {
        int s = src[e];
        int pos = atomicAdd(&cursor[dst[e]], 1);
        pair[pos] = make_int2(s, __float_as_int(dis[s]));
    }
}

__global__ void k_count(const int* __restrict__ batch, float* __restrict__ cntG) {
    __shared__ int hist[NG];
    for (int i = threadIdx.x; i < NG; i += 256) hist[i] = 0;
    __syncthreads();
    for (int n = blockIdx.x * 256 + threadIdx.x; n < NN; n += gridDim.x * 256)
        atomicAdd(&hist[batch[n]], 1);
    __syncthreads();
    for (int i = threadIdx.x; i < NG; i += 256)
        if (hist[i]) atomicAdd(&cntG[i], (float)hist[i]);
}

// ---------------- weight conversion ----------------
struct WDesc { const float* s; unsigned short* d; int fin; int fout; };
struct WTable { WDesc w[12]; };

// convert + transpose: dst[c*fin + k] = bf16(src[k*fout + c])
__global__ void k_convw(WTable t) {
    WDesc wd = t.w[blockIdx.x];
    int total = wd.fin * wd.fout;
    for (int i = threadIdx.x; i < total; i += 256) {
        int c = i / wd.fin, k = i % wd.fin;
        wd.d[i] = f2bf(wd.s[(size_t)k * wd.fout + c]);
    }
}

// ---------------- fused level-0 matmul: x(fp32) @ [gcn0|gat0|sWl0|sWr0] ------
__global__ __launch_bounds__(256) void k_mm0(
        const float* __restrict__ X, const unsigned short* __restrict__ Wf,
        const float* __restrict__ as_, const float* __restrict__ ad_,
        float* __restrict__ alsrc, float* __restrict__ aldst,
        unsigned short* __restrict__ outGCN, unsigned short* __restrict__ outGAT,
        unsigned short* __restrict__ outSL, unsigned short* __restrict__ outSR) {
    constexpr int FIN = 128, NCT = 20;   // FOUT = 320
    int wave = threadIdx.x >> 6, lane = threadIdx.x & 63;
    int rowbase = (blockIdx.x * 4 + wave) * 16;
    if (rowbase >= NN) return;
    int lr = lane & 15, lg = lane >> 4;
    int arow = rowbase + lr;
    f32x4 acc[NCT] = {};
    const float* xp = X + (size_t)arow * FIN + lg * 8;
#pragma unroll
    for (int k0 = 0; k0 < FIN; k0 += 32) {
        float4 v0 = *(const float4*)(xp + k0);
        float4 v1 = *(const float4*)(xp + k0 + 4);
        u16x8 au;
        au[0] = f2bf(v0.x); au[1] = f2bf(v0.y); au[2] = f2bf(v0.z); au[3] = f2bf(v0.w);
        au[4] = f2bf(v1.x); au[5] = f2bf(v1.y); au[6] = f2bf(v1.z); au[7] = f2bf(v1.w);
        bf16x8 a1 = *(bf16x8*)&au;
#pragma unroll
        for (int ct = 0; ct < NCT; ++ct) {
            int wcol = ct * 16 + lr;
            bf16x8 b1 = *(const bf16x8*)(Wf + (size_t)wcol * FIN + k0 + lg * 8);
            acc[ct] = __builtin_amdgcn_mfma_f32_16x16x32_bf16(a1, b1, acc[ct], 0, 0, 0);
        }
    }
    // GAT attention-logit epilogue on cols 64..191
    {
        float ps[2][4] = {}, pd[2][4] = {};
#pragma unroll
        for (int ct = 4; ct < 12; ++ct) {
            int hh = (ct >= 8) ? 1 : 0;
            int colg = ct * 16 + lr - 64;
            float cs = as_[colg], cd = ad_[colg];
#pragma unroll
            for (int j = 0; j < 4; ++j) {
                ps[hh][j] += acc[ct][j] * cs;
                pd[hh][j] += acc[ct][j] * cd;
            }
        }
#pragma unroll
        for (int m = 1; m < 16; m <<= 1)
#pragma unroll
            for (int hh = 0; hh < 2; ++hh)
#pragma unroll
                for (int j = 0; j < 4; ++j) {
                    ps[hh][j] += __shfl_xor(ps[hh][j], m);
                    pd[hh][j] += __shfl_xor(pd[hh][j], m);
                }
        if (lr == 0) {
#pragma unroll
            for (int j = 0; j < 4; ++j) {
                int row = rowbase + lg * 4 + j;
#pragma unroll
                for (int hh = 0; hh < 2; ++hh) {
                    alsrc[(size_t)row * 2 + hh] = ps[hh][j];
                    aldst[(size_t)row * 2 + hh] = pd[hh][j];
                }
            }
        }
    }
#pragma unroll
    for (int ct = 0; ct < NCT; ++ct) {
        int col = ct * 16 + lr;
#pragma unroll
        for (int j = 0; j < 4; ++j) {
            int row = rowbase + lg * 4 + j;
            unsigned short v = f2bf(acc[ct][j]);
            if (ct < 4)       outGCN[(size_t)row * 64 + col] = v;
            else if (ct < 12) outGAT[(size_t)row * 128 + (col - 64)] = v;
            else if (ct < 16) outSL[(size_t)row * 64 + (col - 192)] = v;
            else              outSR[(size_t)row * 64 + (col - 256)] = v;
        }
    }
}

// ---------------- MFMA matmul with optional fused BN+act on A1 -------------
// BNACT: 0 none, 1 BN+relu, 2 BN+elu.  ALH: GAT logit epilogue heads.
template <int FIN, int FOUT, bool DUAL, bool BIAS, int BNACT, int ALH>
__global__ __launch_bounds__(256) void k_mm(
        const unsigned short* __restrict__ A1, const unsigned short* __restrict__ W1t,
        const unsigned short* __restrict__ A2, const unsigned short* __restrict__ W2t,
        const float* __restrict__ bias,
        const float* __restrict__ bns, const float* __restrict__ bng, const float* __restrict__ bnb,
        const float* __restrict__ as_, const float* __restrict__ ad_,
        float* __restrict__ alsrc, float* __restrict__ aldst,
        unsigned short* __restrict__ out) {
    constexpr int NCT = FOUT / 16;
    int wave = threadIdx.x >> 6, lane = threadIdx.x & 63;
    int rowbase = (blockIdx.x * 4 + wave) * 16;
    if (rowbase >= NN) return;
    int lr = lane & 15, lg = lane >> 4;
    int arow = rowbase + lr;
    f32x4 acc[NCT] = {};
    const unsigned short* a1p = A1 + (size_t)arow * FIN + lg * 8;
    const unsigned short* a2p = DUAL ? (A2 + (size_t)arow * FIN + lg * 8) : nullptr;
#pragma unroll
    for (int k0 = 0; k0 < FIN; k0 += 32) {
        bf16x8 a1;
        if (BNACT == 0) {
            a1 = *(const bf16x8*)(a1p + k0);
        } else {
            u16x8 araw = *(const u16x8*)(a1p + k0);
            u16x8 atx;
#pragma unroll
            for (int j = 0; j < 8; ++j) {
                int f = k0 + lg * 8 + j;
                float mean = bns[f] * (1.0f / NN);
                float var = bns[FIN + f] * (1.0f / NN) - mean * mean;
                float rstd = rsqrtf(var + BN_EPS);
                float val = (bf2f(araw[j]) - mean) * rstd * bng[f] + bnb[f];
                if (BNACT == 1) val = fmaxf(val, 0.f);
                if (BNACT == 2) val = (val > 0.f) ? val : (__expf(val) - 1.0f);
                atx[j] = f2bf(val);
            }
            a1 = *(bf16x8*)&atx;
        }
        bf16x8 a2v = {};
        if (DUAL) a2v = *(const bf16x8*)(a2p + k0);
#pragma unroll
        for (int ct = 0; ct < NCT; ++ct) {
            int wcol = ct * 16 + lr;
            bf16x8 b1 = *(const bf16x8*)(W1t + (size_t)wcol * FIN + k0 + lg * 8);
            acc[ct] = __builtin_amdgcn_mfma_f32_16x16x32_bf16(a1, b1, acc[ct], 0, 0, 0);
            if (DUAL) {
                bf16x8 b2 = *(const bf16x8*)(W2t + (size_t)wcol * FIN + k0 + lg * 8);
                acc[ct] = __builtin_amdgcn_mfma_f32_16x16x32_bf16(a2v, b2, acc[ct], 0, 0, 0);
            }
        }
    }
    if (ALH > 0) {
        constexpr int NH = (ALH > 0) ? ALH : 1;
        float ps[NH][4] = {}, pd[NH][4] = {};
#pragma unroll
        for (int ct = 0; ct < NCT; ++ct) {
            int hh = (ALH == 2 && ct >= NCT / 2) ? 1 : 0;
            int col = ct * 16 + lr;
            float cs = as_[col], cd = ad_[col];
#pragma unroll
            for (int j = 0; j < 4; ++j) {
                ps[hh][j] += acc[ct][j] * cs;
                pd[hh][j] += acc[ct][j] * cd;
            }
        }
#pragma unroll
        for (int m = 1; m < 16; m <<= 1)
#pragma unroll
            for (int hh = 0; hh < NH; ++hh)
#pragma unroll
                for (int j = 0; j < 4; ++j) {
                    ps[hh][j] += __shfl_xor(ps[hh][j], m);
                    pd[hh][j] += __shfl_xor(pd[hh][j], m);
                }
        if (lr == 0) {
#pragma unroll
            for (int j = 0; j < 4; ++j) {
                int row = rowbase + lg * 4 + j;
#pragma unroll
                for (int hh = 0; hh < NH; ++hh) {
                    alsrc[(size_t)row * ALH + hh] = ps[hh][j];
                    aldst[(size_t)row * ALH + hh] = pd[hh][j];
                }
            }
        }
    }
#pragma unroll
    for (int ct = 0; ct < NCT; ++ct) {
        int col = ct * 16 + lr;
        float bv = BIAS ? bias[col] : 0.f;
#pragma unroll
        for (int j = 0; j < 4; ++j) {
            int row = rowbase + lg * 4 + j;
            out[(size_t)row * FOUT + col] = f2bf(acc[ct][j] + bv);
        }
    }
}

// ---------------- GCN aggregation (CSR, wave/node) ----------
template <int F, bool BIAS>
__global__ __launch_bounds__(256) void k_gcn_agg(
        const int* __restrict__ rowstart, const int2* __restrict__ pair,
        const float* __restrict__ dis, const unsigned short* __restrict__ h,
        const float* __restrict__ bias, unsigned short* __restrict__ out) {
    constexpr int LPE = F / 8;
    constexpr int EPW = 64 / LPE;
    int wave = threadIdx.x >> 6, lane = threadIdx.x & 63;
    int n = blockIdx.x * 4 + wave;
    if (n >= NN) return;
    int r0 = rowstart[n], r1 = rowstart[n + 1];
    float dn = dis[n];
    int fl = lane % LPE, eg = lane / LPE;
    int f0 = fl * 8;
    float acc[8] = {};
    if (eg == 0) {
        u16x8 hv = *(const u16x8*)&h[(size_t)n * F + f0];
        float c = dn * dn;
#pragma unroll
        for (int j = 0; j < 8; ++j) acc[j] = c * bf2f(hv[j]);
    }
#pragma unroll 4
    for (int e = r0 + eg; e < r1; e += EPW) {
        int2 p = pair[e];
        float c = __int_as_float(p.y) * dn;
        u16x8 hs = *(const u16x8*)&h[(size_t)p.x * F + f0];
#pragma unroll
        for (int jj = 0; jj < 8; ++jj) acc[jj] += c * bf2f(hs[jj]);
    }
#pragma unroll
    for (int off = LPE; off < 64; off <<= 1)
#pragma unroll
        for (int jj = 0; jj < 8; ++jj) acc[jj] += __shfl_xor(acc[jj], off);
    if (eg == 0) {
        u16x8 o;
#pragma unroll
        for (int jj = 0; jj < 8; ++jj) {
            float v = acc[jj];
            if (BIAS) v += bias[f0 + jj];
            o[jj] = f2bf(v);
        }
        *(u16x8*)&out[(size_t)n * F + f0] = o;
    }
}

// ---------------- SAGE mean aggregation ----------------
template <int F>
__global__ __launch_bounds__(256) void k_sage_agg(
        const int* __restrict__ rowstart, const int2* __restrict__ pair,
        const unsigned short* __restrict__ h, unsigned short* __restrict__ out) {
    constexpr int LPE = F / 8;
    constexpr int EPW = 64 / LPE;
    int wave = threadIdx.x >> 6, lane = threadIdx.x & 63;
    int n = blockIdx.x * 4 + wave;
    if (n >= NN) return;
    int r0 = rowstart[n], r1 = rowstart[n + 1];
    int fl = lane % LPE, eg = lane / LPE;
    int f0 = fl * 8;
    float acc[8] = {};
#pragma unroll 4
    for (int e = r0 + eg; e < r1; e += EPW) {
        int2 p = pair[e];
        u16x8 hs = *(const u16x8*)&h[(size_t)p.x * F + f0];
#pragma unroll
        for (int jj = 0; jj < 8; ++jj) acc[jj] += bf2f(hs[jj]);
    }
#pragma unroll
    for (int off = LPE; off < 64; off <<= 1)
#pragma unroll
        for (int jj = 0; jj < 8; ++jj) acc[jj] += __shfl_xor(acc[jj], off);
    if (eg == 0) {
        float inv = 1.0f / fmaxf((float)(r1 - r0), 1.0f);
        u16x8 o;
#pragma unroll
        for (int jj = 0; jj < 8; ++jj) o[jj] = f2bf(acc[jj] * inv);
        *(u16x8*)&out[(size_t)n * F + f0] = o;
    }
}

// ---------------- GAT: single-pass softmax + gather ----------
template <int H, int C, bool BIAS>
__global__ __launch_bounds__(256) void k_gat_agg(
        const int* __restrict__ rowstart, const int2* __restrict__ pair,
        const float* __restrict__ alsrc, const float* __restrict__ aldst,
        const unsigned short* __restrict__ h, const float* __restrict__ bias,
        unsigned short* __restrict__ out) {
    constexpr int HC = H * C;      // 128
    constexpr int LPE = HC / 8;    // 16
    constexpr int EPW = 64 / LPE;  // 4
    constexpr int HL = C / 8;      // lanes per head within a group
    int wave = threadIdx.x >> 6, lane = threadIdx.x & 63;
    int n = blockIdx.x * 4 + wave;
    if (n >= NN) return;
    int r0 = rowstart[n], r1 = rowstart[n + 1];
    int fl = lane % LPE, eg = lane / LPE;
    int f0 = fl * 8;
    int hh = (H > 1) ? (fl / HL) : 0;
    float adn = aldst[n * H + hh];
    float t = alsrc[n * H + hh] + adn;
    float ws = __expf((t >= 0.f) ? t : 0.2f * t);
    float acc[8] = {};
    float dsum = 0.f;
    if (eg == 0) {
        u16x8 hv = *(const u16x8*)&h[(size_t)n * HC + f0];
#pragma unroll
        for (int j = 0; j < 8; ++j) acc[j] = ws * bf2f(hv[j]);
    }
#pragma unroll 4
    for (int e = r0 + eg; e < r1; e += EPW) {
        int s = pair[e].x;
        float v = alsrc[(size_t)s * H + hh] + adn;
        v = (v >= 0.f) ? v : 0.2f * v;
        float w = __expf(v);
        dsum += w;
        u16x8 hs = *(const u16x8*)&h[(size_t)s * HC + f0];
#pragma unroll
        for (int jj = 0; jj < 8; ++jj) acc[jj] += w * bf2f(hs[jj]);
    }
    if (H > 1) {
#pragma unroll
        for (int off = 1; off < HL; off <<= 1) dsum += __shfl_xor(dsum, off);
#pragma unroll
        for (int off = LPE; off < 64; off <<= 1) dsum += __shfl_xor(dsum, off);
    } else {
#pragma unroll
        for (int off = 1; off < 64; off <<= 1) dsum += __shfl_xor(dsum, off);
    }
    float den = ws + dsum * (1.0f / HL);
    float dinv = 1.0f / (den + 1e-16f);
#pragma unroll
    for (int off = LPE; off < 64; off <<= 1)
#pragma unroll
        for (int jj = 0; jj < 8; ++jj) acc[jj] += __shfl_xor(acc[jj], off);
    if (eg == 0) {
        u16x8 o;
#pragma unroll
        for (int jj = 0; jj < 8; ++jj) {
            float v = acc[jj] * dinv;
            if (BIAS) v += bias[f0 + jj];
            o[jj] = f2bf(v);
        }
        *(u16x8*)&out[(size_t)n * HC + f0] = o;
    }
}

// ---------------- BatchNorm stats (1- and 2-input) ----------------
template <int F, bool TWO>
__global__ void k_bn_stats(const unsigned short* __restrict__ x,
                           const unsigned short* __restrict__ y,
                           float* __restrict__ sums) {
    constexpr int TPR = F / 8;
    constexpr int RPB = 256 / TPR;
    __shared__ float lsum[F], lsq[F];
    for (int i = threadIdx.x; i < F; i += 256) { lsum[i] = 0.f; lsq[i] = 0.f; }
    __syncthreads();
    int fl = threadIdx.x % TPR, rl = threadIdx.x / TPR;
    int f0 = fl * 8;
    float s[8] = {}, s2[8] = {};
    for (int n = blockIdx.x * RPB + rl; n < NN; n += gridDim.x * RPB) {
        u16x8 v = *(const u16x8*)&x[(size_t)n * F + f0];
        u16x8 w = {};
        if (TWO) w = *(const u16x8*)&y[(size_t)n * F + f0];
#pragma unroll
        for (int j = 0; j < 8; ++j) {
            float f = bf2f(v[j]);
            if (TWO) f += bf2f(w[j]);
            s[j] += f; s2[j] += f * f;
        }
    }
#pragma unroll
    for (int off = TPR; off < 64; off <<= 1)
#pragma unroll
        for (int j = 0; j < 8; ++j) { s[j] += __shfl_xor(s[j], off); s2[j] += __shfl_xor(s2[j], off); }
    if ((threadIdx.x & 63) < TPR) {
#pragma unroll
        for (int j = 0; j < 8; ++j) {
            atomicAdd(&lsum[f0 + j], s[j]);
            atomicAdd(&lsq[f0 + j], s2[j]);
        }
    }
    __syncthreads();
    for (int i = threadIdx.x; i < F; i += 256) {
        atomicAdd(&sums[i], lsum[i]);
        atomicAdd(&sums[F + i], lsq[i]);
    }
}

// ---------------- BatchNorm apply (1- and 2-input) ----------------
// ACT: 1 relu, 2 elu.
template <int F, int ACT, bool TWO>
__global__ void k_bn_apply(const unsigned short* __restrict__ x,
                           const unsigned short* __restrict__ y,
                           const float* __restrict__ sums,
                           const float* __restrict__ gamma, const float* __restrict__ beta,
                           unsigned short* __restrict__ out) {
    int idx = blockIdx.x * 256 + threadIdx.x;   // units of 8 elems
    if (idx >= NN * F / 8) return;
    int f0 = (idx % (F / 8)) * 8;
    u16x8 v = *(const u16x8*)&x[(size_t)idx * 8];
    u16x8 w = {};
    if (TWO) w = *(const u16x8*)&y[(size_t)idx * 8];
    u16x8 o;
#pragma unroll
    for (int j = 0; j < 8; ++j) {
        int f = f0 + j;
        float mean = sums[f] * (1.0f / NN);
        float var = sums[F + f] * (1.0f / NN) - mean * mean;
        float rstd = rsqrtf(var + BN_EPS);
        float raw = bf2f(v[j]);
        if (TWO) raw += bf2f(w[j]);
        float val = (raw - mean) * rstd * gamma[f] + beta[f];
        if (ACT == 1) val = fmaxf(val, 0.f);
        if (ACT == 2) val = (val > 0.f) ? val : (__expf(val) - 1.0f);
        o[j] = f2bf(val);
    }
    *(u16x8*)&out[(size_t)idx * 8] = o;
}

// ---------------- pooling / fusion ----------------
__global__ void k_pool(const unsigned short* __restrict__ x, const int* __restrict__ batch,
                       float* __restrict__ pooled, int off) {
    int f = threadIdx.x & 127;
    int half = threadIdx.x >> 7;
    int nend = min(NN, (int)(blockIdx.x + 1) * 128);
    float acc = 0.f; int gcur = -1;
    for (int n = blockIdx.x * 128 + half; n < nend; n += 2) {
        int g = batch[n];
        if (g != gcur) {
            if (gcur >= 0) atomicAdd(&pooled[(size_t)gcur * 384 + off + f], acc);
            gcur = g; acc = 0.f;
        }
        acc += bf2f(x[(size_t)n * 128 + f]);
    }
    if (gcur >= 0) atomicAdd(&pooled[(size_t)gcur * 384 + off + f], acc);
}

__global__ void k_fusion(const float* __restrict__ pooled, const float* __restrict__ cntG,
                         const float* __restrict__ W, const float* __restrict__ b,
                         float* __restrict__ out) {
    int idx = blockIdx.x * 256 + threadIdx.x;   // NG*128
    if (idx >= NG * 128) return;
    int g = idx / 128, o = idx % 128;
    float inv = 1.0f / fmaxf(cntG[g], 1.0f);
    float acc = b[o];
#pragma unroll 4
    for (int k = 0; k < 384; ++k)
        acc += pooled[g * 384 + k] * inv * W[k * 128 + o];
    out[idx] = acc;
}

// ---------------- launcher ----------------
static inline int grid1(long long n) { return (int)((n + 255) / 256); }

extern "C" void kernel_launch(void* const* d_in, const int* in_sizes, int n_in,
                              void* d_out, int out_size, void* d_ws, size_t ws_size,
                              hipStream_t stream) {
    const float* x       = (const float*)d_in[0];
    const int*   ei      = (const int*)d_in[1];
    const int*   batch   = (const int*)d_in[2];
    const float* gcn_W0  = (const float*)d_in[3];
    const float* gcn_W1  = (const float*)d_in[5];
    const float* gcn_W2  = (const float*)d_in[7];
    const float* gcn_b2  = (const float*)d_in[8];
    const float* gcn_g0  = (const float*)d_in[9];
    const float* gcn_bb0 = (const float*)d_in[10];
    const float* gcn_g1  = (const float*)d_in[11];
    const float* gcn_bb1 = (const float*)d_in[12];
    const float* gat_W0  = (const float*)d_in[13];
    const float* gat_as0 = (const float*)d_in[14];
    const float* gat_ad0 = (const float*)d_in[15];
    const float* gat_W1  = (const float*)d_in[17];
    const float* gat_as1 = (const float*)d_in[18];
    const float* gat_ad1 = (const float*)d_in[19];
    const float* gat_W2  = (const float*)d_in[21];
    const float* gat_as2 = (const float*)d_in[22];
    const float* gat_ad2 = (const float*)d_in[23];
    const float* gat_b2  = (const float*)d_in[24];
    const float* gat_g0  = (const float*)d_in[25];
    const float* gat_bb0 = (const float*)d_in[26];
    const float* gat_g1  = (const float*)d_in[27];
    const float* gat_bb1 = (const float*)d_in[28];
    const float* sage_Wl0 = (const float*)d_in[29];
    const float* sage_Wr0 = (const float*)d_in[30];
    const float* sage_Wl1 = (const float*)d_in[32];
    const float* sage_Wr1 = (const float*)d_in[33];
    const float* sage_Wl2 = (const float*)d_in[35];
    const float* sage_Wr2 = (const float*)d_in[36];
    const float* sage_b2  = (const float*)d_in[37];
    const float* sage_g0  = (const float*)d_in[38];
    const float* sage_bb0 = (const float*)d_in[39];
    const float* sage_g1  = (const float*)d_in[40];
    const float* sage_bb1 = (const float*)d_in[41];
    const float* fus_W    = (const float*)d_in[42];
    const float* fus_b    = (const float*)d_in[43];

    const int* src = ei;
    const int* dst = ei + NE;

    // workspace layout
    float* ws = (float*)d_ws;
    size_t off = 0;
    auto alloc = [&](size_t n) { float* p = ws + off; off += (n + 3) & ~(size_t)3; return p; };
    unsigned short* bufA  = (unsigned short*)alloc((size_t)NN * 64);   // NN*128 bf16
    unsigned short* bufB  = (unsigned short*)alloc((size_t)NN * 64);
    unsigned short* bufC  = (unsigned short*)alloc((size_t)NN * 64);
    unsigned short* bufD  = (unsigned short*)alloc((size_t)NN * 64);   // sl0 | sr0
    unsigned short* wt    = (unsigned short*)alloc(110592 / 2);        // all transposed bf16 weights
    int*   indeg    = (int*)alloc(NN);
    int*   rowstart = (int*)alloc(NN + 1);
    int*   cursor   = (int*)alloc(NN);
    int2*  pair     = (int2*)alloc((size_t)NE * 2);
    int*   bsum     = (int*)alloc(NB);
    int*   boff     = (int*)alloc(NB);
    float* dis   = alloc(NN);
    float* alsrc = alloc((size_t)NN * 2);
    float* aldst = alloc((size_t)NN * 2);
    float* bnsum = alloc(6 * 256 + NG * 384 + NG);   // bnsum | pooled | cntG (one memset)
    float* pooled = bnsum + 6 * 256;
    float* cntG   = pooled + NG * 384;
    (void)ws_size; (void)n_in; (void)in_sizes; (void)out_size;

    unsigned short* sl0 = bufD;
    unsigned short* sr0 = bufD + (size_t)NN * 64;

    // fused L0 weight block: [gcn0(64) | gat0(128) | sWl0(64) | sWr0(64)] x 128
    unsigned short* wf       = wt;                  // 320x128 = 40960
    unsigned short* gcn_W1t  = wf + 40960;          // 64x64
    unsigned short* gcn_W2t  = gcn_W1t + 4096;      // 64x128
    unsigned short* gat_W1t  = gcn_W2t + 8192;      // 128x128
    unsigned short* gat_W2t  = gat_W1t + 16384;
    unsigned short* sage_Wl1t = gat_W2t + 16384;    // 64x64
    unsigned short* sage_Wr1t = sage_Wl1t + 4096;
    unsigned short* sage_Wl2t = sage_Wr1t + 4096;   // 64x128
    unsigned short* sage_Wr2t = sage_Wl2t + 8192;

    const int gAgg = NN / 4;
    const int gMM  = (NN + 63) / 64;

    // ---- CSR build + precompute ----
    hipMemsetAsync(indeg, 0, NN * 4, stream);
    hipMemsetAsync(bnsum, 0, (6 * 256 + NG * 384 + NG) * 4, stream);
    k_indeg<<<grid1(NE), 256, 0, stream>>>(dst, indeg);
    k_scan1<<<NB, 256, 0, stream>>>(indeg, rowstart, bsum, dis);
    k_scan2<<<1, 256, 0, stream>>>(bsum, boff);
    k_scan3<<<NB, 256, 0, stream>>>(rowstart, boff, cursor);
    k_fill<<<grid1(NE), 256, 0, stream>>>(src, dst, dis, cursor, pair);
    k_count<<<128, 256, 0, stream>>>(batch, cntG);
    WTable wtab = {{
        { gcn_W0, wf, 128, 64 }, { gat_W0, wf + 64 * 128, 128, 128 },
        { sage_Wl0, wf + 192 * 128, 128, 64 }, { sage_Wr0, wf + 256 * 128, 128, 64 },
        { gcn_W1, gcn_W1t, 64, 64 }, { gcn_W2, gcn_W2t, 64, 128 },
        { gat_W1, gat_W1t, 128, 128 }, { gat_W2, gat_W2t, 128, 128 },
        { sage_Wl1, sage_Wl1t, 64, 64 }, { sage_Wr1, sage_Wr1t, 64, 64 },
        { sage_Wl2, sage_Wl2t, 64, 128 }, { sage_Wr2, sage_Wr2t, 64, 128 },
    }};
    k_convw<<<12, 256, 0, stream>>>(wtab);

    // ---- fused level-0 matmul ----
    k_mm0<<<gMM, 256, 0, stream>>>(x, wf, gat_as0, gat_ad0, alsrc, aldst,
                                   bufA, bufB, sl0, sr0);

    // ================= GCN ================= (bufA = gcn0)
    k_gcn_agg<64, false><<<gAgg, 256, 0, stream>>>(rowstart, pair, dis, bufA, nullptr, bufC);
    k_bn_stats<64, false><<<250, 256, 0, stream>>>(bufC, nullptr, bnsum + 0 * 256);
    k_mm<64, 64, false, false, 1, 0><<<gMM, 256, 0, stream>>>(          // BN+relu fused on A
        bufC, gcn_W1t, nullptr, nullptr, nullptr,
        bnsum + 0 * 256, gcn_g0, gcn_bb0, nullptr, nullptr, nullptr, nullptr, bufA);
    k_gcn_agg<64, false><<<gAgg, 256, 0, stream>>>(rowstart, pair, dis, bufA, nullptr, bufC);
    k_bn_stats<64, false><<<250, 256, 0, stream>>>(bufC, nullptr, bnsum + 1 * 256);
    k_bn_apply<64, 1, false><<<grid1(NN * 8), 256, 0, stream>>>(
        bufC, nullptr, bnsum + 1 * 256, gcn_g1, gcn_bb1, bufA);
    k_gcn_agg<64, false><<<gAgg, 256, 0, stream>>>(rowstart, pair, dis, bufA, nullptr, bufC);
    k_mm<64, 128, false, true, 0, 0><<<gMM, 256, 0, stream>>>(
        bufC, gcn_W2t, nullptr, nullptr, gcn_b2,
        nullptr, nullptr, nullptr, nullptr, nullptr, nullptr, nullptr, bufA);
    k_pool<<<(NN + 127) / 128, 256, 0, stream>>>(bufA, batch, pooled, 0);

    // ================= GAT ================= (bufB = gat0, alsrc/aldst set)
    k_gat_agg<2, 64, false><<<gAgg, 256, 0, stream>>>(rowstart, pair, alsrc, aldst, bufB, nullptr, bufC);
    k_bn_stats<128, false><<<250, 256, 0, stream>>>(bufC, nullptr, bnsum + 2 * 256);
    k_mm<128, 128, false, false, 2, 2><<<gMM, 256, 0, stream>>>(        // BN+elu fused + AL
        bufC, gat_W1t, nullptr, nullptr, nullptr,
        bnsum + 2 * 256, gat_g0, gat_bb0, gat_as1, gat_ad1, alsrc, aldst, bufB);
    k_gat_agg<2, 64, false><<<gAgg, 256, 0, stream>>>(rowstart, pair, alsrc, aldst, bufB, nullptr, bufC);
    k_bn_stats<128, false><<<250, 256, 0, stream>>>(bufC, nullptr, bnsum + 3 * 256);
    k_mm<128, 128, false, false, 2, 1><<<gMM, 256, 0, stream>>>(
        bufC, gat_W2t, nullptr, nullptr, nullptr,
        bnsum + 3 * 256, gat_g1, gat_bb1, gat_as2, gat_ad2, alsrc, aldst, bufB);
    k_gat_agg<1, 128, true><<<gAgg, 256, 0, stream>>>(rowstart, pair, alsrc, aldst, bufB, gat_b2, bufC);
    k_pool<<<(NN + 127) / 128, 256, 0, stream>>>(bufC, batch, pooled, 128);

    // ================= SAGE ================= (sl0 = x@Wl0, sr0 = x@Wr0)
    k_sage_agg<64><<<gAgg, 256, 0, stream>>>(rowstart, pair, sl0, bufA);
    k_bn_stats<64, true><<<250, 256, 0, stream>>>(bufA, sr0, bnsum + 4 * 256);
    k_bn_apply<64, 1, true><<<grid1(NN * 8), 256, 0, stream>>>(
        bufA, sr0, bnsum + 4 * 256, sage_g0, sage_bb0, bufB);
    k_sage_agg<64><<<gAgg, 256, 0, stream>>>(rowstart, pair, bufB, bufA);
    k_mm<64, 64, true, false, 0, 0><<<gMM, 256, 0, stream>>>(
        bufA, sage_Wl1t, bufB, sage_Wr1t, nullptr,
        nullptr, nullptr, nullptr, nullptr, nullptr, nullptr, nullptr, bufC);
    k_bn_stats<64, false><<<250, 256, 0, stream>>>(bufC, nullptr, bnsum + 5 * 256);
    k_bn_apply<64, 1, false><<<grid1(NN * 8), 256, 0, stream>>>(
        bufC, nullptr, bnsum + 5 * 256, sage_g1, sage_bb1, bufB);
    k_sage_agg<64><<<gAgg, 256, 0, stream>>>(rowstart, pair, bufB, bufA);
    k_mm<64, 128, true, true, 0, 0><<<gMM, 256, 0, stream>>>(
        bufA, sage_Wl2t, bufB, sage_Wr2t, sage_b2,
        nullptr, nullptr, nullptr, nullptr, nullptr, nullptr, nullptr, bufC);
    k_pool<<<(NN + 127) / 128, 256, 0, stream>>>(bufC, batch, pooled, 256);

    // ================= fusion =================
    k_fusion<<<grid1(NG * 128), 256, 0, stream>>>(pooled, cntG, fus_W, fus_b, (float*)d_out);
}

// Round 8
// 663.952 us; speedup vs baseline: 6.5974x; 1.0932x over previous
//
#include <hip/hip_runtime.h>

#define NN 50000
#define NE 800000
#define NG 50
#define NB 196   // ceil(NN/256)

static constexpr float BN_EPS = 1e-5f;

typedef __attribute__((ext_vector_type(8))) short  bf16x8;
typedef __attribute__((ext_vector_type(8))) unsigned short u16x8;
typedef __attribute__((ext_vector_type(4))) float  f32x4;

// ---------------- bf16 helpers ----------------
__device__ __forceinline__ float bf2f(unsigned short u) {
    return __uint_as_float(((unsigned)u) << 16);
}
__device__ __forceinline__ unsigned short f2bf(float f) {
    unsigned u = __float_as_uint(f);
    unsigned r = (u + 0x7fffu + ((u >> 16) & 1u)) >> 16;   // RNE
    return (unsigned short)r;
}

// ---------------- degree / CSR build ----------------
__global__ void k_indeg(const int* __restrict__ dst, int* __restrict__ indeg) {
    int e = blockIdx.x * 256 + threadIdx.x;
    if (e < NE) atomicAdd(&indeg[dst[e]], 1);
}

__global__ void k_scan1(const int* __restrict__ cnt, int* __restrict__ rowstart,
                        int* __restrict__ bsum, float* __restrict__ dis) {
    int i = blockIdx.x * 256 + threadIdx.x;
    int lane = threadIdx.x & 63, wv = threadIdx.x >> 6;
    int v = (i < NN) ? cnt[i] : 0;
    if (i < NN) dis[i] = rsqrtf((float)v + 1.0f);
    int s = v;
#pragma unroll
    for (int d = 1; d < 64; d <<= 1) {
        int t = __shfl_up(s, d);
        if (lane >= d) s += t;
    }
    __shared__ int wtot[4];
    if (lane == 63) wtot[wv] = s;
    __syncthreads();
    int woff = 0;
    for (int w = 0; w < wv; ++w) woff += wtot[w];
    if (i < NN) rowstart[i] = woff + s - v;
    if (threadIdx.x == 255) bsum[blockIdx.x] = woff + s;
}

__global__ void k_scan2(const int* __restrict__ bsum, int* __restrict__ boff) {
    int lane = threadIdx.x & 63, wv = threadIdx.x >> 6;
    int v = (threadIdx.x < NB) ? bsum[threadIdx.x] : 0;
    int s = v;
#pragma unroll
    for (int d = 1; d < 64; d <<= 1) {
        int t = __shfl_up(s, d);
        if (lane >= d) s += t;
    }
    __shared__ int wtot[4];
    if (lane == 63) wtot[wv] = s;
    __syncthreads();
    int woff = 0;
    for (int w = 0; w < wv; ++w) woff += wtot[w];
    if (threadIdx.x < NB) boff[threadIdx.x] = woff + s - v;
}

__global__ void k_scan3(int* __restrict__ rowstart, const int* __restrict__ boff,
                        int* __restrict__ cursor) {
    int i = blockIdx.x * 256 + threadIdx.x;
    if (i < NN) {
        int v = rowstart[i] + boff[blockIdx.x];
        rowstart[i] = v;
        cursor[i] = v;
    }
    if (i == 0) rowstart[NN] = NE;
}

// 4B scatter (cheapest dirty-line form)
__global__ void k_fill(const int* __restrict__ src, const int* __restrict__ dst,
                       int* __restrict__ cursor, int* __restrict__ csr_src) {
    int e = blockIdx.x * 256 + threadIdx.x;
    if (e < NE) {
        int pos = atomicAdd(&cursor[dst[e]], 1);
        csr_src[pos] = src[e];
    }
}

// coalesced pack of {src, dis[src]}
__global__ void k_pack(const int* __restrict__ csr_src, const float* __restrict__ dis,
                       int2* __restrict__ pair) {
    int e = blockIdx.x * 256 + threadIdx.x;
    if (e < NE) {
        int s = csr_src[e];
        pair[e] = make_int2(s, __float_as_int(dis[s]));
    }
}

__global__ void k_count(const int* __restrict__ batch, float* __restrict__ cntG) {
    __shared__ int hist[NG];
    for (int i = threadIdx.x; i < NG; i += 256) hist[i] = 0;
    __syncthreads();
    for (int n = blockIdx.x * 256 + threadIdx.x; n < NN; n += gridDim.x * 256)
        atomicAdd(&hist[batch[n]], 1);
    __syncthreads();
    for (int i = threadIdx.x; i < NG; i += 256)
        if (hist[i]) atomicAdd(&cntG[i], (float)hist[i]);
}

// ---------------- weight conversion ----------------
struct WDesc { const float* s; unsigned short* d; int fin; int fout; };
struct WTable { WDesc w[12]; };

__global__ void k_convw(WTable t) {
    WDesc wd = t.w[blockIdx.x];
    int total = wd.fin * wd.fout;
    for (int i = threadIdx.x; i < total; i += 256) {
        int c = i / wd.fin, k = i % wd.fin;
        wd.d[i] = f2bf(wd.s[(size_t)k * wd.fout + c]);
    }
}

// ---------------- fused level-0 matmul: x(fp32) @ [gcn0|gat0|sWl0|sWr0] ------
// writes comb sections [GCN 0-63 | SAGE 64-127 | GAT 128-255] + sr0 compact
__global__ __launch_bounds__(256) void k_mm0(
        const float* __restrict__ X, const unsigned short* __restrict__ Wf,
        const float* __restrict__ as_, const float* __restrict__ ad_,
        float* __restrict__ alsrc, float* __restrict__ aldst,
        unsigned short* __restrict__ comb, unsigned short* __restrict__ sr0) {
    constexpr int FIN = 128, NCT = 20;   // FOUT = 320
    int wave = threadIdx.x >> 6, lane = threadIdx.x & 63;
    int rowbase = (blockIdx.x * 4 + wave) * 16;
    if (rowbase >= NN) return;
    int lr = lane & 15, lg = lane >> 4;
    int arow = rowbase + lr;
    f32x4 acc[NCT] = {};
    const float* xp = X + (size_t)arow * FIN + lg * 8;
#pragma unroll
    for (int k0 = 0; k0 < FIN; k0 += 32) {
        float4 v0 = *(const float4*)(xp + k0);
        float4 v1 = *(const float4*)(xp + k0 + 4);
        u16x8 au;
        au[0] = f2bf(v0.x); au[1] = f2bf(v0.y); au[2] = f2bf(v0.z); au[3] = f2bf(v0.w);
        au[4] = f2bf(v1.x); au[5] = f2bf(v1.y); au[6] = f2bf(v1.z); au[7] = f2bf(v1.w);
        bf16x8 a1 = *(bf16x8*)&au;
#pragma unroll
        for (int ct = 0; ct < NCT; ++ct) {
            int wcol = ct * 16 + lr;
            bf16x8 b1 = *(const bf16x8*)(Wf + (size_t)wcol * FIN + k0 + lg * 8);
            acc[ct] = __builtin_amdgcn_mfma_f32_16x16x32_bf16(a1, b1, acc[ct], 0, 0, 0);
        }
    }
    // GAT attention-logit epilogue on fused cols 64..191
    {
        float ps[2][4] = {}, pd[2][4] = {};
#pragma unroll
        for (int ct = 4; ct < 12; ++ct) {
            int hh = (ct >= 8) ? 1 : 0;
            int colg = ct * 16 + lr - 64;
            float cs = as_[colg], cd = ad_[colg];
#pragma unroll
            for (int j = 0; j < 4; ++j) {
                ps[hh][j] += acc[ct][j] * cs;
                pd[hh][j] += acc[ct][j] * cd;
            }
        }
#pragma unroll
        for (int m = 1; m < 16; m <<= 1)
#pragma unroll
            for (int hh = 0; hh < 2; ++hh)
#pragma unroll
                for (int j = 0; j < 4; ++j) {
                    ps[hh][j] += __shfl_xor(ps[hh][j], m);
                    pd[hh][j] += __shfl_xor(pd[hh][j], m);
                }
        if (lr == 0) {
#pragma unroll
            for (int j = 0; j < 4; ++j) {
                int row = rowbase + lg * 4 + j;
#pragma unroll
                for (int hh = 0; hh < 2; ++hh) {
                    alsrc[(size_t)row * 2 + hh] = ps[hh][j];
                    aldst[(size_t)row * 2 + hh] = pd[hh][j];
                }
            }
        }
    }
#pragma unroll
    for (int ct = 0; ct < NCT; ++ct) {
        int col = ct * 16 + lr;
#pragma unroll
        for (int j = 0; j < 4; ++j) {
            int row = rowbase + lg * 4 + j;
            unsigned short v = f2bf(acc[ct][j]);
            if (ct < 4)       comb[(size_t)row * 256 + col] = v;              // GCN
            else if (ct < 12) comb[(size_t)row * 256 + 128 + (col - 64)] = v; // GAT
            else if (ct < 16) comb[(size_t)row * 256 + 64 + (col - 192)] = v; // SAGE-L
            else              sr0[(size_t)row * 64 + (col - 256)] = v;
        }
    }
}

// ---------------- MFMA matmul, fused BN+act on A1, strided out -------------
// BNACT: 0 none, 1 BN+relu, 2 BN+elu.  ALH: GAT logit epilogue heads.
template <int FIN, int FOUT, bool DUAL, bool BIAS, int BNACT, int ALH, int OSTR, int OOFF>
__global__ __launch_bounds__(256) void k_mm(
        const unsigned short* __restrict__ A1, const unsigned short* __restrict__ W1t,
        const unsigned short* __restrict__ A2, const unsigned short* __restrict__ W2t,
        const float* __restrict__ bias,
        const float* __restrict__ bns, const float* __restrict__ bng, const float* __restrict__ bnb,
        const float* __restrict__ as_, const float* __restrict__ ad_,
        float* __restrict__ alsrc, float* __restrict__ aldst,
        unsigned short* __restrict__ out) {
    constexpr int NCT = FOUT / 16;
    int wave = threadIdx.x >> 6, lane = threadIdx.x & 63;
    int rowbase = (blockIdx.x * 4 + wave) * 16;
    if (rowbase >= NN) return;
    int lr = lane & 15, lg = lane >> 4;
    int arow = rowbase + lr;
    f32x4 acc[NCT] = {};
    const unsigned short* a1p = A1 + (size_t)arow * FIN + lg * 8;
    const unsigned short* a2p = DUAL ? (A2 + (size_t)arow * FIN + lg * 8) : nullptr;
#pragma unroll
    for (int k0 = 0; k0 < FIN; k0 += 32) {
        bf16x8 a1;
        if (BNACT == 0) {
            a1 = *(const bf16x8*)(a1p + k0);
        } else {
            u16x8 araw = *(const u16x8*)(a1p + k0);
            u16x8 atx;
#pragma unroll
            for (int j = 0; j < 8; ++j) {
                int f = k0 + lg * 8 + j;
                float mean = bns[f] * (1.0f / NN);
                float var = bns[FIN + f] * (1.0f / NN) - mean * mean;
                float rstd = rsqrtf(var + BN_EPS);
                float val = (bf2f(araw[j]) - mean) * rstd * bng[f] + bnb[f];
                if (BNACT == 1) val = fmaxf(val, 0.f);
                if (BNACT == 2) val = (val > 0.f) ? val : (__expf(val) - 1.0f);
                atx[j] = f2bf(val);
            }
            a1 = *(bf16x8*)&atx;
        }
        bf16x8 a2v = {};
        if (DUAL) a2v = *(const bf16x8*)(a2p + k0);
#pragma unroll
        for (int ct = 0; ct < NCT; ++ct) {
            int wcol = ct * 16 + lr;
            bf16x8 b1 = *(const bf16x8*)(W1t + (size_t)wcol * FIN + k0 + lg * 8);
            acc[ct] = __builtin_amdgcn_mfma_f32_16x16x32_bf16(a1, b1, acc[ct], 0, 0, 0);
            if (DUAL) {
                bf16x8 b2 = *(const bf16x8*)(W2t + (size_t)wcol * FIN + k0 + lg * 8);
                acc[ct] = __builtin_amdgcn_mfma_f32_16x16x32_bf16(a2v, b2, acc[ct], 0, 0, 0);
            }
        }
    }
    if (ALH > 0) {
        constexpr int NH = (ALH > 0) ? ALH : 1;
        float ps[NH][4] = {}, pd[NH][4] = {};
#pragma unroll
        for (int ct = 0; ct < NCT; ++ct) {
            int hh = (ALH == 2 && ct >= NCT / 2) ? 1 : 0;
            int col = ct * 16 + lr;
            float cs = as_[col], cd = ad_[col];
#pragma unroll
            for (int j = 0; j < 4; ++j) {
                ps[hh][j] += acc[ct][j] * cs;
                pd[hh][j] += acc[ct][j] * cd;
            }
        }
#pragma unroll
        for (int m = 1; m < 16; m <<= 1)
#pragma unroll
            for (int hh = 0; hh < NH; ++hh)
#pragma unroll
                for (int j = 0; j < 4; ++j) {
                    ps[hh][j] += __shfl_xor(ps[hh][j], m);
                    pd[hh][j] += __shfl_xor(pd[hh][j], m);
                }
        if (lr == 0) {
#pragma unroll
            for (int j = 0; j < 4; ++j) {
                int row = rowbase + lg * 4 + j;
#pragma unroll
                for (int hh = 0; hh < NH; ++hh) {
                    alsrc[(size_t)row * ALH + hh] = ps[hh][j];
                    aldst[(size_t)row * ALH + hh] = pd[hh][j];
                }
            }
        }
    }
#pragma unroll
    for (int ct = 0; ct < NCT; ++ct) {
        int col = ct * 16 + lr;
        float bv = BIAS ? bias[col] : 0.f;
#pragma unroll
        for (int j = 0; j < 4; ++j) {
            int row = rowbase + lg * 4 + j;
            out[(size_t)row * OSTR + OOFF + col] = f2bf(acc[ct][j] + bv);
        }
    }
}

// ---------------- fused 3-branch aggregation over comb[NN][256] -----------
// lane roles: fl 0-7 GCN, fl 8-15 SAGE, fl 16-31 GAT (head-aligned)
template <int H, bool GATBIAS>
__global__ __launch_bounds__(256) void k_aggf(
        const int* __restrict__ rowstart, const int2* __restrict__ pair,
        const float* __restrict__ dis, const float* __restrict__ alsrc,
        const float* __restrict__ aldst, const unsigned short* __restrict__ comb,
        const float* __restrict__ gat_bias,
        unsigned short* __restrict__ outGCN, unsigned short* __restrict__ outGAT,
        unsigned short* __restrict__ outSAGE) {
    int wave = threadIdx.x >> 6, lane = threadIdx.x & 63;
    int n = blockIdx.x * 4 + wave;
    if (n >= NN) return;
    int eg = lane >> 5, fl = lane & 31;
    int f0 = fl * 8;
    bool isGCN = fl < 8, isSAGE = (fl >= 8) && (fl < 16), isGAT = fl >= 16;
    int hh = (H == 2) ? ((fl >= 24) ? 1 : 0) : 0;
    int r0 = rowstart[n], r1 = rowstart[n + 1];
    float dn = dis[n];
    float adn = isGAT ? aldst[n * H + hh] : 0.f;
    float tself = isGAT ? (alsrc[n * H + hh] + adn) : 0.f;
    tself = (tself >= 0.f) ? tself : 0.2f * tself;
    float wsG = __expf(tself);                       // GAT self weight
    float selfw = isGCN ? dn * dn : (isGAT ? wsG : 0.f);
    float acc[8] = {};
    if (eg == 0) {
        u16x8 hv = *(const u16x8*)&comb[(size_t)n * 256 + f0];
#pragma unroll
        for (int j = 0; j < 8; ++j) acc[j] = selfw * bf2f(hv[j]);
    }
    float dsum = 0.f;
#pragma unroll 4
    for (int e = r0 + eg; e < r1; e += 2) {
        int2 p = pair[e];
        int s = p.x;
        float al = isGAT ? alsrc[(size_t)s * H + hh] : 0.f;
        float v = al + adn;
        v = (v >= 0.f) ? v : 0.2f * v;
        float we = __expf(v);
        dsum += we;
        float w = isGCN ? __int_as_float(p.y) * dn : (isGAT ? we : 1.0f);
        u16x8 hs = *(const u16x8*)&comb[(size_t)s * 256 + f0];
#pragma unroll
        for (int jj = 0; jj < 8; ++jj) acc[jj] += w * bf2f(hs[jj]);
    }
    // GAT denominator (masked butterfly within head cluster + cross-eg)
    if (H == 2) {
        dsum += __shfl_xor(dsum, 1);
        dsum += __shfl_xor(dsum, 2);
        dsum += __shfl_xor(dsum, 4);
        dsum += __shfl_xor(dsum, 32);
        dsum *= 0.125f;
    } else {
        dsum += __shfl_xor(dsum, 1);
        dsum += __shfl_xor(dsum, 2);
        dsum += __shfl_xor(dsum, 4);
        dsum += __shfl_xor(dsum, 8);
        dsum += __shfl_xor(dsum, 32);
        dsum *= 0.0625f;
    }
    float dinv = 1.0f / (wsG + dsum + 1e-16f);
    // feature reduce across the two edge-groups
#pragma unroll
    for (int jj = 0; jj < 8; ++jj) acc[jj] += __shfl_xor(acc[jj], 32);
    if (eg == 0) {
        float inv = 1.0f / fmaxf((float)(r1 - r0), 1.0f);
        float mul = isGCN ? 1.0f : (isSAGE ? inv : dinv);
        u16x8 o;
#pragma unroll
        for (int jj = 0; jj < 8; ++jj) {
            float v = acc[jj] * mul;
            if (GATBIAS && isGAT) v += gat_bias[f0 - 128 + jj];
            o[jj] = f2bf(v);
        }
        if (isGCN)       *(u16x8*)&outGCN[(size_t)n * 64 + f0] = o;
        else if (isSAGE) *(u16x8*)&outSAGE[(size_t)n * 64 + (f0 - 64)] = o;
        else             *(u16x8*)&outGAT[(size_t)n * 128 + (f0 - 128)] = o;
    }
}

// ---------------- BatchNorm stats (1- and 2-input) ----------------
template <int F, bool TWO>
__global__ void k_bn_stats(const unsigned short* __restrict__ x,
                           const unsigned short* __restrict__ y,
                           float* __restrict__ sums) {
    constexpr int TPR = F / 8;
    constexpr int RPB = 256 / TPR;
    __shared__ float lsum[F], lsq[F];
    for (int i = threadIdx.x; i < F; i += 256) { lsum[i] = 0.f; lsq[i] = 0.f; }
    __syncthreads();
    int fl = threadIdx.x % TPR, rl = threadIdx.x / TPR;
    int f0 = fl * 8;
    float s[8] = {}, s2[8] = {};
    for (int n = blockIdx.x * RPB + rl; n < NN; n += gridDim.x * RPB) {
        u16x8 v = *(const u16x8*)&x[(size_t)n * F + f0];
        u16x8 w = {};
        if (TWO) w = *(const u16x8*)&y[(size_t)n * F + f0];
#pragma unroll
        for (int j = 0; j < 8; ++j) {
            float f = bf2f(v[j]);
            if (TWO) f += bf2f(w[j]);
            s[j] += f; s2[j] += f * f;
        }
    }
#pragma unroll
    for (int off = TPR; off < 64; off <<= 1)
#pragma unroll
        for (int j = 0; j < 8; ++j) { s[j] += __shfl_xor(s[j], off); s2[j] += __shfl_xor(s2[j], off); }
    if ((threadIdx.x & 63) < TPR) {
#pragma unroll
        for (int j = 0; j < 8; ++j) {
            atomicAdd(&lsum[f0 + j], s[j]);
            atomicAdd(&lsq[f0 + j], s2[j]);
        }
    }
    __syncthreads();
    for (int i = threadIdx.x; i < F; i += 256) {
        atomicAdd(&sums[i], lsum[i]);
        atomicAdd(&sums[F + i], lsq[i]);
    }
}

// ---------------- BatchNorm apply, optional dual output --------------------
// ACT: 1 relu, 2 elu. O1: compact out. O2: strided into comb at OOFF.
template <int F, int ACT, bool TWO, bool O1, bool O2, int OOFF>
__global__ void k_bn_apply(const unsigned short* __restrict__ x,
                           const unsigned short* __restrict__ y,
                           const float* __restrict__ sums,
                           const float* __restrict__ gamma, const float* __restrict__ beta,
                           unsigned short* __restrict__ out1, unsigned short* __restrict__ comb) {
    int idx = blockIdx.x * 256 + threadIdx.x;   // units of 8 elems
    if (idx >= NN * F / 8) return;
    int row = idx / (F / 8);
    int f0 = (idx % (F / 8)) * 8;
    u16x8 v = *(const u16x8*)&x[(size_t)idx * 8];
    u16x8 w = {};
    if (TWO) w = *(const u16x8*)&y[(size_t)idx * 8];
    u16x8 o;
#pragma unroll
    for (int j = 0; j < 8; ++j) {
        int f = f0 + j;
        float mean = sums[f] * (1.0f / NN);
        float var = sums[F + f] * (1.0f / NN) - mean * mean;
        float rstd = rsqrtf(var + BN_EPS);
        float raw = bf2f(v[j]);
        if (TWO) raw += bf2f(w[j]);
        float val = (raw - mean) * rstd * gamma[f] + beta[f];
        if (ACT == 1) val = fmaxf(val, 0.f);
        if (ACT == 2) val = (val > 0.f) ? val : (__expf(val) - 1.0f);
        o[j] = f2bf(val);
    }
    if (O1) *(u16x8*)&out1[(size_t)idx * 8] = o;
    if (O2) *(u16x8*)&comb[(size_t)row * 256 + OOFF + f0] = o;
}

// ---------------- pooling / fusion ----------------
__global__ void k_pool(const unsigned short* __restrict__ x, const int* __restrict__ batch,
                       float* __restrict__ pooled, int off) {
    int f = threadIdx.x & 127;
    int half = threadIdx.x >> 7;
    int nend = min(NN, (int)(blockIdx.x + 1) * 128);
    float acc = 0.f; int gcur = -1;
    for (int n = blockIdx.x * 128 + half; n < nend; n += 2) {
        int g = batch[n];
        if (g != gcur) {
            if (gcur >= 0) atomicAdd(&pooled[(size_t)gcur * 384 + off + f], acc);
            gcur = g; acc = 0.f;
        }
        acc += bf2f(x[(size_t)n * 128 + f]);
    }
    if (gcur >= 0) atomicAdd(&pooled[(size_t)gcur * 384 + off + f], acc);
}

__global__ void k_fusion(const float* __restrict__ pooled, const float* __restrict__ cntG,
                         const float* __restrict__ W, const float* __restrict__ b,
                         float* __restrict__ out) {
    int idx = blockIdx.x * 256 + threadIdx.x;   // NG*128
    if (idx >= NG * 128) return;
    int g = idx / 128, o = idx % 128;
    float inv = 1.0f / fmaxf(cntG[g], 1.0f);
    float acc = b[o];
#pragma unroll 4
    for (int k = 0; k < 384; ++k)
        acc += pooled[g * 384 + k] * inv * W[k * 128 + o];
    out[idx] = acc;
}

// ---------------- launcher ----------------
static inline int grid1(long long n) { return (int)((n + 255) / 256); }

extern "C" void kernel_launch(void* const* d_in, const int* in_sizes, int n_in,
                              void* d_out, int out_size, void* d_ws, size_t ws_size,
                              hipStream_t stream) {
    const float* x       = (const float*)d_in[0];
    const int*   ei      = (const int*)d_in[1];
    const int*   batch   = (const int*)d_in[2];
    const float* gcn_W0  = (const float*)d_in[3];
    const float* gcn_W1  = (const float*)d_in[5];
    const float* gcn_W2  = (const float*)d_in[7];
    const float* gcn_b2  = (const float*)d_in[8];
    const float* gcn_g0  = (const float*)d_in[9];
    const float* gcn_bb0 = (const float*)d_in[10];
    const float* gcn_g1  = (const float*)d_in[11];
    const float* gcn_bb1 = (const float*)d_in[12];
    const float* gat_W0  = (const float*)d_in[13];
    const float* gat_as0 = (const float*)d_in[14];
    const float* gat_ad0 = (const float*)d_in[15];
    const float* gat_W1  = (const float*)d_in[17];
    const float* gat_as1 = (const float*)d_in[18];
    const float* gat_ad1 = (const float*)d_in[19];
    const float* gat_W2  = (const float*)d_in[21];
    const float* gat_as2 = (const float*)d_in[22];
    const float* gat_ad2 = (const float*)d_in[23];
    const float* gat_b2  = (const float*)d_in[24];
    const float* gat_g0  = (const float*)d_in[25];
    const float* gat_bb0 = (const float*)d_in[26];
    const float* gat_g1  = (const float*)d_in[27];
    const float* gat_bb1 = (const float*)d_in[28];
    const float* sage_Wl0 = (const float*)d_in[29];
    const float* sage_Wr0 = (const float*)d_in[30];
    const float* sage_Wl1 = (const float*)d_in[32];
    const float* sage_Wr1 = (const float*)d_in[33];
    const float* sage_Wl2 = (const float*)d_in[35];
    const float* sage_Wr2 = (const float*)d_in[36];
    const float* sage_b2  = (const float*)d_in[37];
    const float* sage_g0  = (const float*)d_in[38];
    const float* sage_bb0 = (const float*)d_in[39];
    const float* sage_g1  = (const float*)d_in[40];
    const float* sage_bb1 = (const float*)d_in[41];
    const float* fus_W    = (const float*)d_in[42];
    const float* fus_b    = (const float*)d_in[43];

    const int* src = ei;
    const int* dst = ei + NE;

    // workspace layout (float units)
    float* ws = (float*)d_ws;
    size_t off = 0;
    auto alloc = [&](size_t n) { float* p = ws + off; off += (n + 3) & ~(size_t)3; return p; };
    unsigned short* combA = (unsigned short*)alloc((size_t)NN * 128);  // NN*256 bf16
    unsigned short* combB = (unsigned short*)alloc((size_t)NN * 128);
    unsigned short* bufGCN  = (unsigned short*)alloc((size_t)NN * 32); // NN*64 bf16
    unsigned short* bufGAT  = (unsigned short*)alloc((size_t)NN * 64); // NN*128 bf16
    unsigned short* bufSAGE = (unsigned short*)alloc((size_t)NN * 32);
    unsigned short* sr0     = (unsigned short*)alloc((size_t)NN * 32);
    unsigned short* sageH0  = (unsigned short*)alloc((size_t)NN * 32);
    unsigned short* sageM1  = (unsigned short*)alloc((size_t)NN * 32);
    unsigned short* wt      = (unsigned short*)alloc(110592 / 2);
    int*   indeg    = (int*)alloc(NN);
    int*   rowstart = (int*)alloc(NN + 1);
    int*   cursor   = (int*)alloc(NN);
    int*   csr_src  = (int*)alloc(NE);
    int2*  pair     = (int2*)alloc((size_t)NE * 2);
    int*   bsum     = (int*)alloc(NB);
    int*   boff     = (int*)alloc(NB);
    float* dis   = alloc(NN);
    float* alsrc = alloc((size_t)NN * 2);
    float* aldst = alloc((size_t)NN * 2);
    float* bnsum = alloc(6 * 256 + NG * 384 + NG);
    float* pooled = bnsum + 6 * 256;
    float* cntG   = pooled + NG * 384;
    (void)ws_size; (void)n_in; (void)in_sizes; (void)out_size;

    unsigned short* sageH1  = sr0;                    // sr0 dead after L0
    unsigned short* finGCN  = combB;                  // combB dead after aggF1
    unsigned short* finSAGE = combB + (size_t)NN * 128;

    // fused L0 weights [gcn(64)|gat(128)|sWl(64)|sWr(64)] x 128 + per-layer W^T
    unsigned short* wf        = wt;                  // 40960
    unsigned short* gcn_W1t   = wf + 40960;          // 64x64
    unsigned short* gcn_W2t   = gcn_W1t + 4096;      // 64x128
    unsigned short* gat_W1t   = gcn_W2t + 8192;      // 128x128
    unsigned short* gat_W2t   = gat_W1t + 16384;
    unsigned short* sage_Wl1t = gat_W2t + 16384;
    unsigned short* sage_Wr1t = sage_Wl1t + 4096;
    unsigned short* sage_Wl2t = sage_Wr1t + 4096;
    unsigned short* sage_Wr2t = sage_Wl2t + 8192;

    const int gAgg = NN / 4;
    const int gMM  = (NN + 63) / 64;

    // ---- CSR build + precompute ----
    hipMemsetAsync(indeg, 0, NN * 4, stream);
    hipMemsetAsync(bnsum, 0, (6 * 256 + NG * 384 + NG) * 4, stream);
    k_indeg<<<grid1(NE), 256, 0, stream>>>(dst, indeg);
    k_scan1<<<NB, 256, 0, stream>>>(indeg, rowstart, bsum, dis);
    k_scan2<<<1, 256, 0, stream>>>(bsum, boff);
    k_scan3<<<NB, 256, 0, stream>>>(rowstart, boff, cursor);
    k_fill<<<grid1(NE), 256, 0, stream>>>(src, dst, cursor, csr_src);
    k_pack<<<grid1(NE), 256, 0, stream>>>(csr_src, dis, pair);
    k_count<<<128, 256, 0, stream>>>(batch, cntG);
    WTable wtab = {{
        { gcn_W0, wf, 128, 64 }, { gat_W0, wf + 64 * 128, 128, 128 },
        { sage_Wl0, wf + 192 * 128, 128, 64 }, { sage_Wr0, wf + 256 * 128, 128, 64 },
        { gcn_W1, gcn_W1t, 64, 64 }, { gcn_W2, gcn_W2t, 64, 128 },
        { gat_W1, gat_W1t, 128, 128 }, { gat_W2, gat_W2t, 128, 128 },
        { sage_Wl1, sage_Wl1t, 64, 64 }, { sage_Wr1, sage_Wr1t, 64, 64 },
        { sage_Wl2, sage_Wl2t, 64, 128 }, { sage_Wr2, sage_Wr2t, 64, 128 },
    }};
    k_convw<<<12, 256, 0, stream>>>(wtab);

    // ---- L0: fused matmul -> combA; fused agg -> compacts ----
    k_mm0<<<gMM, 256, 0, stream>>>(x, wf, gat_as0, gat_ad0, alsrc, aldst, combA, sr0);
    k_aggf<2, false><<<gAgg, 256, 0, stream>>>(rowstart, pair, dis, alsrc, aldst,
                                               combA, nullptr, bufGCN, bufGAT, bufSAGE);
    k_bn_stats<64, false><<<250, 256, 0, stream>>>(bufGCN, nullptr, bnsum + 0 * 256);
    k_bn_stats<128, false><<<250, 256, 0, stream>>>(bufGAT, nullptr, bnsum + 2 * 256);
    k_bn_stats<64, true><<<250, 256, 0, stream>>>(bufSAGE, sr0, bnsum + 4 * 256);
    // L1 producers -> combB
    k_mm<64, 64, false, false, 1, 0, 256, 0><<<gMM, 256, 0, stream>>>(
        bufGCN, gcn_W1t, nullptr, nullptr, nullptr,
        bnsum + 0 * 256, gcn_g0, gcn_bb0, nullptr, nullptr, nullptr, nullptr, combB);
    k_mm<128, 128, false, false, 2, 2, 256, 128><<<gMM, 256, 0, stream>>>(
        bufGAT, gat_W1t, nullptr, nullptr, nullptr,
        bnsum + 2 * 256, gat_g0, gat_bb0, gat_as1, gat_ad1, alsrc, aldst, combB);
    k_bn_apply<64, 1, true, true, true, 64><<<grid1(NN * 8), 256, 0, stream>>>(
        bufSAGE, sr0, bnsum + 4 * 256, sage_g0, sage_bb0, sageH0, combB);

    // ---- L1: fused agg ----
    k_aggf<2, false><<<gAgg, 256, 0, stream>>>(rowstart, pair, dis, alsrc, aldst,
                                               combB, nullptr, bufGCN, bufGAT, bufSAGE);
    k_bn_stats<64, false><<<250, 256, 0, stream>>>(bufGCN, nullptr, bnsum + 1 * 256);
    k_bn_stats<128, false><<<250, 256, 0, stream>>>(bufGAT, nullptr, bnsum + 3 * 256);
    k_mm<64, 64, true, false, 0, 0, 64, 0><<<gMM, 256, 0, stream>>>(
        bufSAGE, sage_Wl1t, sageH0, sage_Wr1t, nullptr,
        nullptr, nullptr, nullptr, nullptr, nullptr, nullptr, nullptr, sageM1);
    // L2 producers -> combA
    k_bn_apply<64, 1, false, false, true, 0><<<grid1(NN * 8), 256, 0, stream>>>(
        bufGCN, nullptr, bnsum + 1 * 256, gcn_g1, gcn_bb1, nullptr, combA);
    k_mm<128, 128, false, false, 2, 1, 256, 128><<<gMM, 256, 0, stream>>>(
        bufGAT, gat_W2t, nullptr, nullptr, nullptr,
        bnsum + 3 * 256, gat_g1, gat_bb1, gat_as2, gat_ad2, alsrc, aldst, combA);
    k_bn_stats<64, false><<<250, 256, 0, stream>>>(sageM1, nullptr, bnsum + 5 * 256);
    k_bn_apply<64, 1, false, true, true, 64><<<grid1(NN * 8), 256, 0, stream>>>(
        sageM1, nullptr, bnsum + 5 * 256, sage_g1, sage_bb1, sageH1, combA);

    // ---- L2: fused agg (GAT H=1, bias fused) ----
    k_aggf<1, true><<<gAgg, 256, 0, stream>>>(rowstart, pair, dis, alsrc, aldst,
                                              combA, gat_b2, bufGCN, bufGAT, bufSAGE);
    k_mm<64, 128, false, true, 0, 0, 128, 0><<<gMM, 256, 0, stream>>>(
        bufGCN, gcn_W2t, nullptr, nullptr, gcn_b2,
        nullptr, nullptr, nullptr, nullptr, nullptr, nullptr, nullptr, finGCN);
    k_mm<64, 128, true, true, 0, 0, 128, 0><<<gMM, 256, 0, stream>>>(
        bufSAGE, sage_Wl2t, sageH1, sage_Wr2t, sage_b2,
        nullptr, nullptr, nullptr, nullptr, nullptr, nullptr, nullptr, finSAGE);

    // ---- pool + fusion ----
    k_pool<<<(NN + 127) / 128, 256, 0, stream>>>(finGCN, batch, pooled, 0);
    k_pool<<<(NN + 127) / 128, 256, 0, stream>>>(bufGAT, batch, pooled, 128);
    k_pool<<<(NN + 127) / 128, 256, 0, stream>>>(finSAGE, batch, pooled, 256);
    k_fusion<<<grid1(NG * 128), 256, 0, stream>>>(pooled, cntG, fus_W, fus_b, (float*)d_out);
}